// Round 1
// 457.897 us; speedup vs baseline: 1.0395x; 1.0395x over previous
//
#include <hip/hip_runtime.h>
#include <stdint.h>
#include <stddef.h>

#define N_NODES 200000
#define N_EDGES 800000
#define NREL 16
#define NBASES 8

typedef __attribute__((ext_vector_type(8))) short short8b;
typedef __attribute__((ext_vector_type(4))) float float4v;

__device__ __forceinline__ short f32_bf16(float f) {
  uint32_t u = __builtin_bit_cast(uint32_t, f);
  uint32_t r = u + 0x7FFFu + ((u >> 16) & 1u);
  return (short)(uint16_t)(r >> 16);
}
__device__ __forceinline__ float bf2f(uint16_t h) {
  return __builtin_bit_cast(float, (uint32_t)h << 16);
}

// ============================ shared: W table ============================
// Wt[r][e][d] = bf16( sum_b att[r][b] * bases[b][d][e] )   (W transposed)
__global__ __launch_bounds__(256) void k_wprep(const float* __restrict__ bases,
                                               const float* __restrict__ att,
                                               uint16_t* __restrict__ Wt) {
  int i = blockIdx.x * 256 + threadIdx.x;
  if (i >= 17 * 64 * 64) return;
  int r = i >> 12;
  int e = (i >> 6) & 63;
  int d = i & 63;
  float acc = 0.f;
  for (int b = 0; b < NBASES; ++b)
    acc += att[r * NBASES + b] * bases[b * 4096 + d * 64 + e];
  Wt[i] = (uint16_t)f32_bf16(acc);
}

// ======================================================================
// MAIN PATH: two-phase target-sorted (no output atomics)
// ======================================================================
#define MAXTILES 112528
#define MAXRECS  (MAXTILES * 16)
#define WS_CNTR    0          // 32 int
#define WS_RCUR    128        // 32 int
#define WS_RSTART  256        // 32 int (kept for layout compat, unused)
#define WS_GCUR    384        // 1 int
#define WS_WT      512        // 17*64*64 u16 -> ends 139776
#define WS_TILEREL 139776     // MAXTILES u8 -> ends 252304 (pad to 252416)
#define WS_CNTV    252416     // 200000 int
#define WS_VSTART  1052416    // 200000 int
#define WS_VCUR    1852416    // 200000 int
#define WS_RECS    2652416    // MAXRECS int2 -> ends 17056000 (pad to 17056128)
#define WS_MSG     17056128   // MAXRECS * 64 u16 rows
#define WS_TOTAL   (WS_MSG + (size_t)MAXRECS * 128)   // ~247.5 MB
#define XBF_BYTES  ((size_t)N_NODES * 64 * 2)         // 25.6 MB bf16 x table

// Fused: Wt prep (blocks 0..272) | zero cntr/rcur/gcur+cntv (273..1054) | x->bf16 (1055..7304)
__global__ __launch_bounds__(256) void k_init(const float* __restrict__ bases,
                                              const float* __restrict__ att,
                                              uint16_t* __restrict__ Wt,
                                              const float* __restrict__ x,
                                              uint16_t* __restrict__ xb,
                                              int* __restrict__ zero0,
                                              int* __restrict__ cntv) {
  int b = blockIdx.x;
  int tid = threadIdx.x;
  if (b < 273) {
    int i = b * 256 + tid;
    if (i < 17 * 64 * 64) {
      int r = i >> 12;
      int e = (i >> 6) & 63;
      int d = i & 63;
      float acc = 0.f;
      for (int bb = 0; bb < NBASES; ++bb)
        acc += att[r * NBASES + bb] * bases[bb * 4096 + d * 64 + e];
      Wt[i] = (uint16_t)f32_bf16(acc);
    }
  } else if (b < 1055) {
    int idx = (b - 273) * 256 + tid;
    if (idx < 128) zero0[idx] = 0;            // cntr/rcur/rstart/gcur region (512 B)
    else if (idx - 128 < N_NODES) cntv[idx - 128] = 0;
  } else {
    int i = (b - 1055) * 256 + tid;           // grid sized exactly: i < 1,600,000
    const float* xp = x + (size_t)i * 8;
    float4v q0 = *(const float4v*)xp;
    float4v q1 = *(const float4v*)(xp + 4);
    short8b o;
    o[0] = f32_bf16(q0[0]); o[1] = f32_bf16(q0[1]); o[2] = f32_bf16(q0[2]); o[3] = f32_bf16(q0[3]);
    o[4] = f32_bf16(q1[0]); o[5] = f32_bf16(q1[1]); o[6] = f32_bf16(q1[2]); o[7] = f32_bf16(q1[3]);
    *(short8b*)(xb + (size_t)i * 8) = o;
  }
}

__global__ __launch_bounds__(256) void k_count(const int* __restrict__ src,
                                               const int* __restrict__ tgt,
                                               const int* __restrict__ et,
                                               const int* __restrict__ mask,
                                               int* __restrict__ cntr,
                                               int* __restrict__ cntv,
                                               int nE, int nN) {
  __shared__ int lh[NREL + 1];
  if (threadIdx.x <= NREL) lh[threadIdx.x] = 0;
  __syncthreads();
  int i = blockIdx.x * 256 + threadIdx.x;
  if (i < nE) {
    atomicAdd(&lh[et[i]], 2);
    atomicAdd(&cntv[tgt[i]], 1);
    atomicAdd(&cntv[src[i]], 1);
  }
  if (i < nN && mask[i]) {
    atomicAdd(&lh[NREL], 1);
    atomicAdd(&cntv[i], 1);
  }
  __syncthreads();
  if (threadIdx.x <= NREL && lh[threadIdx.x])
    atomicAdd(&cntr[threadIdx.x], lh[threadIdx.x]);
}

// Fused bucket-prefix + tileRel + pad-record writes (replaces k_bucket, k_tilerel,
// and the 14.4 MB recs memset: only <=272 bucket-padding slots need (-1,-1)).
__global__ __launch_bounds__(256) void k_prep(const int* __restrict__ cntr,
                                              int* __restrict__ rcur,
                                              uint8_t* __restrict__ tileRel,
                                              int2* __restrict__ recs,
                                              int maxTiles) {
  __shared__ int s[NREL + 2];
  if (threadIdx.x == 0) {
    int base = 0;
    for (int r = 0; r <= NREL; ++r) {
      s[r] = base;
      base = (base + cntr[r] + 15) & ~15;
    }
    s[NREL + 1] = base;
  }
  __syncthreads();
  if (blockIdx.x == 0) {
    if (threadIdx.x <= NREL) rcur[threadIdx.x] = s[threadIdx.x];
    // pad slots: bucket r occupies [s[r], s[r+1]); records fill s[r]..s[r]+cntr[r]
    for (int w = threadIdx.x; w < (NREL + 1) * 16; w += 256) {
      int r = w >> 4, j = w & 15;
      int pos = s[r] + cntr[r] + j;
      if (pos < s[r + 1]) recs[pos] = make_int2(-1, -1);
    }
  }
  int t = blockIdx.x * 256 + threadIdx.x;
  if (t < maxTiles) {
    int p = t * 16;
    uint8_t rr = 255;
    if (p < s[NREL + 1]) {
      int q = 0;
      for (int k = 1; k <= NREL; ++k)
        if (p >= s[k]) q = k;
      rr = (uint8_t)q;
    }
    tileRel[t] = rr;
  }
}

// per-target contiguous segment allocation; shfl-scan (2 barriers instead of 16)
__global__ __launch_bounds__(256) void k_vseg(const int* __restrict__ cntv,
                                              int* __restrict__ vstart,
                                              int* __restrict__ vcur,
                                              int* __restrict__ gcur, int nN) {
  __shared__ int wsum[4];
  __shared__ int s_base;
  int v = blockIdx.x * 256 + threadIdx.x;
  int lane = threadIdx.x & 63;
  int wid = threadIdx.x >> 6;
  int c = (v < nN) ? cntv[v] : 0;
  int incl = c;
  for (int off = 1; off < 64; off <<= 1) {
    int n = __shfl_up(incl, off, 64);
    if (lane >= off) incl += n;
  }
  if (lane == 63) wsum[wid] = incl;
  __syncthreads();
  if (threadIdx.x == 0) {
    int t0 = wsum[0], t1 = wsum[1], t2 = wsum[2], t3 = wsum[3];
    s_base = atomicAdd(gcur, t0 + t1 + t2 + t3);
    wsum[0] = 0;
    wsum[1] = t0;
    wsum[2] = t0 + t1;
    wsum[3] = t0 + t1 + t2;
  }
  __syncthreads();
  if (v < nN) {
    int st = s_base + wsum[wid] + incl - c;
    vstart[v] = st;
    vcur[v] = st;
  }
}

__global__ __launch_bounds__(256) void k_records(const int* __restrict__ src,
                                                 const int* __restrict__ tgt,
                                                 const int* __restrict__ et,
                                                 const int* __restrict__ mask,
                                                 int2* __restrict__ recs,
                                                 int* __restrict__ rcur,
                                                 int* __restrict__ vcur,
                                                 int nE, int nN) {
  __shared__ int lh[NREL + 1], lbase[NREL + 1];
  if (threadIdx.x <= NREL) lh[threadIdx.x] = 0;
  __syncthreads();
  int i = blockIdx.x * 256 + threadIdx.x;
  bool isE = i < nE;
  bool isN = (i < nN) && mask[i];
  int r = 0, loff = 0, loffN = 0, s_ = 0, t_ = 0;
  if (isE) {
    r = et[i];
    s_ = src[i];
    t_ = tgt[i];
    loff = atomicAdd(&lh[r], 2);
  }
  if (isN) loffN = atomicAdd(&lh[NREL], 1);
  __syncthreads();
  if (threadIdx.x <= NREL)
    lbase[threadIdx.x] = lh[threadIdx.x] ? atomicAdd(&rcur[threadIdx.x], lh[threadIdx.x]) : 0;
  __syncthreads();
  if (isE) {
    int pos = lbase[r] + loff;            // even -> 16B aligned
    int o1 = atomicAdd(&vcur[t_], 1);     // msg (s_ -> t_)
    int o2 = atomicAdd(&vcur[s_], 1);     // msg (t_ -> s_)
    *(int4*)(recs + pos) = make_int4(s_, o1, t_, o2);
  }
  if (isN) {
    int pos = lbase[NREL] + loffN;
    int o = atomicAdd(&vcur[i], 1);
    recs[pos] = make_int2(i, o);
  }
}

// Phase A: relation-grouped MFMA, write bf16 message rows at target-sorted slots.
// LDS (s_m/s_slot) is strictly wave-private: no __syncthreads needed — DS ops of a
// wave execute in order; lgkmcnt + sched_barrier(0) pins compiler ordering (rule #18).
template <bool XBF>
__global__ __launch_bounds__(256) void k_phaseA(const float* __restrict__ x,
                                                const uint16_t* __restrict__ xb,
                                                const int2* __restrict__ recs,
                                                const uint16_t* __restrict__ Wt,
                                                const uint8_t* __restrict__ tileRel,
                                                uint16_t* __restrict__ msg,
                                                int ntiles) {
  __shared__ uint16_t s_m[4][16 * 72];   // +8 elem row pad
  __shared__ int s_slot[4][16];
  const int wid = threadIdx.x >> 6;
  const int lane = threadIdx.x & 63;
  const int quad = lane >> 4;
  const int m16 = lane & 15;
  const int t0 = (blockIdx.x * 4 + wid) * 4;

  if (tileRel[t0] == 255) return;        // wave-uniform tail exit (tileRel monotonic)

  int curRel = -1;
  short8b bfrag[4][2] = {};

  for (int it = 0; it < 4; ++it) {
    int t = t0 + it;
    int rel = (t < ntiles) ? (int)tileRel[t] : 255;
    bool valid = (rel != 255);

    if (valid && rel != curRel) {
      curRel = rel;
      const uint16_t* wbase = Wt + (size_t)rel * 4096;
      for (int nt = 0; nt < 4; ++nt)
        for (int kt = 0; kt < 2; ++kt)
          bfrag[nt][kt] = *(const short8b*)(wbase + (size_t)(nt * 16 + m16) * 64 + kt * 32 + quad * 8);
    }

    int2 rec = valid ? recs[t * 16 + m16] : make_int2(-1, -1);
    int u = rec.x < 0 ? 0 : rec.x;

    short8b a0, a1;
    if (XBF) {
      const uint16_t* xp = xb + (size_t)u * 64 + quad * 8;
      a0 = *(const short8b*)(xp);
      a1 = *(const short8b*)(xp + 32);
    } else {
      const float* xp = x + (size_t)u * 64 + quad * 8;
      float4v q0 = *(const float4v*)(xp);
      float4v q1 = *(const float4v*)(xp + 4);
      float4v q2 = *(const float4v*)(xp + 32);
      float4v q3 = *(const float4v*)(xp + 36);
      a0[0] = f32_bf16(q0[0]); a0[1] = f32_bf16(q0[1]); a0[2] = f32_bf16(q0[2]); a0[3] = f32_bf16(q0[3]);
      a0[4] = f32_bf16(q1[0]); a0[5] = f32_bf16(q1[1]); a0[6] = f32_bf16(q1[2]); a0[7] = f32_bf16(q1[3]);
      a1[0] = f32_bf16(q2[0]); a1[1] = f32_bf16(q2[1]); a1[2] = f32_bf16(q2[2]); a1[3] = f32_bf16(q2[3]);
      a1[4] = f32_bf16(q3[0]); a1[5] = f32_bf16(q3[1]); a1[6] = f32_bf16(q3[2]); a1[7] = f32_bf16(q3[3]);
    }

    float4v acc[4];
    for (int nt = 0; nt < 4; ++nt) { acc[nt][0] = 0.f; acc[nt][1] = 0.f; acc[nt][2] = 0.f; acc[nt][3] = 0.f; }
    for (int nt = 0; nt < 4; ++nt) {
      acc[nt] = __builtin_amdgcn_mfma_f32_16x16x32_bf16(a0, bfrag[nt][0], acc[nt], 0, 0, 0);
      acc[nt] = __builtin_amdgcn_mfma_f32_16x16x32_bf16(a1, bfrag[nt][1], acc[nt], 0, 0, 0);
    }

    // C/D: col(dim) = m16 + nt*16, row(message) = quad*4 + reg
    if (quad == 0) s_slot[wid][m16] = rec.y;
    for (int reg = 0; reg < 4; ++reg)
      for (int nt = 0; nt < 4; ++nt)
        s_m[wid][(quad * 4 + reg) * 72 + nt * 16 + m16] = (uint16_t)f32_bf16(acc[nt][reg]);

    asm volatile("s_waitcnt lgkmcnt(0)" ::: "memory");
    __builtin_amdgcn_sched_barrier(0);

    // 16 rows x 128 B, 8 lanes/row x 16 B
    for (int p = 0; p < 2; ++p) {
      int row = (lane >> 3) + p * 8;
      int slot = s_slot[wid][row];
      if (slot >= 0) {
        const uint16_t* lp = &s_m[wid][row * 72 + (lane & 7) * 8];
        int4 val = *(const int4*)lp;
        *(int4*)(msg + (size_t)slot * 64 + (lane & 7) * 8) = val;
      }
    }
    __builtin_amdgcn_sched_barrier(0);   // keep next iter's ds_writes after these reads
  }
}

// Phase B: per-target segmented sum. 8 lanes/target, 16 B loads, 32 targets/block.
__global__ __launch_bounds__(256) void k_phaseB(const uint16_t* __restrict__ msg,
                                                const int* __restrict__ cntv,
                                                const int* __restrict__ vstart,
                                                float* __restrict__ out, int nN) {
  int v = blockIdx.x * 32 + (threadIdx.x >> 3);
  int l = threadIdx.x & 7;
  if (v >= nN) return;
  int cnt = cntv[v];
  int base = vstart[v];
  float a[8] = {0.f, 0.f, 0.f, 0.f, 0.f, 0.f, 0.f, 0.f};
  const uint16_t* mp = msg + (size_t)base * 64 + l * 8;
  int j = 0;
  for (; j + 2 <= cnt; j += 2) {
    short8b h0 = *(const short8b*)(mp + (size_t)j * 64);
    short8b h1 = *(const short8b*)(mp + (size_t)(j + 1) * 64);
#pragma unroll
    for (int k = 0; k < 8; ++k)
      a[k] += bf2f((uint16_t)h0[k]) + bf2f((uint16_t)h1[k]);
  }
  if (j < cnt) {
    short8b h = *(const short8b*)(mp + (size_t)j * 64);
#pragma unroll
    for (int k = 0; k < 8; ++k)
      a[k] += bf2f((uint16_t)h[k]);
  }
  float* op = out + (size_t)v * 64 + l * 8;
  *(float4*)op = make_float4(a[0], a[1], a[2], a[3]);
  *(float4*)(op + 4) = make_float4(a[4], a[5], a[6], a[7]);
}

// ======================================================================
// FALLBACK PATH (atomic scatter) — used only if ws_size too small
// ======================================================================
#define F_WS_HIST    0
#define F_WS_CURSOR  64
#define F_WS_START   128
#define F_WS_WT      512
#define F_WS_TILEREL 139776
#define F_WS_RECS    262144
#define F_MAXTILES   112520
#define F_MAXRECS    (F_MAXTILES * 16)

__global__ __launch_bounds__(256) void f_hist(const int* __restrict__ et,
                                              int* __restrict__ hist, int nE) {
  __shared__ int lh[NREL];
  if (threadIdx.x < NREL) lh[threadIdx.x] = 0;
  __syncthreads();
  int i = blockIdx.x * 256 + threadIdx.x;
  if (i < nE) atomicAdd(&lh[et[i]], 2);
  __syncthreads();
  if (threadIdx.x < NREL && lh[threadIdx.x] > 0)
    atomicAdd(&hist[threadIdx.x], lh[threadIdx.x]);
}

__global__ __launch_bounds__(256) void f_prefix(const int* __restrict__ hist,
                                                int* __restrict__ cursor,
                                                int* __restrict__ start,
                                                uint8_t* __restrict__ tileRel,
                                                int nN, int maxTiles) {
  __shared__ int s_start[17];
  if (threadIdx.x == 0) {
    int base = nN;
    for (int r = 0; r < NREL; ++r) {
      s_start[r] = base;
      cursor[r] = base;
      start[r] = base;
      base = (base + hist[r] + 15) & ~15;
    }
    s_start[16] = base;
    start[16] = base;
  }
  __syncthreads();
  int endp = s_start[16];
  for (int t = threadIdx.x; t < maxTiles; t += 256) {
    int p = t * 16;
    uint8_t r;
    if (p < nN) r = 16;
    else if (p >= endp) r = 255;
    else {
      int q = 0;
      for (int k = 1; k < NREL; ++k) if (p >= s_start[k]) q = k;
      r = (uint8_t)q;
    }
    tileRel[t] = r;
  }
}

__global__ __launch_bounds__(256) void f_scatter(const int* __restrict__ src,
                                                 const int* __restrict__ tgt,
                                                 const int* __restrict__ et,
                                                 const int* __restrict__ mask,
                                                 int2* __restrict__ recs,
                                                 int* __restrict__ cursor,
                                                 int nE, int nN) {
  __shared__ int lh[NREL];
  __shared__ int lbase[NREL];
  if (threadIdx.x < NREL) lh[threadIdx.x] = 0;
  __syncthreads();
  int i = blockIdx.x * 256 + threadIdx.x;
  int r = 0, loff = 0;
  bool isEdge = (i < nE);
  if (isEdge) {
    r = et[i];
    loff = atomicAdd(&lh[r], 2);
  }
  __syncthreads();
  if (threadIdx.x < NREL)
    lbase[threadIdx.x] = (lh[threadIdx.x] > 0) ? atomicAdd(&cursor[threadIdx.x], lh[threadIdx.x]) : 0;
  __syncthreads();
  if (isEdge) {
    int pos = lbase[r] + loff;
    int s = src[i], t = tgt[i];
    *(int4*)(recs + pos) = make_int4(s, t, t, s);
  }
  if (i < nN) {
    recs[i] = (mask[i] != 0) ? make_int2(i, i) : make_int2(-1, -1);
  }
}

__global__ __launch_bounds__(256) void f_compute(const float* __restrict__ x,
                                                 const int2* __restrict__ recs,
                                                 const uint16_t* __restrict__ Wt,
                                                 const uint8_t* __restrict__ tileRel,
                                                 float* __restrict__ out,
                                                 int ntiles) {
  const int lane = threadIdx.x & 63;
  const int quad = lane >> 4;
  const int m16 = lane & 15;
  const int wave = blockIdx.x * 4 + (threadIdx.x >> 6);
  const int t0 = wave * 4;

  int curRel = -1;
  short8b bfrag[4][2] = {};

  for (int it = 0; it < 4; ++it) {
    int t = t0 + it;
    if (t >= ntiles) return;
    int rel = tileRel[t];
    if (rel == 255) return;

    if (rel != curRel) {
      curRel = rel;
      const uint16_t* wbase = Wt + (size_t)rel * 4096;
      for (int nt = 0; nt < 4; ++nt)
        for (int kt = 0; kt < 2; ++kt)
          bfrag[nt][kt] = *(const short8b*)(wbase + (size_t)(nt * 16 + m16) * 64 + kt * 32 + quad * 8);
    }

    int2 rec = recs[t * 16 + m16];
    int u = rec.x < 0 ? 0 : rec.x;

    const float* xp = x + (size_t)u * 64 + quad * 8;
    float4v q0 = *(const float4v*)(xp);
    float4v q1 = *(const float4v*)(xp + 4);
    float4v q2 = *(const float4v*)(xp + 32);
    float4v q3 = *(const float4v*)(xp + 36);
    short8b a0, a1;
    a0[0] = f32_bf16(q0[0]); a0[1] = f32_bf16(q0[1]); a0[2] = f32_bf16(q0[2]); a0[3] = f32_bf16(q0[3]);
    a0[4] = f32_bf16(q1[0]); a0[5] = f32_bf16(q1[1]); a0[6] = f32_bf16(q1[2]); a0[7] = f32_bf16(q1[3]);
    a1[0] = f32_bf16(q2[0]); a1[1] = f32_bf16(q2[1]); a1[2] = f32_bf16(q2[2]); a1[3] = f32_bf16(q2[3]);
    a1[4] = f32_bf16(q3[0]); a1[5] = f32_bf16(q3[1]); a1[6] = f32_bf16(q3[2]); a1[7] = f32_bf16(q3[3]);

    float4v acc[4];
    for (int nt = 0; nt < 4; ++nt) { acc[nt][0] = 0.f; acc[nt][1] = 0.f; acc[nt][2] = 0.f; acc[nt][3] = 0.f; }
    for (int nt = 0; nt < 4; ++nt) {
      acc[nt] = __builtin_amdgcn_mfma_f32_16x16x32_bf16(a0, bfrag[nt][0], acc[nt], 0, 0, 0);
      acc[nt] = __builtin_amdgcn_mfma_f32_16x16x32_bf16(a1, bfrag[nt][1], acc[nt], 0, 0, 0);
    }

    int tg[4];
    for (int reg = 0; reg < 4; ++reg)
      tg[reg] = __shfl(rec.y, quad * 4 + reg, 64);
    for (int reg = 0; reg < 4; ++reg) {
      if (tg[reg] < 0) continue;
      float* op = out + (size_t)tg[reg] * 64 + m16;
      for (int nt = 0; nt < 4; ++nt)
        __hip_atomic_fetch_add(op + nt * 16, acc[nt][reg], __ATOMIC_RELAXED, __HIP_MEMORY_SCOPE_AGENT);
    }
  }
}

// ======================================================================
extern "C" void kernel_launch(void* const* d_in, const int* in_sizes, int n_in,
                              void* d_out, int out_size, void* d_ws, size_t ws_size,
                              hipStream_t stream) {
  const float* x     = (const float*)d_in[0];
  const int*   mask  = (const int*)d_in[1];
  const int*   src   = (const int*)d_in[2];
  const int*   tgt   = (const int*)d_in[3];
  const int*   et    = (const int*)d_in[4];
  const float* bases = (const float*)d_in[5];
  const float* att   = (const float*)d_in[6];
  float* out = (float*)d_out;
  char* ws = (char*)d_ws;

  if (ws_size >= WS_TOTAL) {
    // ---------- two-phase target-sorted path ----------
    int*      cntr    = (int*)(ws + WS_CNTR);
    int*      rcur    = (int*)(ws + WS_RCUR);
    int*      gcur    = (int*)(ws + WS_GCUR);
    uint16_t* Wt      = (uint16_t*)(ws + WS_WT);
    uint8_t*  tileRel = (uint8_t*)(ws + WS_TILEREL);
    int*      cntv    = (int*)(ws + WS_CNTV);
    int*      vstart  = (int*)(ws + WS_VSTART);
    int*      vcur    = (int*)(ws + WS_VCUR);
    int2*     recs    = (int2*)(ws + WS_RECS);
    uint16_t* msg     = (uint16_t*)(ws + WS_MSG);
    uint16_t* xb      = (uint16_t*)(ws + WS_TOTAL);
    bool use_xbf = ws_size >= WS_TOTAL + XBF_BYTES;

    // init: 273 wprep blocks + 782 zero blocks + (x-cast 6250 blocks if room)
    k_init<<<use_xbf ? 7305 : 1055, 256, 0, stream>>>(bases, att, Wt, x, xb, (int*)ws, cntv);
    k_count<<<(N_EDGES + 255) / 256, 256, 0, stream>>>(src, tgt, et, mask, cntr, cntv, N_EDGES, N_NODES);
    k_prep<<<(MAXTILES + 255) / 256, 256, 0, stream>>>(cntr, rcur, tileRel, recs, MAXTILES);
    k_vseg<<<(N_NODES + 255) / 256, 256, 0, stream>>>(cntv, vstart, vcur, gcur, N_NODES);
    k_records<<<(N_EDGES + 255) / 256, 256, 0, stream>>>(src, tgt, et, mask, recs, rcur, vcur, N_EDGES, N_NODES);
    if (use_xbf)
      k_phaseA<true><<<(MAXTILES + 15) / 16, 256, 0, stream>>>(x, xb, recs, Wt, tileRel, msg, MAXTILES);
    else
      k_phaseA<false><<<(MAXTILES + 15) / 16, 256, 0, stream>>>(x, xb, recs, Wt, tileRel, msg, MAXTILES);
    k_phaseB<<<(N_NODES + 31) / 32, 256, 0, stream>>>(msg, cntv, vstart, out, N_NODES);
  } else {
    // ---------- fallback: atomic path ----------
    int*      hist    = (int*)(ws + F_WS_HIST);
    int*      cursor  = (int*)(ws + F_WS_CURSOR);
    int*      start   = (int*)(ws + F_WS_START);
    uint16_t* Wt      = (uint16_t*)(ws + F_WS_WT);
    uint8_t*  tileRel = (uint8_t*)(ws + F_WS_TILEREL);
    int2*     recs    = (int2*)(ws + F_WS_RECS);

    hipMemsetAsync(out, 0, (size_t)N_NODES * 64 * sizeof(float), stream);
    hipMemsetAsync(ws, 0, 512, stream);
    hipMemsetAsync(recs, 0xFF, (size_t)F_MAXRECS * sizeof(int2), stream);

    k_wprep<<<(17 * 64 * 64 + 255) / 256, 256, 0, stream>>>(bases, att, Wt);
    f_hist<<<(N_EDGES + 255) / 256, 256, 0, stream>>>(et, hist, N_EDGES);
    f_prefix<<<1, 256, 0, stream>>>(hist, cursor, start, tileRel, N_NODES, F_MAXTILES);
    f_scatter<<<(N_EDGES + 255) / 256, 256, 0, stream>>>(src, tgt, et, mask, recs, cursor, N_EDGES, N_NODES);
    f_compute<<<(F_MAXTILES + 15) / 16, 256, 0, stream>>>(x, recs, Wt, tileRel, out, F_MAXTILES);
  }
}

// Round 3
// 426.222 us; speedup vs baseline: 1.1168x; 1.0743x over previous
//
#include <hip/hip_runtime.h>
#include <stdint.h>
#include <stddef.h>

#define N_NODES 200000
#define N_EDGES 800000
#define NREL 16
#define NBASES 8

typedef __attribute__((ext_vector_type(8))) short short8b;
typedef __attribute__((ext_vector_type(4))) float float4v;
typedef __attribute__((ext_vector_type(4))) int int4v;

__device__ __forceinline__ short f32_bf16(float f) {
  uint32_t u = __builtin_bit_cast(uint32_t, f);
  uint32_t r = u + 0x7FFFu + ((u >> 16) & 1u);
  return (short)(uint16_t)(r >> 16);
}
__device__ __forceinline__ float bf2f(uint16_t h) {
  return __builtin_bit_cast(float, (uint32_t)h << 16);
}

// ============================ shared: W table ============================
__global__ __launch_bounds__(256) void k_wprep(const float* __restrict__ bases,
                                               const float* __restrict__ att,
                                               uint16_t* __restrict__ Wt) {
  int i = blockIdx.x * 256 + threadIdx.x;
  if (i >= 17 * 64 * 64) return;
  int r = i >> 12;
  int e = (i >> 6) & 63;
  int d = i & 63;
  float acc = 0.f;
  for (int b = 0; b < NBASES; ++b)
    acc += att[r * NBASES + b] * bases[b * 4096 + d * 64 + e];
  Wt[i] = (uint16_t)f32_bf16(acc);
}

// ======================================================================
// MAIN PATH: two-phase target-sorted (no output atomics)
// xb (bf16 copy of x, 25.6 MB) lives in the FIRST HALF OF THE OUTPUT BUFFER
// (out is 51.2 MB and dead until phaseB overwrites it).
// ======================================================================
#define MAXTILES 112528
#define MAXRECS  (MAXTILES * 16)
#define WS_CNTR    0          // 32 int
#define WS_RCUR    128        // 32 int
#define WS_RSTART  256        // 32 int (layout compat, unused)
#define WS_GCUR    384        // 1 int
#define WS_WT      512        // 17*64*64 u16 -> ends 139776
#define WS_TILEREL 139776     // MAXTILES u8 -> ends 252304 (pad to 252416)
#define WS_CNTV    252416     // 200000 int
#define WS_VSTART  1052416    // 200000 int
#define WS_VCUR    1852416    // 200000 int
#define WS_RECS    2652416    // MAXRECS int2 -> ends 17056000 (pad to 17056128)
#define WS_MSG     17056128   // MAXRECS * 64 u16 rows
#define WS_TOTAL   (WS_MSG + (size_t)MAXRECS * 128)   // ~247.5 MB

// Fused: Wt prep (blocks 0..272) | zero cntr/rcur/gcur+cntv (273..1054) | x->bf16 (1055..7304)
__global__ __launch_bounds__(256) void k_init(const float* __restrict__ bases,
                                              const float* __restrict__ att,
                                              uint16_t* __restrict__ Wt,
                                              const float* __restrict__ x,
                                              uint16_t* __restrict__ xb,
                                              int* __restrict__ zero0,
                                              int* __restrict__ cntv) {
  int b = blockIdx.x;
  int tid = threadIdx.x;
  if (b < 273) {
    int i = b * 256 + tid;
    if (i < 17 * 64 * 64) {
      int r = i >> 12;
      int e = (i >> 6) & 63;
      int d = i & 63;
      float acc = 0.f;
      for (int bb = 0; bb < NBASES; ++bb)
        acc += att[r * NBASES + bb] * bases[bb * 4096 + d * 64 + e];
      Wt[i] = (uint16_t)f32_bf16(acc);
    }
  } else if (b < 1055) {
    int idx = (b - 273) * 256 + tid;
    if (idx < 128) zero0[idx] = 0;            // cntr/rcur/rstart/gcur region (512 B)
    else if (idx - 128 < N_NODES) cntv[idx - 128] = 0;
  } else {
    int i = (b - 1055) * 256 + tid;           // exact: i < 1,600,000
    const float* xp = x + (size_t)i * 8;
    // x is read exactly once in the whole pipeline -> non-temporal
    float4v q0 = __builtin_nontemporal_load((const float4v*)xp);
    float4v q1 = __builtin_nontemporal_load((const float4v*)(xp + 4));
    short8b o;
    o[0] = f32_bf16(q0[0]); o[1] = f32_bf16(q0[1]); o[2] = f32_bf16(q0[2]); o[3] = f32_bf16(q0[3]);
    o[4] = f32_bf16(q1[0]); o[5] = f32_bf16(q1[1]); o[6] = f32_bf16(q1[2]); o[7] = f32_bf16(q1[3]);
    *(short8b*)(xb + (size_t)i * 8) = o;      // keep cacheable: phaseA re-reads it
  }
}

__global__ __launch_bounds__(256) void k_count(const int* __restrict__ src,
                                               const int* __restrict__ tgt,
                                               const int* __restrict__ et,
                                               const int* __restrict__ mask,
                                               int* __restrict__ cntr,
                                               int* __restrict__ cntv,
                                               int nE, int nN) {
  __shared__ int lh[NREL + 1];
  if (threadIdx.x <= NREL) lh[threadIdx.x] = 0;
  __syncthreads();
  int i = blockIdx.x * 256 + threadIdx.x;
  if (i < nE) {
    atomicAdd(&lh[et[i]], 2);
    atomicAdd(&cntv[tgt[i]], 1);
    atomicAdd(&cntv[src[i]], 1);
  }
  if (i < nN && mask[i]) {
    atomicAdd(&lh[NREL], 1);
    atomicAdd(&cntv[i], 1);
  }
  __syncthreads();
  if (threadIdx.x <= NREL && lh[threadIdx.x])
    atomicAdd(&cntr[threadIdx.x], lh[threadIdx.x]);
}

// Fused bucket-prefix + tileRel + pad-record writes
__global__ __launch_bounds__(256) void k_prep(const int* __restrict__ cntr,
                                              int* __restrict__ rcur,
                                              uint8_t* __restrict__ tileRel,
                                              int2* __restrict__ recs,
                                              int maxTiles) {
  __shared__ int s[NREL + 2];
  if (threadIdx.x == 0) {
    int base = 0;
    for (int r = 0; r <= NREL; ++r) {
      s[r] = base;
      base = (base + cntr[r] + 15) & ~15;
    }
    s[NREL + 1] = base;
  }
  __syncthreads();
  if (blockIdx.x == 0) {
    if (threadIdx.x <= NREL) rcur[threadIdx.x] = s[threadIdx.x];
    for (int w = threadIdx.x; w < (NREL + 1) * 16; w += 256) {
      int r = w >> 4, j = w & 15;
      int pos = s[r] + cntr[r] + j;
      if (pos < s[r + 1]) recs[pos] = make_int2(-1, -1);
    }
  }
  int t = blockIdx.x * 256 + threadIdx.x;
  if (t < maxTiles) {
    int p = t * 16;
    uint8_t rr = 255;
    if (p < s[NREL + 1]) {
      int q = 0;
      for (int k = 1; k <= NREL; ++k)
        if (p >= s[k]) q = k;
      rr = (uint8_t)q;
    }
    tileRel[t] = rr;
  }
}

// per-target contiguous segment allocation; shfl-scan
__global__ __launch_bounds__(256) void k_vseg(const int* __restrict__ cntv,
                                              int* __restrict__ vstart,
                                              int* __restrict__ vcur,
                                              int* __restrict__ gcur, int nN) {
  __shared__ int wsum[4];
  __shared__ int s_base;
  int v = blockIdx.x * 256 + threadIdx.x;
  int lane = threadIdx.x & 63;
  int wid = threadIdx.x >> 6;
  int c = (v < nN) ? cntv[v] : 0;
  int incl = c;
  for (int off = 1; off < 64; off <<= 1) {
    int n = __shfl_up(incl, off, 64);
    if (lane >= off) incl += n;
  }
  if (lane == 63) wsum[wid] = incl;
  __syncthreads();
  if (threadIdx.x == 0) {
    int t0 = wsum[0], t1 = wsum[1], t2 = wsum[2], t3 = wsum[3];
    s_base = atomicAdd(gcur, t0 + t1 + t2 + t3);
    wsum[0] = 0;
    wsum[1] = t0;
    wsum[2] = t0 + t1;
    wsum[3] = t0 + t1 + t2;
  }
  __syncthreads();
  if (v < nN) {
    int st = s_base + wsum[wid] + incl - c;
    vstart[v] = st;
    vcur[v] = st;
  }
}

__global__ __launch_bounds__(256) void k_records(const int* __restrict__ src,
                                                 const int* __restrict__ tgt,
                                                 const int* __restrict__ et,
                                                 const int* __restrict__ mask,
                                                 int2* __restrict__ recs,
                                                 int* __restrict__ rcur,
                                                 int* __restrict__ vcur,
                                                 int nE, int nN) {
  __shared__ int lh[NREL + 1], lbase[NREL + 1];
  if (threadIdx.x <= NREL) lh[threadIdx.x] = 0;
  __syncthreads();
  int i = blockIdx.x * 256 + threadIdx.x;
  bool isE = i < nE;
  bool isN = (i < nN) && mask[i];
  int r = 0, loff = 0, loffN = 0, s_ = 0, t_ = 0;
  if (isE) {
    r = et[i];
    s_ = src[i];
    t_ = tgt[i];
    loff = atomicAdd(&lh[r], 2);
  }
  if (isN) loffN = atomicAdd(&lh[NREL], 1);
  __syncthreads();
  if (threadIdx.x <= NREL)
    lbase[threadIdx.x] = lh[threadIdx.x] ? atomicAdd(&rcur[threadIdx.x], lh[threadIdx.x]) : 0;
  __syncthreads();
  if (isE) {
    int pos = lbase[r] + loff;            // even -> 16B aligned
    int o1 = atomicAdd(&vcur[t_], 1);     // msg (s_ -> t_)
    int o2 = atomicAdd(&vcur[s_], 1);     // msg (t_ -> s_)
    *(int4*)(recs + pos) = make_int4(s_, o1, t_, o2);
  }
  if (isN) {
    int pos = lbase[NREL] + loffN;
    int o = atomicAdd(&vcur[i], 1);
    recs[pos] = make_int2(i, o);
  }
}

// Phase A: relation-grouped MFMA over bf16 x-table; nt-stores for streaming msg.
// LDS is wave-private: in-wave DS ordering + lgkmcnt + sched_barrier (rule #18).
__global__ __launch_bounds__(256) void k_phaseA(const uint16_t* __restrict__ xb,
                                                const int2* __restrict__ recs,
                                                const uint16_t* __restrict__ Wt,
                                                const uint8_t* __restrict__ tileRel,
                                                uint16_t* __restrict__ msg,
                                                int ntiles) {
  __shared__ uint16_t s_m[4][16 * 72];   // +8 elem row pad
  __shared__ int s_slot[4][16];
  const int wid = threadIdx.x >> 6;
  const int lane = threadIdx.x & 63;
  const int quad = lane >> 4;
  const int m16 = lane & 15;
  const int t0 = (blockIdx.x * 4 + wid) * 4;

  if (tileRel[t0] == 255) return;        // wave-uniform tail exit (tileRel monotonic)

  int curRel = -1;
  short8b bfrag[4][2] = {};

  for (int it = 0; it < 4; ++it) {
    int t = t0 + it;
    int rel = (t < ntiles) ? (int)tileRel[t] : 255;
    bool valid = (rel != 255);

    if (valid && rel != curRel) {
      curRel = rel;
      const uint16_t* wbase = Wt + (size_t)rel * 4096;
      for (int nt = 0; nt < 4; ++nt)
        for (int kt = 0; kt < 2; ++kt)
          bfrag[nt][kt] = *(const short8b*)(wbase + (size_t)(nt * 16 + m16) * 64 + kt * 32 + quad * 8);
    }

    // recs are read exactly once -> non-temporal
    int2 rec;
    if (valid) {
      long long rv = __builtin_nontemporal_load((const long long*)(recs + t * 16 + m16));
      rec.x = (int)(rv & 0xFFFFFFFFll);
      rec.y = (int)(rv >> 32);
    } else {
      rec = make_int2(-1, -1);
    }
    int u = rec.x < 0 ? 0 : rec.x;

    const uint16_t* xp = xb + (size_t)u * 64 + quad * 8;
    short8b a0 = *(const short8b*)(xp);
    short8b a1 = *(const short8b*)(xp + 32);

    float4v acc[4];
    for (int nt = 0; nt < 4; ++nt) { acc[nt][0] = 0.f; acc[nt][1] = 0.f; acc[nt][2] = 0.f; acc[nt][3] = 0.f; }
    for (int nt = 0; nt < 4; ++nt) {
      acc[nt] = __builtin_amdgcn_mfma_f32_16x16x32_bf16(a0, bfrag[nt][0], acc[nt], 0, 0, 0);
      acc[nt] = __builtin_amdgcn_mfma_f32_16x16x32_bf16(a1, bfrag[nt][1], acc[nt], 0, 0, 0);
    }

    // C/D: col(dim) = m16 + nt*16, row(message) = quad*4 + reg
    if (quad == 0) s_slot[wid][m16] = rec.y;
    for (int reg = 0; reg < 4; ++reg)
      for (int nt = 0; nt < 4; ++nt)
        s_m[wid][(quad * 4 + reg) * 72 + nt * 16 + m16] = (uint16_t)f32_bf16(acc[nt][reg]);

    asm volatile("s_waitcnt lgkmcnt(0)" ::: "memory");
    __builtin_amdgcn_sched_barrier(0);

    // 16 rows x 128 B, 8 lanes/row x 16 B; msg is write-once streaming -> nt
    for (int p = 0; p < 2; ++p) {
      int row = (lane >> 3) + p * 8;
      int slot = s_slot[wid][row];
      if (slot >= 0) {
        const uint16_t* lp = &s_m[wid][row * 72 + (lane & 7) * 8];
        int4v val = *(const int4v*)lp;
        __builtin_nontemporal_store(val, (int4v*)(msg + (size_t)slot * 64 + (lane & 7) * 8));
      }
    }
    __builtin_amdgcn_sched_barrier(0);   // keep next iter's ds_writes after these reads
  }
}

// Phase B: per-target segmented sum. 8 lanes/target, nt 16 B loads.
__global__ __launch_bounds__(256) void k_phaseB(const uint16_t* __restrict__ msg,
                                                const int* __restrict__ cntv,
                                                const int* __restrict__ vstart,
                                                float* __restrict__ out, int nN) {
  int v = blockIdx.x * 32 + (threadIdx.x >> 3);
  int l = threadIdx.x & 7;
  if (v >= nN) return;
  int cnt = cntv[v];
  int base = vstart[v];
  float a[8] = {0.f, 0.f, 0.f, 0.f, 0.f, 0.f, 0.f, 0.f};
  const uint16_t* mp = msg + (size_t)base * 64 + l * 8;
  int j = 0;
  for (; j + 2 <= cnt; j += 2) {
    int4v r0 = __builtin_nontemporal_load((const int4v*)(mp + (size_t)j * 64));
    int4v r1 = __builtin_nontemporal_load((const int4v*)(mp + (size_t)(j + 1) * 64));
    short8b h0 = __builtin_bit_cast(short8b, r0);
    short8b h1 = __builtin_bit_cast(short8b, r1);
#pragma unroll
    for (int k = 0; k < 8; ++k)
      a[k] += bf2f((uint16_t)h0[k]) + bf2f((uint16_t)h1[k]);
  }
  if (j < cnt) {
    int4v r0 = __builtin_nontemporal_load((const int4v*)(mp + (size_t)j * 64));
    short8b h = __builtin_bit_cast(short8b, r0);
#pragma unroll
    for (int k = 0; k < 8; ++k)
      a[k] += bf2f((uint16_t)h[k]);
  }
  float* op = out + (size_t)v * 64 + l * 8;
  float4v o0, o1;
  o0[0] = a[0]; o0[1] = a[1]; o0[2] = a[2]; o0[3] = a[3];
  o1[0] = a[4]; o1[1] = a[5]; o1[2] = a[6]; o1[3] = a[7];
  __builtin_nontemporal_store(o0, (float4v*)op);
  __builtin_nontemporal_store(o1, (float4v*)(op + 4));
}

// ======================================================================
// FALLBACK PATH (atomic scatter) — used only if ws_size too small
// ======================================================================
#define F_WS_HIST    0
#define F_WS_CURSOR  64
#define F_WS_START   128
#define F_WS_WT      512
#define F_WS_TILEREL 139776
#define F_WS_RECS    262144
#define F_MAXTILES   112520
#define F_MAXRECS    (F_MAXTILES * 16)

__global__ __launch_bounds__(256) void f_hist(const int* __restrict__ et,
                                              int* __restrict__ hist, int nE) {
  __shared__ int lh[NREL];
  if (threadIdx.x < NREL) lh[threadIdx.x] = 0;
  __syncthreads();
  int i = blockIdx.x * 256 + threadIdx.x;
  if (i < nE) atomicAdd(&lh[et[i]], 2);
  __syncthreads();
  if (threadIdx.x < NREL && lh[threadIdx.x] > 0)
    atomicAdd(&hist[threadIdx.x], lh[threadIdx.x]);
}

__global__ __launch_bounds__(256) void f_prefix(const int* __restrict__ hist,
                                                int* __restrict__ cursor,
                                                int* __restrict__ start,
                                                uint8_t* __restrict__ tileRel,
                                                int nN, int maxTiles) {
  __shared__ int s_start[17];
  if (threadIdx.x == 0) {
    int base = nN;
    for (int r = 0; r < NREL; ++r) {
      s_start[r] = base;
      cursor[r] = base;
      start[r] = base;
      base = (base + hist[r] + 15) & ~15;
    }
    s_start[16] = base;
    start[16] = base;
  }
  __syncthreads();
  int endp = s_start[16];
  for (int t = threadIdx.x; t < maxTiles; t += 256) {
    int p = t * 16;
    uint8_t r;
    if (p < nN) r = 16;
    else if (p >= endp) r = 255;
    else {
      int q = 0;
      for (int k = 1; k < NREL; ++k) if (p >= s_start[k]) q = k;
      r = (uint8_t)q;
    }
    tileRel[t] = r;
  }
}

__global__ __launch_bounds__(256) void f_scatter(const int* __restrict__ src,
                                                 const int* __restrict__ tgt,
                                                 const int* __restrict__ et,
                                                 const int* __restrict__ mask,
                                                 int2* __restrict__ recs,
                                                 int* __restrict__ cursor,
                                                 int nE, int nN) {
  __shared__ int lh[NREL];
  __shared__ int lbase[NREL];
  if (threadIdx.x < NREL) lh[threadIdx.x] = 0;
  __syncthreads();
  int i = blockIdx.x * 256 + threadIdx.x;
  int r = 0, loff = 0;
  bool isEdge = (i < nE);
  if (isEdge) {
    r = et[i];
    loff = atomicAdd(&lh[r], 2);
  }
  __syncthreads();
  if (threadIdx.x < NREL)
    lbase[threadIdx.x] = (lh[threadIdx.x] > 0) ? atomicAdd(&cursor[threadIdx.x], lh[threadIdx.x]) : 0;
  __syncthreads();
  if (isEdge) {
    int pos = lbase[r] + loff;
    int s = src[i], t = tgt[i];
    *(int4*)(recs + pos) = make_int4(s, t, t, s);
  }
  if (i < nN) {
    recs[i] = (mask[i] != 0) ? make_int2(i, i) : make_int2(-1, -1);
  }
}

__global__ __launch_bounds__(256) void f_compute(const float* __restrict__ x,
                                                 const int2* __restrict__ recs,
                                                 const uint16_t* __restrict__ Wt,
                                                 const uint8_t* __restrict__ tileRel,
                                                 float* __restrict__ out,
                                                 int ntiles) {
  const int lane = threadIdx.x & 63;
  const int quad = lane >> 4;
  const int m16 = lane & 15;
  const int wave = blockIdx.x * 4 + (threadIdx.x >> 6);
  const int t0 = wave * 4;

  int curRel = -1;
  short8b bfrag[4][2] = {};

  for (int it = 0; it < 4; ++it) {
    int t = t0 + it;
    if (t >= ntiles) return;
    int rel = tileRel[t];
    if (rel == 255) return;

    if (rel != curRel) {
      curRel = rel;
      const uint16_t* wbase = Wt + (size_t)rel * 4096;
      for (int nt = 0; nt < 4; ++nt)
        for (int kt = 0; kt < 2; ++kt)
          bfrag[nt][kt] = *(const short8b*)(wbase + (size_t)(nt * 16 + m16) * 64 + kt * 32 + quad * 8);
    }

    int2 rec = recs[t * 16 + m16];
    int u = rec.x < 0 ? 0 : rec.x;

    const float* xp = x + (size_t)u * 64 + quad * 8;
    float4v q0 = *(const float4v*)(xp);
    float4v q1 = *(const float4v*)(xp + 4);
    float4v q2 = *(const float4v*)(xp + 32);
    float4v q3 = *(const float4v*)(xp + 36);
    short8b a0, a1;
    a0[0] = f32_bf16(q0[0]); a0[1] = f32_bf16(q0[1]); a0[2] = f32_bf16(q0[2]); a0[3] = f32_bf16(q0[3]);
    a0[4] = f32_bf16(q1[0]); a0[5] = f32_bf16(q1[1]); a0[6] = f32_bf16(q1[2]); a0[7] = f32_bf16(q1[3]);
    a1[0] = f32_bf16(q2[0]); a1[1] = f32_bf16(q2[1]); a1[2] = f32_bf16(q2[2]); a1[3] = f32_bf16(q2[3]);
    a1[4] = f32_bf16(q3[0]); a1[5] = f32_bf16(q3[1]); a1[6] = f32_bf16(q3[2]); a1[7] = f32_bf16(q3[3]);

    float4v acc[4];
    for (int nt = 0; nt < 4; ++nt) { acc[nt][0] = 0.f; acc[nt][1] = 0.f; acc[nt][2] = 0.f; acc[nt][3] = 0.f; }
    for (int nt = 0; nt < 4; ++nt) {
      acc[nt] = __builtin_amdgcn_mfma_f32_16x16x32_bf16(a0, bfrag[nt][0], acc[nt], 0, 0, 0);
      acc[nt] = __builtin_amdgcn_mfma_f32_16x16x32_bf16(a1, bfrag[nt][1], acc[nt], 0, 0, 0);
    }

    int tg[4];
    for (int reg = 0; reg < 4; ++reg)
      tg[reg] = __shfl(rec.y, quad * 4 + reg, 64);
    for (int reg = 0; reg < 4; ++reg) {
      if (tg[reg] < 0) continue;
      float* op = out + (size_t)tg[reg] * 64 + m16;
      for (int nt = 0; nt < 4; ++nt)
        __hip_atomic_fetch_add(op + nt * 16, acc[nt][reg], __ATOMIC_RELAXED, __HIP_MEMORY_SCOPE_AGENT);
    }
  }
}

// ======================================================================
extern "C" void kernel_launch(void* const* d_in, const int* in_sizes, int n_in,
                              void* d_out, int out_size, void* d_ws, size_t ws_size,
                              hipStream_t stream) {
  const float* x     = (const float*)d_in[0];
  const int*   mask  = (const int*)d_in[1];
  const int*   src   = (const int*)d_in[2];
  const int*   tgt   = (const int*)d_in[3];
  const int*   et    = (const int*)d_in[4];
  const float* bases = (const float*)d_in[5];
  const float* att   = (const float*)d_in[6];
  float* out = (float*)d_out;
  char* ws = (char*)d_ws;

  if (ws_size >= WS_TOTAL) {
    // ---------- two-phase target-sorted path ----------
    int*      cntr    = (int*)(ws + WS_CNTR);
    int*      rcur    = (int*)(ws + WS_RCUR);
    int*      gcur    = (int*)(ws + WS_GCUR);
    uint16_t* Wt      = (uint16_t*)(ws + WS_WT);
    uint8_t*  tileRel = (uint8_t*)(ws + WS_TILEREL);
    int*      cntv    = (int*)(ws + WS_CNTV);
    int*      vstart  = (int*)(ws + WS_VSTART);
    int*      vcur    = (int*)(ws + WS_VCUR);
    int2*     recs    = (int2*)(ws + WS_RECS);
    uint16_t* msg     = (uint16_t*)(ws + WS_MSG);
    uint16_t* xb      = (uint16_t*)out;   // bf16 x-table in dead output buffer

    k_init<<<7305, 256, 0, stream>>>(bases, att, Wt, x, xb, (int*)ws, cntv);
    k_count<<<(N_EDGES + 255) / 256, 256, 0, stream>>>(src, tgt, et, mask, cntr, cntv, N_EDGES, N_NODES);
    k_prep<<<(MAXTILES + 255) / 256, 256, 0, stream>>>(cntr, rcur, tileRel, recs, MAXTILES);
    k_vseg<<<(N_NODES + 255) / 256, 256, 0, stream>>>(cntv, vstart, vcur, gcur, N_NODES);
    k_records<<<(N_EDGES + 255) / 256, 256, 0, stream>>>(src, tgt, et, mask, recs, rcur, vcur, N_EDGES, N_NODES);
    k_phaseA<<<(MAXTILES + 15) / 16, 256, 0, stream>>>(xb, recs, Wt, tileRel, msg, MAXTILES);
    k_phaseB<<<(N_NODES + 31) / 32, 256, 0, stream>>>(msg, cntv, vstart, out, N_NODES);
  } else {
    // ---------- fallback: atomic path ----------
    int*      hist    = (int*)(ws + F_WS_HIST);
    int*      cursor  = (int*)(ws + F_WS_CURSOR);
    int*      start   = (int*)(ws + F_WS_START);
    uint16_t* Wt      = (uint16_t*)(ws + F_WS_WT);
    uint8_t*  tileRel = (uint8_t*)(ws + F_WS_TILEREL);
    int2*     recs    = (int2*)(ws + F_WS_RECS);

    (void)hipMemsetAsync(out, 0, (size_t)N_NODES * 64 * sizeof(float), stream);
    (void)hipMemsetAsync(ws, 0, 512, stream);
    (void)hipMemsetAsync(recs, 0xFF, (size_t)F_MAXRECS * sizeof(int2), stream);

    k_wprep<<<(17 * 64 * 64 + 255) / 256, 256, 0, stream>>>(bases, att, Wt);
    f_hist<<<(N_EDGES + 255) / 256, 256, 0, stream>>>(et, hist, N_EDGES);
    f_prefix<<<1, 256, 0, stream>>>(hist, cursor, start, tileRel, N_NODES, F_MAXTILES);
    f_scatter<<<(N_EDGES + 255) / 256, 256, 0, stream>>>(src, tgt, et, mask, recs, cursor, N_EDGES, N_NODES);
    f_compute<<<(F_MAXTILES + 15) / 16, 256, 0, stream>>>(x, recs, Wt, tileRel, out, F_MAXTILES);
  }
}

// Round 4
// 351.441 us; speedup vs baseline: 1.3544x; 1.2128x over previous
//
#include <hip/hip_runtime.h>
#include <stdint.h>
#include <stddef.h>

#define N_NODES 200000
#define N_EDGES 800000
#define NREL 16
#define NBASES 8

typedef __attribute__((ext_vector_type(8))) short short8b;
typedef __attribute__((ext_vector_type(4))) float float4v;
typedef __attribute__((ext_vector_type(4))) int int4v;

__device__ __forceinline__ short f32_bf16(float f) {
  uint32_t u = __builtin_bit_cast(uint32_t, f);
  uint32_t r = u + 0x7FFFu + ((u >> 16) & 1u);
  return (short)(uint16_t)(r >> 16);
}
__device__ __forceinline__ float bf2f(uint16_t h) {
  return __builtin_bit_cast(float, (uint32_t)h << 16);
}

// ============================ shared: W table ============================
__global__ __launch_bounds__(256) void k_wprep(const float* __restrict__ bases,
                                               const float* __restrict__ att,
                                               uint16_t* __restrict__ Wt) {
  int i = blockIdx.x * 256 + threadIdx.x;
  if (i >= 17 * 64 * 64) return;
  int r = i >> 12;
  int e = (i >> 6) & 63;
  int d = i & 63;
  float acc = 0.f;
  for (int b = 0; b < NBASES; ++b)
    acc += att[r * NBASES + b] * bases[b * 4096 + d * 64 + e];
  Wt[i] = (uint16_t)f32_bf16(acc);
}

// ======================================================================
// MAIN PATH: two-phase target-sorted (no output atomics)
// xb (bf16 x copy, 25.6 MB) lives in the dead first half of the output buffer.
// Offsets (eoff/noff) live at the head of the msg region: consumed by k_write
// BEFORE phaseA overwrites msg.
// ======================================================================
#define MAXTILES 112528
#define MAXRECS  (MAXTILES * 16)
#define WS_CNTR    0          // 32 int
#define WS_RCUR    128        // 32 int (unused, layout compat)
#define WS_RSTART  256        // 18 int, written by k_prep, read by k_write
#define WS_GCUR    384        // 1 int
#define WS_WT      512        // 17*64*64 u16 -> ends 139776
#define WS_TILEREL 139776     // MAXTILES u8 -> ends 252304 (pad to 252416)
#define WS_CNTV    252416     // 200000 int (edge-only counts)
#define WS_VSTART  1052416    // 200000 int
#define WS_CNTT    1852416    // 200000 int (total counts incl self, by k_vseg)
#define WS_RECS    2652416    // MAXRECS int2 -> ends 17056000 (pad to 17056128)
#define WS_MSG     17056128   // MAXRECS * 64 u16 rows
#define WS_TOTAL   (WS_MSG + (size_t)MAXRECS * 128)   // ~247.5 MB
// transient, inside msg region:
#define OFF_EOFF   WS_MSG                         // 800000 int4 = 12.8 MB
#define OFF_NOFF   (WS_MSG + (size_t)N_EDGES*16)  // 200000 int  = 0.8 MB

// Fused: Wt prep (0..272) | zero cntr/gcur+cntv (273..1054) | x->bf16 (1055..7304)
__global__ __launch_bounds__(256) void k_init(const float* __restrict__ bases,
                                              const float* __restrict__ att,
                                              uint16_t* __restrict__ Wt,
                                              const float* __restrict__ x,
                                              uint16_t* __restrict__ xb,
                                              int* __restrict__ zero0,
                                              int* __restrict__ cntv) {
  int b = blockIdx.x;
  int tid = threadIdx.x;
  if (b < 273) {
    int i = b * 256 + tid;
    if (i < 17 * 64 * 64) {
      int r = i >> 12;
      int e = (i >> 6) & 63;
      int d = i & 63;
      float acc = 0.f;
      for (int bb = 0; bb < NBASES; ++bb)
        acc += att[r * NBASES + bb] * bases[bb * 4096 + d * 64 + e];
      Wt[i] = (uint16_t)f32_bf16(acc);
    }
  } else if (b < 1055) {
    int idx = (b - 273) * 256 + tid;
    if (idx < 128) zero0[idx] = 0;            // cntr/rcur/rstart/gcur region
    else if (idx - 128 < N_NODES) cntv[idx - 128] = 0;
  } else {
    int i = (b - 1055) * 256 + tid;           // exact: i < 1,600,000
    const float* xp = x + (size_t)i * 8;
    float4v q0 = __builtin_nontemporal_load((const float4v*)xp);
    float4v q1 = __builtin_nontemporal_load((const float4v*)(xp + 4));
    short8b o;
    o[0] = f32_bf16(q0[0]); o[1] = f32_bf16(q0[1]); o[2] = f32_bf16(q0[2]); o[3] = f32_bf16(q0[3]);
    o[4] = f32_bf16(q1[0]); o[5] = f32_bf16(q1[1]); o[6] = f32_bf16(q1[2]); o[7] = f32_bf16(q1[3]);
    *(short8b*)(xb + (size_t)i * 8) = o;      // cacheable: phaseA re-reads it
  }
}

// The ONLY scattered-atomic pass. Saves returned offsets so no later pass
// needs atomics: eoff[i] = (relofs_in_bucket, o1, o2, -), noff[i] = relofs.
// Self-loop slot is deterministic (last in segment) -> no node atomics.
__global__ __launch_bounds__(256) void k_count(const int* __restrict__ src,
                                               const int* __restrict__ tgt,
                                               const int* __restrict__ et,
                                               const int* __restrict__ mask,
                                               int* __restrict__ cntr,
                                               int* __restrict__ cntv,
                                               int4* __restrict__ eoff,
                                               int* __restrict__ noff,
                                               int nE, int nN) {
  __shared__ int lh[NREL + 1], lbase[NREL + 1];
  if (threadIdx.x <= NREL) lh[threadIdx.x] = 0;
  __syncthreads();
  int i = blockIdx.x * 256 + threadIdx.x;
  bool isE = i < nE;
  bool isN = (i < nN) && mask[i];
  int r = 0, loff = 0, loffN = 0, o1 = 0, o2 = 0;
  if (isE) {
    r = et[i];
    loff = atomicAdd(&lh[r], 2);
    o1 = atomicAdd(&cntv[tgt[i]], 1);      // scattered, device scope
    o2 = atomicAdd(&cntv[src[i]], 1);
  }
  if (isN) loffN = atomicAdd(&lh[NREL], 1);
  __syncthreads();
  if (threadIdx.x <= NREL)
    lbase[threadIdx.x] = lh[threadIdx.x] ? atomicAdd(&cntr[threadIdx.x], lh[threadIdx.x]) : 0;
  __syncthreads();
  if (isE) {
    int4v v; v[0] = lbase[r] + loff; v[1] = o1; v[2] = o2; v[3] = 0;
    __builtin_nontemporal_store(v, (int4v*)(eoff + i));
  }
  if (isN) __builtin_nontemporal_store(lbase[NREL] + loffN, noff + i);
}

// Fused bucket-prefix + publish rstart + tileRel + pad-record writes
__global__ __launch_bounds__(256) void k_prep(const int* __restrict__ cntr,
                                              int* __restrict__ rstart_g,
                                              uint8_t* __restrict__ tileRel,
                                              int2* __restrict__ recs,
                                              int maxTiles) {
  __shared__ int s[NREL + 2];
  if (threadIdx.x == 0) {
    int base = 0;
    for (int r = 0; r <= NREL; ++r) {
      s[r] = base;
      base = (base + cntr[r] + 15) & ~15;
    }
    s[NREL + 1] = base;
  }
  __syncthreads();
  if (blockIdx.x == 0) {
    if (threadIdx.x <= NREL + 1) rstart_g[threadIdx.x] = s[threadIdx.x];
    for (int w = threadIdx.x; w < (NREL + 1) * 16; w += 256) {
      int r = w >> 4, j = w & 15;
      int pos = s[r] + cntr[r] + j;
      if (pos < s[r + 1]) recs[pos] = make_int2(-1, -1);
    }
  }
  int t = blockIdx.x * 256 + threadIdx.x;
  if (t < maxTiles) {
    int p = t * 16;
    uint8_t rr = 255;
    if (p < s[NREL + 1]) {
      int q = 0;
      for (int k = 1; k <= NREL; ++k)
        if (p >= s[k]) q = k;
      rr = (uint8_t)q;
    }
    tileRel[t] = rr;
  }
}

// per-target contiguous segments; total count = edge count + self (mask)
__global__ __launch_bounds__(256) void k_vseg(const int* __restrict__ cntv,
                                              const int* __restrict__ mask,
                                              int* __restrict__ vstart,
                                              int* __restrict__ cntt,
                                              int* __restrict__ gcur, int nN) {
  __shared__ int wsum[4];
  __shared__ int s_base;
  int v = blockIdx.x * 256 + threadIdx.x;
  int lane = threadIdx.x & 63;
  int wid = threadIdx.x >> 6;
  int c = 0;
  if (v < nN) c = cntv[v] + (mask[v] ? 1 : 0);
  int incl = c;
  for (int off = 1; off < 64; off <<= 1) {
    int n = __shfl_up(incl, off, 64);
    if (lane >= off) incl += n;
  }
  if (lane == 63) wsum[wid] = incl;
  __syncthreads();
  if (threadIdx.x == 0) {
    int t0 = wsum[0], t1 = wsum[1], t2 = wsum[2], t3 = wsum[3];
    s_base = atomicAdd(gcur, t0 + t1 + t2 + t3);
    wsum[0] = 0;
    wsum[1] = t0;
    wsum[2] = t0 + t1;
    wsum[3] = t0 + t1 + t2;
  }
  __syncthreads();
  if (v < nN) {
    vstart[v] = s_base + wsum[wid] + incl - c;
    cntt[v] = c;
  }
}

// Record construction: ZERO atomics. Positions/slots fully determined by
// saved offsets + scans. Pure streaming + L2 gathers of vstart.
__global__ __launch_bounds__(256) void k_write(const int* __restrict__ src,
                                               const int* __restrict__ tgt,
                                               const int* __restrict__ et,
                                               const int* __restrict__ mask,
                                               const int4* __restrict__ eoff,
                                               const int* __restrict__ noff,
                                               const int* __restrict__ rstart,
                                               const int* __restrict__ cntv,
                                               const int* __restrict__ vstart,
                                               int2* __restrict__ recs,
                                               int nE, int nN) {
  __shared__ int s_rs[NREL + 1];
  if (threadIdx.x <= NREL) s_rs[threadIdx.x] = rstart[threadIdx.x];
  __syncthreads();
  int i = blockIdx.x * 256 + threadIdx.x;
  if (i < nE) {
    int r = et[i];
    int4v e = __builtin_nontemporal_load((const int4v*)(eoff + i));
    int s_ = src[i], t_ = tgt[i];
    int pos = s_rs[r] + e[0];                 // even -> 16B aligned
    int s1 = vstart[t_] + e[1];               // msg (s_ -> t_)
    int s2 = vstart[s_] + e[2];               // msg (t_ -> s_)
    *(int4*)(recs + pos) = make_int4(s_, s1, t_, s2);
  }
  if (i < nN && mask[i]) {
    int pos = s_rs[NREL] + noff[i];
    int slot = vstart[i] + cntv[i];           // self takes the last slot
    recs[pos] = make_int2(i, slot);
  }
}

// Phase A: relation-grouped MFMA over bf16 x-table; nt-stores for streaming msg.
// LDS is wave-private: in-wave DS ordering + lgkmcnt + sched_barrier (rule #18).
__global__ __launch_bounds__(256) void k_phaseA(const uint16_t* __restrict__ xb,
                                                const int2* __restrict__ recs,
                                                const uint16_t* __restrict__ Wt,
                                                const uint8_t* __restrict__ tileRel,
                                                uint16_t* __restrict__ msg,
                                                int ntiles) {
  __shared__ uint16_t s_m[4][16 * 72];   // +8 elem row pad
  __shared__ int s_slot[4][16];
  const int wid = threadIdx.x >> 6;
  const int lane = threadIdx.x & 63;
  const int quad = lane >> 4;
  const int m16 = lane & 15;
  const int t0 = (blockIdx.x * 4 + wid) * 4;

  if (tileRel[t0] == 255) return;        // wave-uniform tail exit (tileRel monotonic)

  int curRel = -1;
  short8b bfrag[4][2] = {};

  for (int it = 0; it < 4; ++it) {
    int t = t0 + it;
    int rel = (t < ntiles) ? (int)tileRel[t] : 255;
    bool valid = (rel != 255);

    if (valid && rel != curRel) {
      curRel = rel;
      const uint16_t* wbase = Wt + (size_t)rel * 4096;
      for (int nt = 0; nt < 4; ++nt)
        for (int kt = 0; kt < 2; ++kt)
          bfrag[nt][kt] = *(const short8b*)(wbase + (size_t)(nt * 16 + m16) * 64 + kt * 32 + quad * 8);
    }

    int2 rec;
    if (valid) {
      long long rv = __builtin_nontemporal_load((const long long*)(recs + t * 16 + m16));
      rec.x = (int)(rv & 0xFFFFFFFFll);
      rec.y = (int)(rv >> 32);
    } else {
      rec = make_int2(-1, -1);
    }
    int u = rec.x < 0 ? 0 : rec.x;

    const uint16_t* xp = xb + (size_t)u * 64 + quad * 8;
    short8b a0 = *(const short8b*)(xp);
    short8b a1 = *(const short8b*)(xp + 32);

    float4v acc[4];
    for (int nt = 0; nt < 4; ++nt) { acc[nt][0] = 0.f; acc[nt][1] = 0.f; acc[nt][2] = 0.f; acc[nt][3] = 0.f; }
    for (int nt = 0; nt < 4; ++nt) {
      acc[nt] = __builtin_amdgcn_mfma_f32_16x16x32_bf16(a0, bfrag[nt][0], acc[nt], 0, 0, 0);
      acc[nt] = __builtin_amdgcn_mfma_f32_16x16x32_bf16(a1, bfrag[nt][1], acc[nt], 0, 0, 0);
    }

    // C/D: col(dim) = m16 + nt*16, row(message) = quad*4 + reg
    if (quad == 0) s_slot[wid][m16] = rec.y;
    for (int reg = 0; reg < 4; ++reg)
      for (int nt = 0; nt < 4; ++nt)
        s_m[wid][(quad * 4 + reg) * 72 + nt * 16 + m16] = (uint16_t)f32_bf16(acc[nt][reg]);

    asm volatile("s_waitcnt lgkmcnt(0)" ::: "memory");
    __builtin_amdgcn_sched_barrier(0);

    // 16 rows x 128 B, 8 lanes/row x 16 B; msg is write-once streaming -> nt
    for (int p = 0; p < 2; ++p) {
      int row = (lane >> 3) + p * 8;
      int slot = s_slot[wid][row];
      if (slot >= 0) {
        const uint16_t* lp = &s_m[wid][row * 72 + (lane & 7) * 8];
        int4v val = *(const int4v*)lp;
        __builtin_nontemporal_store(val, (int4v*)(msg + (size_t)slot * 64 + (lane & 7) * 8));
      }
    }
    __builtin_amdgcn_sched_barrier(0);   // keep next iter's ds_writes after these reads
  }
}

// Phase B: per-target segmented sum. 8 lanes/target, nt 16 B loads.
__global__ __launch_bounds__(256) void k_phaseB(const uint16_t* __restrict__ msg,
                                                const int* __restrict__ cntt,
                                                const int* __restrict__ vstart,
                                                float* __restrict__ out, int nN) {
  int v = blockIdx.x * 32 + (threadIdx.x >> 3);
  int l = threadIdx.x & 7;
  if (v >= nN) return;
  int cnt = cntt[v];
  int base = vstart[v];
  float a[8] = {0.f, 0.f, 0.f, 0.f, 0.f, 0.f, 0.f, 0.f};
  const uint16_t* mp = msg + (size_t)base * 64 + l * 8;
  int j = 0;
  for (; j + 2 <= cnt; j += 2) {
    int4v r0 = __builtin_nontemporal_load((const int4v*)(mp + (size_t)j * 64));
    int4v r1 = __builtin_nontemporal_load((const int4v*)(mp + (size_t)(j + 1) * 64));
    short8b h0 = __builtin_bit_cast(short8b, r0);
    short8b h1 = __builtin_bit_cast(short8b, r1);
#pragma unroll
    for (int k = 0; k < 8; ++k)
      a[k] += bf2f((uint16_t)h0[k]) + bf2f((uint16_t)h1[k]);
  }
  if (j < cnt) {
    int4v r0 = __builtin_nontemporal_load((const int4v*)(mp + (size_t)j * 64));
    short8b h = __builtin_bit_cast(short8b, r0);
#pragma unroll
    for (int k = 0; k < 8; ++k)
      a[k] += bf2f((uint16_t)h[k]);
  }
  float* op = out + (size_t)v * 64 + l * 8;
  float4v o0, o1;
  o0[0] = a[0]; o0[1] = a[1]; o0[2] = a[2]; o0[3] = a[3];
  o1[0] = a[4]; o1[1] = a[5]; o1[2] = a[6]; o1[3] = a[7];
  __builtin_nontemporal_store(o0, (float4v*)op);
  __builtin_nontemporal_store(o1, (float4v*)(op + 4));
}

// ======================================================================
// FALLBACK PATH (atomic scatter) — used only if ws_size too small
// ======================================================================
#define F_WS_HIST    0
#define F_WS_CURSOR  64
#define F_WS_START   128
#define F_WS_WT      512
#define F_WS_TILEREL 139776
#define F_WS_RECS    262144
#define F_MAXTILES   112520
#define F_MAXRECS    (F_MAXTILES * 16)

__global__ __launch_bounds__(256) void f_hist(const int* __restrict__ et,
                                              int* __restrict__ hist, int nE) {
  __shared__ int lh[NREL];
  if (threadIdx.x < NREL) lh[threadIdx.x] = 0;
  __syncthreads();
  int i = blockIdx.x * 256 + threadIdx.x;
  if (i < nE) atomicAdd(&lh[et[i]], 2);
  __syncthreads();
  if (threadIdx.x < NREL && lh[threadIdx.x] > 0)
    atomicAdd(&hist[threadIdx.x], lh[threadIdx.x]);
}

__global__ __launch_bounds__(256) void f_prefix(const int* __restrict__ hist,
                                                int* __restrict__ cursor,
                                                int* __restrict__ start,
                                                uint8_t* __restrict__ tileRel,
                                                int nN, int maxTiles) {
  __shared__ int s_start[17];
  if (threadIdx.x == 0) {
    int base = nN;
    for (int r = 0; r < NREL; ++r) {
      s_start[r] = base;
      cursor[r] = base;
      start[r] = base;
      base = (base + hist[r] + 15) & ~15;
    }
    s_start[16] = base;
    start[16] = base;
  }
  __syncthreads();
  int endp = s_start[16];
  for (int t = threadIdx.x; t < maxTiles; t += 256) {
    int p = t * 16;
    uint8_t r;
    if (p < nN) r = 16;
    else if (p >= endp) r = 255;
    else {
      int q = 0;
      for (int k = 1; k < NREL; ++k) if (p >= s_start[k]) q = k;
      r = (uint8_t)q;
    }
    tileRel[t] = r;
  }
}

__global__ __launch_bounds__(256) void f_scatter(const int* __restrict__ src,
                                                 const int* __restrict__ tgt,
                                                 const int* __restrict__ et,
                                                 const int* __restrict__ mask,
                                                 int2* __restrict__ recs,
                                                 int* __restrict__ cursor,
                                                 int nE, int nN) {
  __shared__ int lh[NREL];
  __shared__ int lbase[NREL];
  if (threadIdx.x < NREL) lh[threadIdx.x] = 0;
  __syncthreads();
  int i = blockIdx.x * 256 + threadIdx.x;
  int r = 0, loff = 0;
  bool isEdge = (i < nE);
  if (isEdge) {
    r = et[i];
    loff = atomicAdd(&lh[r], 2);
  }
  __syncthreads();
  if (threadIdx.x < NREL)
    lbase[threadIdx.x] = (lh[threadIdx.x] > 0) ? atomicAdd(&cursor[threadIdx.x], lh[threadIdx.x]) : 0;
  __syncthreads();
  if (isEdge) {
    int pos = lbase[r] + loff;
    int s = src[i], t = tgt[i];
    *(int4*)(recs + pos) = make_int4(s, t, t, s);
  }
  if (i < nN) {
    recs[i] = (mask[i] != 0) ? make_int2(i, i) : make_int2(-1, -1);
  }
}

__global__ __launch_bounds__(256) void f_compute(const float* __restrict__ x,
                                                 const int2* __restrict__ recs,
                                                 const uint16_t* __restrict__ Wt,
                                                 const uint8_t* __restrict__ tileRel,
                                                 float* __restrict__ out,
                                                 int ntiles) {
  const int lane = threadIdx.x & 63;
  const int quad = lane >> 4;
  const int m16 = lane & 15;
  const int wave = blockIdx.x * 4 + (threadIdx.x >> 6);
  const int t0 = wave * 4;

  int curRel = -1;
  short8b bfrag[4][2] = {};

  for (int it = 0; it < 4; ++it) {
    int t = t0 + it;
    if (t >= ntiles) return;
    int rel = tileRel[t];
    if (rel == 255) return;

    if (rel != curRel) {
      curRel = rel;
      const uint16_t* wbase = Wt + (size_t)rel * 4096;
      for (int nt = 0; nt < 4; ++nt)
        for (int kt = 0; kt < 2; ++kt)
          bfrag[nt][kt] = *(const short8b*)(wbase + (size_t)(nt * 16 + m16) * 64 + kt * 32 + quad * 8);
    }

    int2 rec = recs[t * 16 + m16];
    int u = rec.x < 0 ? 0 : rec.x;

    const float* xp = x + (size_t)u * 64 + quad * 8;
    float4v q0 = *(const float4v*)(xp);
    float4v q1 = *(const float4v*)(xp + 4);
    float4v q2 = *(const float4v*)(xp + 32);
    float4v q3 = *(const float4v*)(xp + 36);
    short8b a0, a1;
    a0[0] = f32_bf16(q0[0]); a0[1] = f32_bf16(q0[1]); a0[2] = f32_bf16(q0[2]); a0[3] = f32_bf16(q0[3]);
    a0[4] = f32_bf16(q1[0]); a0[5] = f32_bf16(q1[1]); a0[6] = f32_bf16(q1[2]); a0[7] = f32_bf16(q1[3]);
    a1[0] = f32_bf16(q2[0]); a1[1] = f32_bf16(q2[1]); a1[2] = f32_bf16(q2[2]); a1[3] = f32_bf16(q2[3]);
    a1[4] = f32_bf16(q3[0]); a1[5] = f32_bf16(q3[1]); a1[6] = f32_bf16(q3[2]); a1[7] = f32_bf16(q3[3]);

    float4v acc[4];
    for (int nt = 0; nt < 4; ++nt) { acc[nt][0] = 0.f; acc[nt][1] = 0.f; acc[nt][2] = 0.f; acc[nt][3] = 0.f; }
    for (int nt = 0; nt < 4; ++nt) {
      acc[nt] = __builtin_amdgcn_mfma_f32_16x16x32_bf16(a0, bfrag[nt][0], acc[nt], 0, 0, 0);
      acc[nt] = __builtin_amdgcn_mfma_f32_16x16x32_bf16(a1, bfrag[nt][1], acc[nt], 0, 0, 0);
    }

    int tg[4];
    for (int reg = 0; reg < 4; ++reg)
      tg[reg] = __shfl(rec.y, quad * 4 + reg, 64);
    for (int reg = 0; reg < 4; ++reg) {
      if (tg[reg] < 0) continue;
      float* op = out + (size_t)tg[reg] * 64 + m16;
      for (int nt = 0; nt < 4; ++nt)
        __hip_atomic_fetch_add(op + nt * 16, acc[nt][reg], __ATOMIC_RELAXED, __HIP_MEMORY_SCOPE_AGENT);
    }
  }
}

// ======================================================================
extern "C" void kernel_launch(void* const* d_in, const int* in_sizes, int n_in,
                              void* d_out, int out_size, void* d_ws, size_t ws_size,
                              hipStream_t stream) {
  const float* x     = (const float*)d_in[0];
  const int*   mask  = (const int*)d_in[1];
  const int*   src   = (const int*)d_in[2];
  const int*   tgt   = (const int*)d_in[3];
  const int*   et    = (const int*)d_in[4];
  const float* bases = (const float*)d_in[5];
  const float* att   = (const float*)d_in[6];
  float* out = (float*)d_out;
  char* ws = (char*)d_ws;

  if (ws_size >= WS_TOTAL) {
    // ---------- two-phase target-sorted path ----------
    int*      cntr    = (int*)(ws + WS_CNTR);
    int*      rstart  = (int*)(ws + WS_RSTART);
    int*      gcur    = (int*)(ws + WS_GCUR);
    uint16_t* Wt      = (uint16_t*)(ws + WS_WT);
    uint8_t*  tileRel = (uint8_t*)(ws + WS_TILEREL);
    int*      cntv    = (int*)(ws + WS_CNTV);
    int*      vstart  = (int*)(ws + WS_VSTART);
    int*      cntt    = (int*)(ws + WS_CNTT);
    int2*     recs    = (int2*)(ws + WS_RECS);
    uint16_t* msg     = (uint16_t*)(ws + WS_MSG);
    int4*     eoff    = (int4*)(ws + OFF_EOFF);   // transient, inside msg
    int*      noff    = (int*)(ws + OFF_NOFF);    // transient, inside msg
    uint16_t* xb      = (uint16_t*)out;           // bf16 x-table in dead output

    k_init<<<7305, 256, 0, stream>>>(bases, att, Wt, x, xb, (int*)ws, cntv);
    k_count<<<(N_EDGES + 255) / 256, 256, 0, stream>>>(src, tgt, et, mask, cntr, cntv, eoff, noff, N_EDGES, N_NODES);
    k_prep<<<(MAXTILES + 255) / 256, 256, 0, stream>>>(cntr, rstart, tileRel, recs, MAXTILES);
    k_vseg<<<(N_NODES + 255) / 256, 256, 0, stream>>>(cntv, mask, vstart, cntt, gcur, N_NODES);
    k_write<<<(N_EDGES + 255) / 256, 256, 0, stream>>>(src, tgt, et, mask, eoff, noff, rstart, cntv, vstart, recs, N_EDGES, N_NODES);
    k_phaseA<<<(MAXTILES + 15) / 16, 256, 0, stream>>>(xb, recs, Wt, tileRel, msg, MAXTILES);
    k_phaseB<<<(N_NODES + 31) / 32, 256, 0, stream>>>(msg, cntt, vstart, out, N_NODES);
  } else {
    // ---------- fallback: atomic path ----------
    int*      hist    = (int*)(ws + F_WS_HIST);
    int*      cursor  = (int*)(ws + F_WS_CURSOR);
    int*      start   = (int*)(ws + F_WS_START);
    uint16_t* Wt      = (uint16_t*)(ws + F_WS_WT);
    uint8_t*  tileRel = (uint8_t*)(ws + F_WS_TILEREL);
    int2*     recs    = (int2*)(ws + F_WS_RECS);

    (void)hipMemsetAsync(out, 0, (size_t)N_NODES * 64 * sizeof(float), stream);
    (void)hipMemsetAsync(ws, 0, 512, stream);
    (void)hipMemsetAsync(recs, 0xFF, (size_t)F_MAXRECS * sizeof(int2), stream);

    k_wprep<<<(17 * 64 * 64 + 255) / 256, 256, 0, stream>>>(bases, att, Wt);
    f_hist<<<(N_EDGES + 255) / 256, 256, 0, stream>>>(et, hist, N_EDGES);
    f_prefix<<<1, 256, 0, stream>>>(hist, cursor, start, tileRel, N_NODES, F_MAXTILES);
    f_scatter<<<(N_EDGES + 255) / 256, 256, 0, stream>>>(src, tgt, et, mask, recs, cursor, N_EDGES, N_NODES);
    f_compute<<<(F_MAXTILES + 15) / 16, 256, 0, stream>>>(x, recs, Wt, tileRel, out, F_MAXTILES);
  }
}

// Round 5
// 345.479 us; speedup vs baseline: 1.3778x; 1.0173x over previous
//
#include <hip/hip_runtime.h>
#include <hip/hip_bf16.h>
#include <stdint.h>
#include <stddef.h>

#define N_NODES 200000
#define N_EDGES 800000
#define NREL 16
#define NBASES 8

typedef __attribute__((ext_vector_type(8))) short short8b;
typedef __attribute__((ext_vector_type(4))) float float4v;
typedef __attribute__((ext_vector_type(4))) int int4v;

__device__ __forceinline__ short f32_bf16(float f) {
  uint32_t u = __builtin_bit_cast(uint32_t, f);
  uint32_t r = u + 0x7FFFu + ((u >> 16) & 1u);
  return (short)(uint16_t)(r >> 16);
}
// hardware RNE conversion (gfx950 v_cvt_pk_bf16_f32); same rounding as above
__device__ __forceinline__ uint16_t f32_bf16_hw(float f) {
  __hip_bfloat16 h = __float2bfloat16(f);
  return __builtin_bit_cast(uint16_t, h);
}
__device__ __forceinline__ float bf2f(uint16_t h) {
  return __builtin_bit_cast(float, (uint32_t)h << 16);
}

// ============================ shared: W table ============================
__global__ __launch_bounds__(256) void k_wprep(const float* __restrict__ bases,
                                               const float* __restrict__ att,
                                               uint16_t* __restrict__ Wt) {
  int i = blockIdx.x * 256 + threadIdx.x;
  if (i >= 17 * 64 * 64) return;
  int r = i >> 12;
  int e = (i >> 6) & 63;
  int d = i & 63;
  float acc = 0.f;
  for (int b = 0; b < NBASES; ++b)
    acc += att[r * NBASES + b] * bases[b * 4096 + d * 64 + e];
  Wt[i] = (uint16_t)f32_bf16(acc);
}

// ======================================================================
// MAIN PATH: two-phase target-sorted (no output atomics)
// xb (bf16 x copy, 25.6 MB) lives in the dead first half of the output buffer.
// Offsets (eoff/noff) live at the head of the msg region: consumed by k_write
// BEFORE phaseA overwrites msg.
// ======================================================================
#define MAXTILES 112528
#define MAXRECS  (MAXTILES * 16)
#define WS_CNTR    0          // 32 int
#define WS_RCUR    128        // 32 int (unused, layout compat)
#define WS_RSTART  256        // 18 int, written by k_scan, read by k_write
#define WS_GCUR    384        // 1 int
#define WS_WT      512        // 17*64*64 u16 -> ends 139776
#define WS_TILEREL 139776     // MAXTILES u8 -> ends 252304 (pad to 252416)
#define WS_CNTV    252416     // 200000 int (edge-only counts)
#define WS_VSTART  1052416    // 200000 int
#define WS_CNTT    1852416    // 200000 int (total counts incl self)
#define WS_RECS    2652416    // MAXRECS int2 -> ends 17056000 (pad to 17056128)
#define WS_MSG     17056128   // MAXRECS * 64 u16 rows
#define WS_TOTAL   (WS_MSG + (size_t)MAXRECS * 128)   // ~247.5 MB
// transient, inside msg region:
#define OFF_EOFF   WS_MSG                         // 800000 int4 = 12.8 MB
#define OFF_NOFF   (WS_MSG + (size_t)N_EDGES*16)  // 200000 int  = 0.8 MB

// Fused: Wt prep (0..272) | zero cntr/gcur + cntv (273..1054)
__global__ __launch_bounds__(256) void k_init(const float* __restrict__ bases,
                                              const float* __restrict__ att,
                                              uint16_t* __restrict__ Wt,
                                              int* __restrict__ zero0,
                                              int* __restrict__ cntv) {
  int b = blockIdx.x;
  int tid = threadIdx.x;
  if (b < 273) {
    int i = b * 256 + tid;
    if (i < 17 * 64 * 64) {
      int r = i >> 12;
      int e = (i >> 6) & 63;
      int d = i & 63;
      float acc = 0.f;
      for (int bb = 0; bb < NBASES; ++bb)
        acc += att[r * NBASES + bb] * bases[bb * 4096 + d * 64 + e];
      Wt[i] = (uint16_t)f32_bf16(acc);
    }
  } else {
    int idx = (b - 273) * 256 + tid;
    if (idx < 128) zero0[idx] = 0;            // cntr/rcur/rstart/gcur region
    else if (idx - 128 < N_NODES) cntv[idx - 128] = 0;
  }
}

// Fused: scattered-atomic count pass (blocks 0..3124) + x->bf16 cast
// (blocks 3125..9374). The cast is streaming-bound; the count is
// atomic-latency-bound at <10% HBM -> co-residency hides the cast.
#define CNT_BLOCKS  3125
#define CAST_BLOCKS 6250
__global__ __launch_bounds__(256) void k_count(const int* __restrict__ src,
                                               const int* __restrict__ tgt,
                                               const int* __restrict__ et,
                                               const int* __restrict__ mask,
                                               int* __restrict__ cntr,
                                               int* __restrict__ cntv,
                                               int4* __restrict__ eoff,
                                               int* __restrict__ noff,
                                               const float* __restrict__ x,
                                               uint16_t* __restrict__ xb,
                                               int nE, int nN) {
  int b = blockIdx.x;
  if (b >= CNT_BLOCKS) {
    int i = (b - CNT_BLOCKS) * 256 + threadIdx.x;   // exact: i < 1,600,000
    const float* xp = x + (size_t)i * 8;
    float4v q0 = __builtin_nontemporal_load((const float4v*)xp);
    float4v q1 = __builtin_nontemporal_load((const float4v*)(xp + 4));
    short8b o;
    o[0] = f32_bf16_hw(q0[0]); o[1] = f32_bf16_hw(q0[1]); o[2] = f32_bf16_hw(q0[2]); o[3] = f32_bf16_hw(q0[3]);
    o[4] = f32_bf16_hw(q1[0]); o[5] = f32_bf16_hw(q1[1]); o[6] = f32_bf16_hw(q1[2]); o[7] = f32_bf16_hw(q1[3]);
    *(short8b*)(xb + (size_t)i * 8) = o;      // cacheable: phaseA re-reads it
    return;
  }
  __shared__ int lh[NREL + 1], lbase[NREL + 1];
  if (threadIdx.x <= NREL) lh[threadIdx.x] = 0;
  __syncthreads();
  int i = b * 256 + threadIdx.x;
  bool isE = i < nE;
  bool isN = (i < nN) && mask[i];
  int r = 0, loff = 0, loffN = 0, o1 = 0, o2 = 0;
  if (isE) {
    r = et[i];
    loff = atomicAdd(&lh[r], 2);
    o1 = atomicAdd(&cntv[tgt[i]], 1);      // scattered, device scope
    o2 = atomicAdd(&cntv[src[i]], 1);
  }
  if (isN) loffN = atomicAdd(&lh[NREL], 1);
  __syncthreads();
  if (threadIdx.x <= NREL)
    lbase[threadIdx.x] = lh[threadIdx.x] ? atomicAdd(&cntr[threadIdx.x], lh[threadIdx.x]) : 0;
  __syncthreads();
  if (isE) {
    int4v v; v[0] = lbase[r] + loff; v[1] = o1; v[2] = o2; v[3] = 0;
    __builtin_nontemporal_store(v, (int4v*)(eoff + i));
  }
  if (isN) __builtin_nontemporal_store(lbase[NREL] + loffN, noff + i);
}

// Fused: bucket-prefix + rstart publish + tileRel + pad-records (blocks 0..439)
// and per-target segment scan (blocks 440..1221). Both depend only on k_count.
#define PREP_BLOCKS 440
#define VSEG_BLOCKS 782
__global__ __launch_bounds__(256) void k_scan(const int* __restrict__ cntr,
                                              int* __restrict__ rstart_g,
                                              uint8_t* __restrict__ tileRel,
                                              int2* __restrict__ recs,
                                              const int* __restrict__ cntv,
                                              const int* __restrict__ mask,
                                              int* __restrict__ vstart,
                                              int* __restrict__ cntt,
                                              int* __restrict__ gcur,
                                              int maxTiles, int nN) {
  int b = blockIdx.x;
  if (b < PREP_BLOCKS) {
    __shared__ int s[NREL + 2];
    if (threadIdx.x == 0) {
      int base = 0;
      for (int r = 0; r <= NREL; ++r) {
        s[r] = base;
        base = (base + cntr[r] + 15) & ~15;
      }
      s[NREL + 1] = base;
    }
    __syncthreads();
    if (b == 0) {
      if (threadIdx.x <= NREL + 1) rstart_g[threadIdx.x] = s[threadIdx.x];
      for (int w = threadIdx.x; w < (NREL + 1) * 16; w += 256) {
        int r = w >> 4, j = w & 15;
        int pos = s[r] + cntr[r] + j;
        if (pos < s[r + 1]) recs[pos] = make_int2(-1, -1);
      }
    }
    int t = b * 256 + threadIdx.x;
    if (t < maxTiles) {
      int p = t * 16;
      uint8_t rr = 255;
      if (p < s[NREL + 1]) {
        int q = 0;
        for (int k = 1; k <= NREL; ++k)
          if (p >= s[k]) q = k;
        rr = (uint8_t)q;
      }
      tileRel[t] = rr;
    }
  } else {
    __shared__ int wsum[4];
    __shared__ int s_base;
    int v = (b - PREP_BLOCKS) * 256 + threadIdx.x;
    int lane = threadIdx.x & 63;
    int wid = threadIdx.x >> 6;
    int c = 0;
    if (v < nN) c = cntv[v] + (mask[v] ? 1 : 0);
    int incl = c;
    for (int off = 1; off < 64; off <<= 1) {
      int n = __shfl_up(incl, off, 64);
      if (lane >= off) incl += n;
    }
    if (lane == 63) wsum[wid] = incl;
    __syncthreads();
    if (threadIdx.x == 0) {
      int t0 = wsum[0], t1 = wsum[1], t2 = wsum[2], t3 = wsum[3];
      s_base = atomicAdd(gcur, t0 + t1 + t2 + t3);
      wsum[0] = 0;
      wsum[1] = t0;
      wsum[2] = t0 + t1;
      wsum[3] = t0 + t1 + t2;
    }
    __syncthreads();
    if (v < nN) {
      vstart[v] = s_base + wsum[wid] + incl - c;
      cntt[v] = c;
    }
  }
}

// Record construction: ZERO atomics. Positions/slots fully determined by
// saved offsets + scans. Pure streaming + L2 gathers of vstart.
__global__ __launch_bounds__(256) void k_write(const int* __restrict__ src,
                                               const int* __restrict__ tgt,
                                               const int* __restrict__ et,
                                               const int* __restrict__ mask,
                                               const int4* __restrict__ eoff,
                                               const int* __restrict__ noff,
                                               const int* __restrict__ rstart,
                                               const int* __restrict__ cntv,
                                               const int* __restrict__ vstart,
                                               int2* __restrict__ recs,
                                               int nE, int nN) {
  __shared__ int s_rs[NREL + 1];
  if (threadIdx.x <= NREL) s_rs[threadIdx.x] = rstart[threadIdx.x];
  __syncthreads();
  int i = blockIdx.x * 256 + threadIdx.x;
  if (i < nE) {
    int r = et[i];
    int4v e = __builtin_nontemporal_load((const int4v*)(eoff + i));
    int s_ = src[i], t_ = tgt[i];
    int pos = s_rs[r] + e[0];                 // even -> 16B aligned
    int s1 = vstart[t_] + e[1];               // msg (s_ -> t_)
    int s2 = vstart[s_] + e[2];               // msg (t_ -> s_)
    *(int4*)(recs + pos) = make_int4(s_, s1, t_, s2);
  }
  if (i < nN && mask[i]) {
    int pos = s_rs[NREL] + noff[i];
    int slot = vstart[i] + cntv[i];           // self takes the last slot
    recs[pos] = make_int2(i, slot);
  }
}

// Phase A: relation-grouped MFMA over bf16 x-table; nt-stores for streaming msg.
// LDS is wave-private: in-wave DS ordering + lgkmcnt + sched_barrier (rule #18).
__global__ __launch_bounds__(256) void k_phaseA(const uint16_t* __restrict__ xb,
                                                const int2* __restrict__ recs,
                                                const uint16_t* __restrict__ Wt,
                                                const uint8_t* __restrict__ tileRel,
                                                uint16_t* __restrict__ msg,
                                                int ntiles) {
  __shared__ uint16_t s_m[4][16 * 72];   // +8 elem row pad
  __shared__ int s_slot[4][16];
  const int wid = threadIdx.x >> 6;
  const int lane = threadIdx.x & 63;
  const int quad = lane >> 4;
  const int m16 = lane & 15;
  const int t0 = (blockIdx.x * 4 + wid) * 4;

  if (tileRel[t0] == 255) return;        // wave-uniform tail exit (tileRel monotonic)

  int curRel = -1;
  short8b bfrag[4][2] = {};

  for (int it = 0; it < 4; ++it) {
    int t = t0 + it;
    int rel = (t < ntiles) ? (int)tileRel[t] : 255;
    bool valid = (rel != 255);

    if (valid && rel != curRel) {
      curRel = rel;
      const uint16_t* wbase = Wt + (size_t)rel * 4096;
      for (int nt = 0; nt < 4; ++nt)
        for (int kt = 0; kt < 2; ++kt)
          bfrag[nt][kt] = *(const short8b*)(wbase + (size_t)(nt * 16 + m16) * 64 + kt * 32 + quad * 8);
    }

    int2 rec;
    if (valid) {
      long long rv = __builtin_nontemporal_load((const long long*)(recs + t * 16 + m16));
      rec.x = (int)(rv & 0xFFFFFFFFll);
      rec.y = (int)(rv >> 32);
    } else {
      rec = make_int2(-1, -1);
    }
    int u = rec.x < 0 ? 0 : rec.x;

    const uint16_t* xp = xb + (size_t)u * 64 + quad * 8;
    short8b a0 = *(const short8b*)(xp);
    short8b a1 = *(const short8b*)(xp + 32);

    float4v acc[4];
    for (int nt = 0; nt < 4; ++nt) { acc[nt][0] = 0.f; acc[nt][1] = 0.f; acc[nt][2] = 0.f; acc[nt][3] = 0.f; }
    for (int nt = 0; nt < 4; ++nt) {
      acc[nt] = __builtin_amdgcn_mfma_f32_16x16x32_bf16(a0, bfrag[nt][0], acc[nt], 0, 0, 0);
      acc[nt] = __builtin_amdgcn_mfma_f32_16x16x32_bf16(a1, bfrag[nt][1], acc[nt], 0, 0, 0);
    }

    // C/D: col(dim) = m16 + nt*16, row(message) = quad*4 + reg
    if (quad == 0) s_slot[wid][m16] = rec.y;
    for (int reg = 0; reg < 4; ++reg)
      for (int nt = 0; nt < 4; ++nt)
        s_m[wid][(quad * 4 + reg) * 72 + nt * 16 + m16] = f32_bf16_hw(acc[nt][reg]);

    asm volatile("s_waitcnt lgkmcnt(0)" ::: "memory");
    __builtin_amdgcn_sched_barrier(0);

    // 16 rows x 128 B, 8 lanes/row x 16 B; msg is write-once streaming -> nt
    for (int p = 0; p < 2; ++p) {
      int row = (lane >> 3) + p * 8;
      int slot = s_slot[wid][row];
      if (slot >= 0) {
        const uint16_t* lp = &s_m[wid][row * 72 + (lane & 7) * 8];
        int4v val = *(const int4v*)lp;
        __builtin_nontemporal_store(val, (int4v*)(msg + (size_t)slot * 64 + (lane & 7) * 8));
      }
    }
    __builtin_amdgcn_sched_barrier(0);   // keep next iter's ds_writes after these reads
  }
}

// Phase B: per-target segmented sum. 8 lanes/target, nt 16 B loads.
__global__ __launch_bounds__(256) void k_phaseB(const uint16_t* __restrict__ msg,
                                                const int* __restrict__ cntt,
                                                const int* __restrict__ vstart,
                                                float* __restrict__ out, int nN) {
  int v = blockIdx.x * 32 + (threadIdx.x >> 3);
  int l = threadIdx.x & 7;
  if (v >= nN) return;
  int cnt = cntt[v];
  int base = vstart[v];
  float a[8] = {0.f, 0.f, 0.f, 0.f, 0.f, 0.f, 0.f, 0.f};
  const uint16_t* mp = msg + (size_t)base * 64 + l * 8;
  int j = 0;
  for (; j + 2 <= cnt; j += 2) {
    int4v r0 = __builtin_nontemporal_load((const int4v*)(mp + (size_t)j * 64));
    int4v r1 = __builtin_nontemporal_load((const int4v*)(mp + (size_t)(j + 1) * 64));
    short8b h0 = __builtin_bit_cast(short8b, r0);
    short8b h1 = __builtin_bit_cast(short8b, r1);
#pragma unroll
    for (int k = 0; k < 8; ++k)
      a[k] += bf2f((uint16_t)h0[k]) + bf2f((uint16_t)h1[k]);
  }
  if (j < cnt) {
    int4v r0 = __builtin_nontemporal_load((const int4v*)(mp + (size_t)j * 64));
    short8b h = __builtin_bit_cast(short8b, r0);
#pragma unroll
    for (int k = 0; k < 8; ++k)
      a[k] += bf2f((uint16_t)h[k]);
  }
  float* op = out + (size_t)v * 64 + l * 8;
  float4v o0, o1;
  o0[0] = a[0]; o0[1] = a[1]; o0[2] = a[2]; o0[3] = a[3];
  o1[0] = a[4]; o1[1] = a[5]; o1[2] = a[6]; o1[3] = a[7];
  __builtin_nontemporal_store(o0, (float4v*)op);
  __builtin_nontemporal_store(o1, (float4v*)(op + 4));
}

// ======================================================================
// FALLBACK PATH (atomic scatter) — used only if ws_size too small
// ======================================================================
#define F_WS_HIST    0
#define F_WS_CURSOR  64
#define F_WS_START   128
#define F_WS_WT      512
#define F_WS_TILEREL 139776
#define F_WS_RECS    262144
#define F_MAXTILES   112520
#define F_MAXRECS    (F_MAXTILES * 16)

__global__ __launch_bounds__(256) void f_hist(const int* __restrict__ et,
                                              int* __restrict__ hist, int nE) {
  __shared__ int lh[NREL];
  if (threadIdx.x < NREL) lh[threadIdx.x] = 0;
  __syncthreads();
  int i = blockIdx.x * 256 + threadIdx.x;
  if (i < nE) atomicAdd(&lh[et[i]], 2);
  __syncthreads();
  if (threadIdx.x < NREL && lh[threadIdx.x] > 0)
    atomicAdd(&hist[threadIdx.x], lh[threadIdx.x]);
}

__global__ __launch_bounds__(256) void f_prefix(const int* __restrict__ hist,
                                                int* __restrict__ cursor,
                                                int* __restrict__ start,
                                                uint8_t* __restrict__ tileRel,
                                                int nN, int maxTiles) {
  __shared__ int s_start[17];
  if (threadIdx.x == 0) {
    int base = nN;
    for (int r = 0; r < NREL; ++r) {
      s_start[r] = base;
      cursor[r] = base;
      start[r] = base;
      base = (base + hist[r] + 15) & ~15;
    }
    s_start[16] = base;
    start[16] = base;
  }
  __syncthreads();
  int endp = s_start[16];
  for (int t = threadIdx.x; t < maxTiles; t += 256) {
    int p = t * 16;
    uint8_t r;
    if (p < nN) r = 16;
    else if (p >= endp) r = 255;
    else {
      int q = 0;
      for (int k = 1; k < NREL; ++k) if (p >= s_start[k]) q = k;
      r = (uint8_t)q;
    }
    tileRel[t] = r;
  }
}

__global__ __launch_bounds__(256) void f_scatter(const int* __restrict__ src,
                                                 const int* __restrict__ tgt,
                                                 const int* __restrict__ et,
                                                 const int* __restrict__ mask,
                                                 int2* __restrict__ recs,
                                                 int* __restrict__ cursor,
                                                 int nE, int nN) {
  __shared__ int lh[NREL];
  __shared__ int lbase[NREL];
  if (threadIdx.x < NREL) lh[threadIdx.x] = 0;
  __syncthreads();
  int i = blockIdx.x * 256 + threadIdx.x;
  int r = 0, loff = 0;
  bool isEdge = (i < nE);
  if (isEdge) {
    r = et[i];
    loff = atomicAdd(&lh[r], 2);
  }
  __syncthreads();
  if (threadIdx.x < NREL)
    lbase[threadIdx.x] = (lh[threadIdx.x] > 0) ? atomicAdd(&cursor[threadIdx.x], lh[threadIdx.x]) : 0;
  __syncthreads();
  if (isEdge) {
    int pos = lbase[r] + loff;
    int s = src[i], t = tgt[i];
    *(int4*)(recs + pos) = make_int4(s, t, t, s);
  }
  if (i < nN) {
    recs[i] = (mask[i] != 0) ? make_int2(i, i) : make_int2(-1, -1);
  }
}

__global__ __launch_bounds__(256) void f_compute(const float* __restrict__ x,
                                                 const int2* __restrict__ recs,
                                                 const uint16_t* __restrict__ Wt,
                                                 const uint8_t* __restrict__ tileRel,
                                                 float* __restrict__ out,
                                                 int ntiles) {
  const int lane = threadIdx.x & 63;
  const int quad = lane >> 4;
  const int m16 = lane & 15;
  const int wave = blockIdx.x * 4 + (threadIdx.x >> 6);
  const int t0 = wave * 4;

  int curRel = -1;
  short8b bfrag[4][2] = {};

  for (int it = 0; it < 4; ++it) {
    int t = t0 + it;
    if (t >= ntiles) return;
    int rel = tileRel[t];
    if (rel == 255) return;

    if (rel != curRel) {
      curRel = rel;
      const uint16_t* wbase = Wt + (size_t)rel * 4096;
      for (int nt = 0; nt < 4; ++nt)
        for (int kt = 0; kt < 2; ++kt)
          bfrag[nt][kt] = *(const short8b*)(wbase + (size_t)(nt * 16 + m16) * 64 + kt * 32 + quad * 8);
    }

    int2 rec = recs[t * 16 + m16];
    int u = rec.x < 0 ? 0 : rec.x;

    const float* xp = x + (size_t)u * 64 + quad * 8;
    float4v q0 = *(const float4v*)(xp);
    float4v q1 = *(const float4v*)(xp + 4);
    float4v q2 = *(const float4v*)(xp + 32);
    float4v q3 = *(const float4v*)(xp + 36);
    short8b a0, a1;
    a0[0] = f32_bf16(q0[0]); a0[1] = f32_bf16(q0[1]); a0[2] = f32_bf16(q0[2]); a0[3] = f32_bf16(q0[3]);
    a0[4] = f32_bf16(q1[0]); a0[5] = f32_bf16(q1[1]); a0[6] = f32_bf16(q1[2]); a0[7] = f32_bf16(q1[3]);
    a1[0] = f32_bf16(q2[0]); a1[1] = f32_bf16(q2[1]); a1[2] = f32_bf16(q2[2]); a1[3] = f32_bf16(q2[3]);
    a1[4] = f32_bf16(q3[0]); a1[5] = f32_bf16(q3[1]); a1[6] = f32_bf16(q3[2]); a1[7] = f32_bf16(q3[3]);

    float4v acc[4];
    for (int nt = 0; nt < 4; ++nt) { acc[nt][0] = 0.f; acc[nt][1] = 0.f; acc[nt][2] = 0.f; acc[nt][3] = 0.f; }
    for (int nt = 0; nt < 4; ++nt) {
      acc[nt] = __builtin_amdgcn_mfma_f32_16x16x32_bf16(a0, bfrag[nt][0], acc[nt], 0, 0, 0);
      acc[nt] = __builtin_amdgcn_mfma_f32_16x16x32_bf16(a1, bfrag[nt][1], acc[nt], 0, 0, 0);
    }

    int tg[4];
    for (int reg = 0; reg < 4; ++reg)
      tg[reg] = __shfl(rec.y, quad * 4 + reg, 64);
    for (int reg = 0; reg < 4; ++reg) {
      if (tg[reg] < 0) continue;
      float* op = out + (size_t)tg[reg] * 64 + m16;
      for (int nt = 0; nt < 4; ++nt)
        __hip_atomic_fetch_add(op + nt * 16, acc[nt][reg], __ATOMIC_RELAXED, __HIP_MEMORY_SCOPE_AGENT);
    }
  }
}

// ======================================================================
extern "C" void kernel_launch(void* const* d_in, const int* in_sizes, int n_in,
                              void* d_out, int out_size, void* d_ws, size_t ws_size,
                              hipStream_t stream) {
  const float* x     = (const float*)d_in[0];
  const int*   mask  = (const int*)d_in[1];
  const int*   src   = (const int*)d_in[2];
  const int*   tgt   = (const int*)d_in[3];
  const int*   et    = (const int*)d_in[4];
  const float* bases = (const float*)d_in[5];
  const float* att   = (const float*)d_in[6];
  float* out = (float*)d_out;
  char* ws = (char*)d_ws;

  if (ws_size >= WS_TOTAL) {
    // ---------- two-phase target-sorted path ----------
    int*      cntr    = (int*)(ws + WS_CNTR);
    int*      rstart  = (int*)(ws + WS_RSTART);
    int*      gcur    = (int*)(ws + WS_GCUR);
    uint16_t* Wt      = (uint16_t*)(ws + WS_WT);
    uint8_t*  tileRel = (uint8_t*)(ws + WS_TILEREL);
    int*      cntv    = (int*)(ws + WS_CNTV);
    int*      vstart  = (int*)(ws + WS_VSTART);
    int*      cntt    = (int*)(ws + WS_CNTT);
    int2*     recs    = (int2*)(ws + WS_RECS);
    uint16_t* msg     = (uint16_t*)(ws + WS_MSG);
    int4*     eoff    = (int4*)(ws + OFF_EOFF);   // transient, inside msg
    int*      noff    = (int*)(ws + OFF_NOFF);    // transient, inside msg
    uint16_t* xb      = (uint16_t*)out;           // bf16 x-table in dead output

    k_init<<<1055, 256, 0, stream>>>(bases, att, Wt, (int*)ws, cntv);
    k_count<<<CNT_BLOCKS + CAST_BLOCKS, 256, 0, stream>>>(src, tgt, et, mask, cntr, cntv, eoff, noff, x, xb, N_EDGES, N_NODES);
    k_scan<<<PREP_BLOCKS + VSEG_BLOCKS, 256, 0, stream>>>(cntr, rstart, tileRel, recs, cntv, mask, vstart, cntt, gcur, MAXTILES, N_NODES);
    k_write<<<(N_EDGES + 255) / 256, 256, 0, stream>>>(src, tgt, et, mask, eoff, noff, rstart, cntv, vstart, recs, N_EDGES, N_NODES);
    k_phaseA<<<(MAXTILES + 15) / 16, 256, 0, stream>>>(xb, recs, Wt, tileRel, msg, MAXTILES);
    k_phaseB<<<(N_NODES + 31) / 32, 256, 0, stream>>>(msg, cntt, vstart, out, N_NODES);
  } else {
    // ---------- fallback: atomic path ----------
    int*      hist    = (int*)(ws + F_WS_HIST);
    int*      cursor  = (int*)(ws + F_WS_CURSOR);
    int*      start   = (int*)(ws + F_WS_START);
    uint16_t* Wt      = (uint16_t*)(ws + F_WS_WT);
    uint8_t*  tileRel = (uint8_t*)(ws + F_WS_TILEREL);
    int2*     recs    = (int2*)(ws + F_WS_RECS);

    (void)hipMemsetAsync(out, 0, (size_t)N_NODES * 64 * sizeof(float), stream);
    (void)hipMemsetAsync(ws, 0, 512, stream);
    (void)hipMemsetAsync(recs, 0xFF, (size_t)F_MAXRECS * sizeof(int2), stream);

    k_wprep<<<(17 * 64 * 64 + 255) / 256, 256, 0, stream>>>(bases, att, Wt);
    f_hist<<<(N_EDGES + 255) / 256, 256, 0, stream>>>(et, hist, N_EDGES);
    f_prefix<<<1, 256, 0, stream>>>(hist, cursor, start, tileRel, N_NODES, F_MAXTILES);
    f_scatter<<<(N_EDGES + 255) / 256, 256, 0, stream>>>(src, tgt, et, mask, recs, cursor, N_EDGES, N_NODES);
    f_compute<<<(F_MAXTILES + 15) / 16, 256, 0, stream>>>(x, recs, Wt, tileRel, out, F_MAXTILES);
  }
}

// Round 6
// 340.367 us; speedup vs baseline: 1.3985x; 1.0150x over previous
//
#include <hip/hip_runtime.h>
#include <hip/hip_bf16.h>
#include <stdint.h>
#include <stddef.h>

#define N_NODES 200000
#define N_EDGES 800000
#define NREL 16
#define NBASES 8

typedef __attribute__((ext_vector_type(8))) short short8b;
typedef __attribute__((ext_vector_type(4))) float float4v;
typedef __attribute__((ext_vector_type(4))) int int4v;

__device__ __forceinline__ short f32_bf16(float f) {
  uint32_t u = __builtin_bit_cast(uint32_t, f);
  uint32_t r = u + 0x7FFFu + ((u >> 16) & 1u);
  return (short)(uint16_t)(r >> 16);
}
// hardware RNE conversion (gfx950); same rounding as the manual version
__device__ __forceinline__ uint16_t f32_bf16_hw(float f) {
  __hip_bfloat16 h = __float2bfloat16(f);
  return __builtin_bit_cast(uint16_t, h);
}
__device__ __forceinline__ float bf2f(uint16_t h) {
  return __builtin_bit_cast(float, (uint32_t)h << 16);
}

// ============================ shared: W table ============================
__global__ __launch_bounds__(256) void k_wprep(const float* __restrict__ bases,
                                               const float* __restrict__ att,
                                               uint16_t* __restrict__ Wt) {
  int i = blockIdx.x * 256 + threadIdx.x;
  if (i >= 17 * 64 * 64) return;
  int r = i >> 12;
  int e = (i >> 6) & 63;
  int d = i & 63;
  float acc = 0.f;
  for (int b = 0; b < NBASES; ++b)
    acc += att[r * NBASES + b] * bases[b * 4096 + d * 64 + e];
  Wt[i] = (uint16_t)f32_bf16(acc);
}

// ======================================================================
// MAIN PATH: two-phase target-sorted (no output atomics)
// xb (bf16 x copy, 25.6 MB) lives in the dead first half of the output buffer.
// Offsets (eoff/noff) live at the head of the msg region: consumed by k_write
// BEFORE phaseA overwrites msg.
// ======================================================================
#define MAXTILES 112528
#define MAXRECS  (MAXTILES * 16)
#define WS_CNTR    0          // 32 int
#define WS_RCUR    128        // 32 int (unused, layout compat)
#define WS_RSTART  256        // 18 int, written by k_scan, read by k_write
#define WS_GCUR    384        // 1 int
#define WS_WT      512        // 17*64*64 u16 -> ends 139776
#define WS_TILEREL 139776     // MAXTILES u8 -> ends 252304 (pad to 252416)
#define WS_CNTV    252416     // 200000 int (edge-only counts)
#define WS_VSTART  1052416    // 200000 int
#define WS_CNTT    1852416    // 200000 int (total counts incl self)
#define WS_RECS    2652416    // MAXRECS int2 -> ends 17056000 (pad to 17056128)
#define WS_MSG     17056128   // MAXRECS * 64 u16 rows
#define WS_TOTAL   (WS_MSG + (size_t)MAXRECS * 128)   // ~247.5 MB
// transient, inside msg region:
#define OFF_EOFF   WS_MSG                         // 800000 int4 = 12.8 MB
#define OFF_NOFF   (WS_MSG + (size_t)N_EDGES*16)  // 200000 int  = 0.8 MB

// Fused: Wt prep (0..272) | zero cntr/gcur + cntv (273..1054)
__global__ __launch_bounds__(256) void k_init(const float* __restrict__ bases,
                                              const float* __restrict__ att,
                                              uint16_t* __restrict__ Wt,
                                              int* __restrict__ zero0,
                                              int* __restrict__ cntv) {
  int b = blockIdx.x;
  int tid = threadIdx.x;
  if (b < 273) {
    int i = b * 256 + tid;
    if (i < 17 * 64 * 64) {
      int r = i >> 12;
      int e = (i >> 6) & 63;
      int d = i & 63;
      float acc = 0.f;
      for (int bb = 0; bb < NBASES; ++bb)
        acc += att[r * NBASES + bb] * bases[bb * 4096 + d * 64 + e];
      Wt[i] = (uint16_t)f32_bf16(acc);
    }
  } else {
    int idx = (b - 273) * 256 + tid;
    if (idx < 128) zero0[idx] = 0;            // cntr/rcur/rstart/gcur region
    else if (idx - 128 < N_NODES) cntv[idx - 128] = 0;
  }
}

// Fused count (blocks 0..781, 4 edges/thread) + x->bf16 cast (6250 blocks).
// Restructure for atomic MLP: LDS hist + both barriers complete FIRST, then
// each thread fires 8 independent scattered atomics with no trailing barrier,
// so waves retire as their atomics drain (no vmcnt(0)-at-barrier coupling).
#define CNT_BLOCKS  782          // ceil(800000/1024)
#define CAST_BLOCKS 6250
__global__ __launch_bounds__(256) void k_count(const int* __restrict__ src,
                                               const int* __restrict__ tgt,
                                               const int* __restrict__ et,
                                               const int* __restrict__ mask,
                                               int* __restrict__ cntr,
                                               int* __restrict__ cntv,
                                               int4* __restrict__ eoff,
                                               int* __restrict__ noff,
                                               const float* __restrict__ x,
                                               uint16_t* __restrict__ xb,
                                               int nE, int nN) {
  int b = blockIdx.x;
  if (b >= CNT_BLOCKS) {
    int i = (b - CNT_BLOCKS) * 256 + threadIdx.x;   // exact: i < 1,600,000
    const float* xp = x + (size_t)i * 8;
    float4v q0 = __builtin_nontemporal_load((const float4v*)xp);
    float4v q1 = __builtin_nontemporal_load((const float4v*)(xp + 4));
    short8b o;
    o[0] = f32_bf16_hw(q0[0]); o[1] = f32_bf16_hw(q0[1]); o[2] = f32_bf16_hw(q0[2]); o[3] = f32_bf16_hw(q0[3]);
    o[4] = f32_bf16_hw(q1[0]); o[5] = f32_bf16_hw(q1[1]); o[6] = f32_bf16_hw(q1[2]); o[7] = f32_bf16_hw(q1[3]);
    *(short8b*)(xb + (size_t)i * 8) = o;      // cacheable: phaseA re-reads it
    return;
  }
  __shared__ int lh[NREL + 1], lbase[NREL + 1];
  if (threadIdx.x <= NREL) lh[threadIdx.x] = 0;
  __syncthreads();
  int base = b * 1024 + threadIdx.x;
  bool isE[4], isN[4];
  int r4[4], loff[4], loffN[4], s4[4], t4[4];
#pragma unroll
  for (int k = 0; k < 4; ++k) {
    int i = base + k * 256;
    isE[k] = i < nE;
    isN[k] = (i < nN) && mask[i];
    if (isE[k]) {
      r4[k] = et[i];
      s4[k] = src[i];
      t4[k] = tgt[i];
      loff[k] = atomicAdd(&lh[r4[k]], 2);
    }
    if (isN[k]) loffN[k] = atomicAdd(&lh[NREL], 1);
  }
  __syncthreads();
  if (threadIdx.x <= NREL)
    lbase[threadIdx.x] = lh[threadIdx.x] ? atomicAdd(&cntr[threadIdx.x], lh[threadIdx.x]) : 0;
  __syncthreads();
  // 8 independent scattered atomics in flight per thread
  int o1[4], o2[4];
#pragma unroll
  for (int k = 0; k < 4; ++k) {
    if (isE[k]) {
      o1[k] = atomicAdd(&cntv[t4[k]], 1);
      o2[k] = atomicAdd(&cntv[s4[k]], 1);
    }
  }
#pragma unroll
  for (int k = 0; k < 4; ++k) {
    int i = base + k * 256;
    if (isE[k]) {
      int4v v; v[0] = lbase[r4[k]] + loff[k]; v[1] = o1[k]; v[2] = o2[k]; v[3] = 0;
      __builtin_nontemporal_store(v, (int4v*)(eoff + i));
    }
    if (isN[k]) __builtin_nontemporal_store(lbase[NREL] + loffN[k], noff + i);
  }
}

// Fused: bucket-prefix + rstart publish + tileRel + pad-records (blocks 0..439)
// and per-target segment scan (blocks 440..1221). Both depend only on k_count.
#define PREP_BLOCKS 440
#define VSEG_BLOCKS 782
__global__ __launch_bounds__(256) void k_scan(const int* __restrict__ cntr,
                                              int* __restrict__ rstart_g,
                                              uint8_t* __restrict__ tileRel,
                                              int2* __restrict__ recs,
                                              const int* __restrict__ cntv,
                                              const int* __restrict__ mask,
                                              int* __restrict__ vstart,
                                              int* __restrict__ cntt,
                                              int* __restrict__ gcur,
                                              int maxTiles, int nN) {
  int b = blockIdx.x;
  if (b < PREP_BLOCKS) {
    __shared__ int s[NREL + 2];
    if (threadIdx.x == 0) {
      int base = 0;
      for (int r = 0; r <= NREL; ++r) {
        s[r] = base;
        base = (base + cntr[r] + 15) & ~15;
      }
      s[NREL + 1] = base;
    }
    __syncthreads();
    if (b == 0) {
      if (threadIdx.x <= NREL + 1) rstart_g[threadIdx.x] = s[threadIdx.x];
      for (int w = threadIdx.x; w < (NREL + 1) * 16; w += 256) {
        int r = w >> 4, j = w & 15;
        int pos = s[r] + cntr[r] + j;
        if (pos < s[r + 1]) recs[pos] = make_int2(-1, -1);
      }
    }
    int t = b * 256 + threadIdx.x;
    if (t < maxTiles) {
      int p = t * 16;
      uint8_t rr = 255;
      if (p < s[NREL + 1]) {
        int q = 0;
        for (int k = 1; k <= NREL; ++k)
          if (p >= s[k]) q = k;
        rr = (uint8_t)q;
      }
      tileRel[t] = rr;
    }
  } else {
    __shared__ int wsum[4];
    __shared__ int s_base;
    int v = (b - PREP_BLOCKS) * 256 + threadIdx.x;
    int lane = threadIdx.x & 63;
    int wid = threadIdx.x >> 6;
    int c = 0;
    if (v < nN) c = cntv[v] + (mask[v] ? 1 : 0);
    int incl = c;
    for (int off = 1; off < 64; off <<= 1) {
      int n = __shfl_up(incl, off, 64);
      if (lane >= off) incl += n;
    }
    if (lane == 63) wsum[wid] = incl;
    __syncthreads();
    if (threadIdx.x == 0) {
      int t0 = wsum[0], t1 = wsum[1], t2 = wsum[2], t3 = wsum[3];
      s_base = atomicAdd(gcur, t0 + t1 + t2 + t3);
      wsum[0] = 0;
      wsum[1] = t0;
      wsum[2] = t0 + t1;
      wsum[3] = t0 + t1 + t2;
    }
    __syncthreads();
    if (v < nN) {
      vstart[v] = s_base + wsum[wid] + incl - c;
      cntt[v] = c;
    }
  }
}

// Record construction: ZERO atomics.
__global__ __launch_bounds__(256) void k_write(const int* __restrict__ src,
                                               const int* __restrict__ tgt,
                                               const int* __restrict__ et,
                                               const int* __restrict__ mask,
                                               const int4* __restrict__ eoff,
                                               const int* __restrict__ noff,
                                               const int* __restrict__ rstart,
                                               const int* __restrict__ cntv,
                                               const int* __restrict__ vstart,
                                               int2* __restrict__ recs,
                                               int nE, int nN) {
  __shared__ int s_rs[NREL + 1];
  if (threadIdx.x <= NREL) s_rs[threadIdx.x] = rstart[threadIdx.x];
  __syncthreads();
  int i = blockIdx.x * 256 + threadIdx.x;
  if (i < nE) {
    int r = et[i];
    int4v e = __builtin_nontemporal_load((const int4v*)(eoff + i));
    int s_ = src[i], t_ = tgt[i];
    int pos = s_rs[r] + e[0];                 // even -> 16B aligned
    int s1 = vstart[t_] + e[1];               // msg (s_ -> t_)
    int s2 = vstart[s_] + e[2];               // msg (t_ -> s_)
    *(int4*)(recs + pos) = make_int4(s_, s1, t_, s2);
  }
  if (i < nN && mask[i]) {
    int pos = s_rs[NREL] + noff[i];
    int slot = vstart[i] + cntv[i];           // self takes the last slot
    recs[pos] = make_int2(i, slot);
  }
}

// Phase A: relation-grouped MFMA over bf16 x-table; 4-deep prefetch of
// tileRel/recs/xb fragments at wave entry breaks the per-tile serial chain.
// LDS is wave-private: in-wave DS ordering + lgkmcnt + sched_barrier (rule #18).
__global__ __launch_bounds__(256) void k_phaseA(const uint16_t* __restrict__ xb,
                                                const int2* __restrict__ recs,
                                                const uint16_t* __restrict__ Wt,
                                                const uint8_t* __restrict__ tileRel,
                                                uint16_t* __restrict__ msg,
                                                int ntiles) {
  __shared__ uint16_t s_m[4][16 * 72];   // +8 elem row pad
  __shared__ int s_slot[4][16];
  const int wid = threadIdx.x >> 6;
  const int lane = threadIdx.x & 63;
  const int quad = lane >> 4;
  const int m16 = lane & 15;
  const int t0 = (blockIdx.x * 4 + wid) * 4;

  if (tileRel[t0] == 255) return;        // wave-uniform tail exit (tileRel monotonic)

  // ---- prefetch: tileRel, recs, xb fragments for all 4 tiles ----
  int rel4[4];
#pragma unroll
  for (int it = 0; it < 4; ++it) {
    int t = t0 + it;
    rel4[it] = (t < ntiles) ? (int)tileRel[t] : 255;
  }
  int2 rec4[4];
#pragma unroll
  for (int it = 0; it < 4; ++it) {
    if (rel4[it] != 255) {
      long long rv = __builtin_nontemporal_load((const long long*)(recs + (t0 + it) * 16 + m16));
      rec4[it].x = (int)(rv & 0xFFFFFFFFll);
      rec4[it].y = (int)(rv >> 32);
    } else {
      rec4[it] = make_int2(-1, -1);
    }
  }
  short8b a0_[4], a1_[4];
#pragma unroll
  for (int it = 0; it < 4; ++it) {
    int u = rec4[it].x < 0 ? 0 : rec4[it].x;
    const uint16_t* xp = xb + (size_t)u * 64 + quad * 8;
    a0_[it] = *(const short8b*)(xp);
    a1_[it] = *(const short8b*)(xp + 32);
  }

  int curRel = -1;
  short8b bfrag[4][2] = {};

#pragma unroll
  for (int it = 0; it < 4; ++it) {
    int rel = rel4[it];
    if (rel == 255) continue;            // wave-uniform

    if (rel != curRel) {
      curRel = rel;
      const uint16_t* wbase = Wt + (size_t)rel * 4096;
      for (int nt = 0; nt < 4; ++nt)
        for (int kt = 0; kt < 2; ++kt)
          bfrag[nt][kt] = *(const short8b*)(wbase + (size_t)(nt * 16 + m16) * 64 + kt * 32 + quad * 8);
    }

    float4v acc[4];
    for (int nt = 0; nt < 4; ++nt) { acc[nt][0] = 0.f; acc[nt][1] = 0.f; acc[nt][2] = 0.f; acc[nt][3] = 0.f; }
    for (int nt = 0; nt < 4; ++nt) {
      acc[nt] = __builtin_amdgcn_mfma_f32_16x16x32_bf16(a0_[it], bfrag[nt][0], acc[nt], 0, 0, 0);
      acc[nt] = __builtin_amdgcn_mfma_f32_16x16x32_bf16(a1_[it], bfrag[nt][1], acc[nt], 0, 0, 0);
    }

    // C/D: col(dim) = m16 + nt*16, row(message) = quad*4 + reg
    if (quad == 0) s_slot[wid][m16] = rec4[it].y;
    for (int reg = 0; reg < 4; ++reg)
      for (int nt = 0; nt < 4; ++nt)
        s_m[wid][(quad * 4 + reg) * 72 + nt * 16 + m16] = f32_bf16_hw(acc[nt][reg]);

    asm volatile("s_waitcnt lgkmcnt(0)" ::: "memory");
    __builtin_amdgcn_sched_barrier(0);

    // 16 rows x 128 B, 8 lanes/row x 16 B; msg is write-once streaming -> nt
    for (int p = 0; p < 2; ++p) {
      int row = (lane >> 3) + p * 8;
      int slot = s_slot[wid][row];
      if (slot >= 0) {
        const uint16_t* lp = &s_m[wid][row * 72 + (lane & 7) * 8];
        int4v val = *(const int4v*)lp;
        __builtin_nontemporal_store(val, (int4v*)(msg + (size_t)slot * 64 + (lane & 7) * 8));
      }
    }
    __builtin_amdgcn_sched_barrier(0);   // keep next iter's ds_writes after these reads
  }
}

// Phase B: per-target segmented sum. 8 lanes/target, nt 16 B loads.
__global__ __launch_bounds__(256) void k_phaseB(const uint16_t* __restrict__ msg,
                                                const int* __restrict__ cntt,
                                                const int* __restrict__ vstart,
                                                float* __restrict__ out, int nN) {
  int v = blockIdx.x * 32 + (threadIdx.x >> 3);
  int l = threadIdx.x & 7;
  if (v >= nN) return;
  int cnt = cntt[v];
  int base = vstart[v];
  float a[8] = {0.f, 0.f, 0.f, 0.f, 0.f, 0.f, 0.f, 0.f};
  const uint16_t* mp = msg + (size_t)base * 64 + l * 8;
  int j = 0;
  for (; j + 2 <= cnt; j += 2) {
    int4v r0 = __builtin_nontemporal_load((const int4v*)(mp + (size_t)j * 64));
    int4v r1 = __builtin_nontemporal_load((const int4v*)(mp + (size_t)(j + 1) * 64));
    short8b h0 = __builtin_bit_cast(short8b, r0);
    short8b h1 = __builtin_bit_cast(short8b, r1);
#pragma unroll
    for (int k = 0; k < 8; ++k)
      a[k] += bf2f((uint16_t)h0[k]) + bf2f((uint16_t)h1[k]);
  }
  if (j < cnt) {
    int4v r0 = __builtin_nontemporal_load((const int4v*)(mp + (size_t)j * 64));
    short8b h = __builtin_bit_cast(short8b, r0);
#pragma unroll
    for (int k = 0; k < 8; ++k)
      a[k] += bf2f((uint16_t)h[k]);
  }
  float* op = out + (size_t)v * 64 + l * 8;
  float4v o0, o1;
  o0[0] = a[0]; o0[1] = a[1]; o0[2] = a[2]; o0[3] = a[3];
  o1[0] = a[4]; o1[1] = a[5]; o1[2] = a[6]; o1[3] = a[7];
  __builtin_nontemporal_store(o0, (float4v*)op);
  __builtin_nontemporal_store(o1, (float4v*)(op + 4));
}

// ======================================================================
// FALLBACK PATH (atomic scatter) — used only if ws_size too small
// ======================================================================
#define F_WS_HIST    0
#define F_WS_CURSOR  64
#define F_WS_START   128
#define F_WS_WT      512
#define F_WS_TILEREL 139776
#define F_WS_RECS    262144
#define F_MAXTILES   112520
#define F_MAXRECS    (F_MAXTILES * 16)

__global__ __launch_bounds__(256) void f_hist(const int* __restrict__ et,
                                              int* __restrict__ hist, int nE) {
  __shared__ int lh[NREL];
  if (threadIdx.x < NREL) lh[threadIdx.x] = 0;
  __syncthreads();
  int i = blockIdx.x * 256 + threadIdx.x;
  if (i < nE) atomicAdd(&lh[et[i]], 2);
  __syncthreads();
  if (threadIdx.x < NREL && lh[threadIdx.x] > 0)
    atomicAdd(&hist[threadIdx.x], lh[threadIdx.x]);
}

__global__ __launch_bounds__(256) void f_prefix(const int* __restrict__ hist,
                                                int* __restrict__ cursor,
                                                int* __restrict__ start,
                                                uint8_t* __restrict__ tileRel,
                                                int nN, int maxTiles) {
  __shared__ int s_start[17];
  if (threadIdx.x == 0) {
    int base = nN;
    for (int r = 0; r < NREL; ++r) {
      s_start[r] = base;
      cursor[r] = base;
      start[r] = base;
      base = (base + hist[r] + 15) & ~15;
    }
    s_start[16] = base;
    start[16] = base;
  }
  __syncthreads();
  int endp = s_start[16];
  for (int t = threadIdx.x; t < maxTiles; t += 256) {
    int p = t * 16;
    uint8_t r;
    if (p < nN) r = 16;
    else if (p >= endp) r = 255;
    else {
      int q = 0;
      for (int k = 1; k < NREL; ++k) if (p >= s_start[k]) q = k;
      r = (uint8_t)q;
    }
    tileRel[t] = r;
  }
}

__global__ __launch_bounds__(256) void f_scatter(const int* __restrict__ src,
                                                 const int* __restrict__ tgt,
                                                 const int* __restrict__ et,
                                                 const int* __restrict__ mask,
                                                 int2* __restrict__ recs,
                                                 int* __restrict__ cursor,
                                                 int nE, int nN) {
  __shared__ int lh[NREL];
  __shared__ int lbase[NREL];
  if (threadIdx.x < NREL) lh[threadIdx.x] = 0;
  __syncthreads();
  int i = blockIdx.x * 256 + threadIdx.x;
  int r = 0, loff = 0;
  bool isEdge = (i < nE);
  if (isEdge) {
    r = et[i];
    loff = atomicAdd(&lh[r], 2);
  }
  __syncthreads();
  if (threadIdx.x < NREL)
    lbase[threadIdx.x] = (lh[threadIdx.x] > 0) ? atomicAdd(&cursor[threadIdx.x], lh[threadIdx.x]) : 0;
  __syncthreads();
  if (isEdge) {
    int pos = lbase[r] + loff;
    int s = src[i], t = tgt[i];
    *(int4*)(recs + pos) = make_int4(s, t, t, s);
  }
  if (i < nN) {
    recs[i] = (mask[i] != 0) ? make_int2(i, i) : make_int2(-1, -1);
  }
}

__global__ __launch_bounds__(256) void f_compute(const float* __restrict__ x,
                                                 const int2* __restrict__ recs,
                                                 const uint16_t* __restrict__ Wt,
                                                 const uint8_t* __restrict__ tileRel,
                                                 float* __restrict__ out,
                                                 int ntiles) {
  const int lane = threadIdx.x & 63;
  const int quad = lane >> 4;
  const int m16 = lane & 15;
  const int wave = blockIdx.x * 4 + (threadIdx.x >> 6);
  const int t0 = wave * 4;

  int curRel = -1;
  short8b bfrag[4][2] = {};

  for (int it = 0; it < 4; ++it) {
    int t = t0 + it;
    if (t >= ntiles) return;
    int rel = tileRel[t];
    if (rel == 255) return;

    if (rel != curRel) {
      curRel = rel;
      const uint16_t* wbase = Wt + (size_t)rel * 4096;
      for (int nt = 0; nt < 4; ++nt)
        for (int kt = 0; kt < 2; ++kt)
          bfrag[nt][kt] = *(const short8b*)(wbase + (size_t)(nt * 16 + m16) * 64 + kt * 32 + quad * 8);
    }

    int2 rec = recs[t * 16 + m16];
    int u = rec.x < 0 ? 0 : rec.x;

    const float* xp = x + (size_t)u * 64 + quad * 8;
    float4v q0 = *(const float4v*)(xp);
    float4v q1 = *(const float4v*)(xp + 4);
    float4v q2 = *(const float4v*)(xp + 32);
    float4v q3 = *(const float4v*)(xp + 36);
    short8b a0, a1;
    a0[0] = f32_bf16(q0[0]); a0[1] = f32_bf16(q0[1]); a0[2] = f32_bf16(q0[2]); a0[3] = f32_bf16(q0[3]);
    a0[4] = f32_bf16(q1[0]); a0[5] = f32_bf16(q1[1]); a0[6] = f32_bf16(q1[2]); a0[7] = f32_bf16(q1[3]);
    a1[0] = f32_bf16(q2[0]); a1[1] = f32_bf16(q2[1]); a1[2] = f32_bf16(q2[2]); a1[3] = f32_bf16(q2[3]);
    a1[4] = f32_bf16(q3[0]); a1[5] = f32_bf16(q3[1]); a1[6] = f32_bf16(q3[2]); a1[7] = f32_bf16(q3[3]);

    float4v acc[4];
    for (int nt = 0; nt < 4; ++nt) { acc[nt][0] = 0.f; acc[nt][1] = 0.f; acc[nt][2] = 0.f; acc[nt][3] = 0.f; }
    for (int nt = 0; nt < 4; ++nt) {
      acc[nt] = __builtin_amdgcn_mfma_f32_16x16x32_bf16(a0, bfrag[nt][0], acc[nt], 0, 0, 0);
      acc[nt] = __builtin_amdgcn_mfma_f32_16x16x32_bf16(a1, bfrag[nt][1], acc[nt], 0, 0, 0);
    }

    int tg[4];
    for (int reg = 0; reg < 4; ++reg)
      tg[reg] = __shfl(rec.y, quad * 4 + reg, 64);
    for (int reg = 0; reg < 4; ++reg) {
      if (tg[reg] < 0) continue;
      float* op = out + (size_t)tg[reg] * 64 + m16;
      for (int nt = 0; nt < 4; ++nt)
        __hip_atomic_fetch_add(op + nt * 16, acc[nt][reg], __ATOMIC_RELAXED, __HIP_MEMORY_SCOPE_AGENT);
    }
  }
}

// ======================================================================
extern "C" void kernel_launch(void* const* d_in, const int* in_sizes, int n_in,
                              void* d_out, int out_size, void* d_ws, size_t ws_size,
                              hipStream_t stream) {
  const float* x     = (const float*)d_in[0];
  const int*   mask  = (const int*)d_in[1];
  const int*   src   = (const int*)d_in[2];
  const int*   tgt   = (const int*)d_in[3];
  const int*   et    = (const int*)d_in[4];
  const float* bases = (const float*)d_in[5];
  const float* att   = (const float*)d_in[6];
  float* out = (float*)d_out;
  char* ws = (char*)d_ws;

  if (ws_size >= WS_TOTAL) {
    // ---------- two-phase target-sorted path ----------
    int*      cntr    = (int*)(ws + WS_CNTR);
    int*      rstart  = (int*)(ws + WS_RSTART);
    int*      gcur    = (int*)(ws + WS_GCUR);
    uint16_t* Wt      = (uint16_t*)(ws + WS_WT);
    uint8_t*  tileRel = (uint8_t*)(ws + WS_TILEREL);
    int*      cntv    = (int*)(ws + WS_CNTV);
    int*      vstart  = (int*)(ws + WS_VSTART);
    int*      cntt    = (int*)(ws + WS_CNTT);
    int2*     recs    = (int2*)(ws + WS_RECS);
    uint16_t* msg     = (uint16_t*)(ws + WS_MSG);
    int4*     eoff    = (int4*)(ws + OFF_EOFF);   // transient, inside msg
    int*      noff    = (int*)(ws + OFF_NOFF);    // transient, inside msg
    uint16_t* xb      = (uint16_t*)out;           // bf16 x-table in dead output

    k_init<<<1055, 256, 0, stream>>>(bases, att, Wt, (int*)ws, cntv);
    k_count<<<CNT_BLOCKS + CAST_BLOCKS, 256, 0, stream>>>(src, tgt, et, mask, cntr, cntv, eoff, noff, x, xb, N_EDGES, N_NODES);
    k_scan<<<PREP_BLOCKS + VSEG_BLOCKS, 256, 0, stream>>>(cntr, rstart, tileRel, recs, cntv, mask, vstart, cntt, gcur, MAXTILES, N_NODES);
    k_write<<<(N_EDGES + 255) / 256, 256, 0, stream>>>(src, tgt, et, mask, eoff, noff, rstart, cntv, vstart, recs, N_EDGES, N_NODES);
    k_phaseA<<<(MAXTILES + 15) / 16, 256, 0, stream>>>(xb, recs, Wt, tileRel, msg, MAXTILES);
    k_phaseB<<<(N_NODES + 31) / 32, 256, 0, stream>>>(msg, cntt, vstart, out, N_NODES);
  } else {
    // ---------- fallback: atomic path ----------
    int*      hist    = (int*)(ws + F_WS_HIST);
    int*      cursor  = (int*)(ws + F_WS_CURSOR);
    int*      start   = (int*)(ws + F_WS_START);
    uint16_t* Wt      = (uint16_t*)(ws + F_WS_WT);
    uint8_t*  tileRel = (uint8_t*)(ws + F_WS_TILEREL);
    int2*     recs    = (int2*)(ws + F_WS_RECS);

    (void)hipMemsetAsync(out, 0, (size_t)N_NODES * 64 * sizeof(float), stream);
    (void)hipMemsetAsync(ws, 0, 512, stream);
    (void)hipMemsetAsync(recs, 0xFF, (size_t)F_MAXRECS * sizeof(int2), stream);

    k_wprep<<<(17 * 64 * 64 + 255) / 256, 256, 0, stream>>>(bases, att, Wt);
    f_hist<<<(N_EDGES + 255) / 256, 256, 0, stream>>>(et, hist, N_EDGES);
    f_prefix<<<1, 256, 0, stream>>>(hist, cursor, start, tileRel, N_NODES, F_MAXTILES);
    f_scatter<<<(N_EDGES + 255) / 256, 256, 0, stream>>>(src, tgt, et, mask, recs, cursor, N_EDGES, N_NODES);
    f_compute<<<(F_MAXTILES + 15) / 16, 256, 0, stream>>>(x, recs, Wt, tileRel, out, F_MAXTILES);
  }
}

// Round 7
// 308.714 us; speedup vs baseline: 1.5419x; 1.1025x over previous
//
#include <hip/hip_runtime.h>
#include <hip/hip_bf16.h>
#include <stdint.h>
#include <stddef.h>

#define N_NODES 200000
#define N_EDGES 800000
#define NREL 16
#define NBASES 8

typedef __attribute__((ext_vector_type(8))) short short8b;
typedef __attribute__((ext_vector_type(4))) float float4v;
typedef __attribute__((ext_vector_type(4))) int int4v;

__device__ __forceinline__ short f32_bf16(float f) {
  uint32_t u = __builtin_bit_cast(uint32_t, f);
  uint32_t r = u + 0x7FFFu + ((u >> 16) & 1u);
  return (short)(uint16_t)(r >> 16);
}
// hardware RNE conversion (gfx950); same rounding as the manual version
__device__ __forceinline__ uint16_t f32_bf16_hw(float f) {
  __hip_bfloat16 h = __float2bfloat16(f);
  return __builtin_bit_cast(uint16_t, h);
}
__device__ __forceinline__ float bf2f(uint16_t h) {
  return __builtin_bit_cast(float, (uint32_t)h << 16);
}

// ============================ shared: W table ============================
__global__ __launch_bounds__(256) void k_wprep(const float* __restrict__ bases,
                                               const float* __restrict__ att,
                                               uint16_t* __restrict__ Wt) {
  int i = blockIdx.x * 256 + threadIdx.x;
  if (i >= 17 * 64 * 64) return;
  int r = i >> 12;
  int e = (i >> 6) & 63;
  int d = i & 63;
  float acc = 0.f;
  for (int b = 0; b < NBASES; ++b)
    acc += att[r * NBASES + b] * bases[b * 4096 + d * 64 + e];
  Wt[i] = (uint16_t)f32_bf16(acc);
}

// ======================================================================
// MAIN PATH: two-phase target-sorted, ZERO scattered global atomics.
// Per-node slot assignment via bucketed counting sort (LDS atomics only):
//   K1 k_count : per-block bucket histograms H + relation offsets (+x cast)
//   K2 k_base  : column scan of H -> per-(block,bucket) bases
//   K3 k_scat  : scatter packed endpoint records into bucket regions
//   K4 k_slot  : per-bucket LDS counters -> eslot[itemid], final cntv
// xb (bf16 x copy) lives in the dead first half of the output buffer.
// All transients live at the head of the msg region (dead before phaseA).
// ======================================================================
#define MAXTILES 112528
#define MAXRECS  (MAXTILES * 16)
#define NB 196                 // node buckets of 1024 (196*1024 >= 200000)
#define CNT_BLOCKS  782        // ceil(800000/1024) edge blocks (4 edges/thread)
#define CAST_BLOCKS 6250
#define WS_CNTR    0          // 32 int
#define WS_GCUR2   128        // 1 int (bucket-region allocator)
#define WS_RSTART  256        // 18 int, written by k_scan, read by k_write
#define WS_GCUR    384        // 1 int (segment allocator)
#define WS_WT      512        // 17*64*64 u16 -> ends 139776
#define WS_TILEREL 139776     // MAXTILES u8 -> ends 252304 (pad to 252416)
#define WS_CNTV    252416     // 200000 int (edge-only counts, written by k_slot)
#define WS_VSTART  1052416    // 200000 int
#define WS_CNTT    1852416    // 200000 int (total counts incl self)
#define WS_RECS    2652416    // MAXRECS int2 -> ends 17056000 (pad to 17056128)
#define WS_MSG     17056128   // MAXRECS * 64 u16 rows
#define WS_TOTAL   (WS_MSG + (size_t)MAXRECS * 128)   // ~247.5 MB
// transients inside msg region (consumed by k_write before phaseA):
#define TR_RELOFF  WS_MSG                      // E int   = 3.2 MB
#define TR_NOFF    (TR_RELOFF + 3200000)       // N int   = 0.8 MB
#define TR_ESLOT   (TR_NOFF + 800000)          // 2E int  = 6.4 MB
#define TR_SCRATCH (TR_ESLOT + 6400000)        // 2E int  = 6.4 MB
#define TR_H       (TR_SCRATCH + 6400000)      // 782*196 int
#define TR_BASE    (TR_H + 613088)             // 782*196 int
#define TR_REGS    (TR_BASE + 613088)          // 2*196 int (regStart, regTot)

// Fused: Wt prep (0..272) | zero 512B control head (block 273)
__global__ __launch_bounds__(256) void k_init(const float* __restrict__ bases,
                                              const float* __restrict__ att,
                                              uint16_t* __restrict__ Wt,
                                              int* __restrict__ zero0) {
  int b = blockIdx.x;
  int tid = threadIdx.x;
  if (b < 273) {
    int i = b * 256 + tid;
    if (i < 17 * 64 * 64) {
      int r = i >> 12;
      int e = (i >> 6) & 63;
      int d = i & 63;
      float acc = 0.f;
      for (int bb = 0; bb < NBASES; ++bb)
        acc += att[r * NBASES + bb] * bases[bb * 4096 + d * 64 + e];
      Wt[i] = (uint16_t)f32_bf16(acc);
    }
  } else {
    if (tid < 128) zero0[tid] = 0;   // cntr/gcur2/rstart/gcur region
  }
}

// K1: edge blocks (0..781, 4 edges/thread) + x->bf16 cast blocks.
// LDS-only histograms; global atomics: 17 relation counters per block.
__global__ __launch_bounds__(256) void k_count(const int* __restrict__ src,
                                               const int* __restrict__ tgt,
                                               const int* __restrict__ et,
                                               const int* __restrict__ mask,
                                               int* __restrict__ cntr,
                                               int* __restrict__ H,
                                               int* __restrict__ reloff,
                                               int* __restrict__ noff,
                                               const float* __restrict__ x,
                                               uint16_t* __restrict__ xb,
                                               int nE, int nN) {
  int b = blockIdx.x;
  int tid = threadIdx.x;
  if (b >= CNT_BLOCKS) {
    int i = (b - CNT_BLOCKS) * 256 + tid;   // exact: i < 1,600,000
    const float* xp = x + (size_t)i * 8;
    float4v q0 = __builtin_nontemporal_load((const float4v*)xp);
    float4v q1 = __builtin_nontemporal_load((const float4v*)(xp + 4));
    short8b o;
    o[0] = f32_bf16_hw(q0[0]); o[1] = f32_bf16_hw(q0[1]); o[2] = f32_bf16_hw(q0[2]); o[3] = f32_bf16_hw(q0[3]);
    o[4] = f32_bf16_hw(q1[0]); o[5] = f32_bf16_hw(q1[1]); o[6] = f32_bf16_hw(q1[2]); o[7] = f32_bf16_hw(q1[3]);
    *(short8b*)(xb + (size_t)i * 8) = o;      // cacheable: phaseA re-reads it
    return;
  }
  __shared__ int lh[NREL + 1], lbase[NREL + 1];
  __shared__ int bh[NB];
  if (tid <= NREL) lh[tid] = 0;
  if (tid < NB) bh[tid] = 0;
  __syncthreads();
  int base = b * 1024 + tid;
  bool isE[4], isN[4];
  int r4[4], loff[4], loffN[4];
#pragma unroll
  for (int k = 0; k < 4; ++k) {
    int i = base + k * 256;
    isE[k] = i < nE;
    isN[k] = (i < nN) && mask[i];
    if (isE[k]) {
      r4[k] = et[i];
      int s_ = src[i], t_ = tgt[i];
      loff[k] = atomicAdd(&lh[r4[k]], 2);
      atomicAdd(&bh[t_ >> 10], 1);
      atomicAdd(&bh[s_ >> 10], 1);
    }
    if (isN[k]) loffN[k] = atomicAdd(&lh[NREL], 1);
  }
  __syncthreads();
  if (tid <= NREL)
    lbase[tid] = lh[tid] ? atomicAdd(&cntr[tid], lh[tid]) : 0;
  if (tid < NB) H[b * NB + tid] = bh[tid];
  __syncthreads();
#pragma unroll
  for (int k = 0; k < 4; ++k) {
    int i = base + k * 256;
    if (isE[k]) __builtin_nontemporal_store(lbase[r4[k]] + loff[k], reloff + i);
    if (isN[k]) __builtin_nontemporal_store(lbase[NREL] + loffN[k], noff + i);
  }
}

// K2: per bucket b, scan H[blk][b] over blocks -> baseM[blk][b]; region placed
// via one atomicAdd per bucket (order of regions irrelevant).
__global__ __launch_bounds__(256) void k_base(const int* __restrict__ H,
                                              int* __restrict__ baseM,
                                              int* __restrict__ regStart,
                                              int* __restrict__ regTot,
                                              int* __restrict__ gcur2) {
  int b = blockIdx.x;
  int tid = threadIdx.x;
  int lane = tid & 63, wid = tid >> 6;
  int vals[4]; int ts = 0;
#pragma unroll
  for (int k = 0; k < 4; ++k) {
    int idx = tid * 4 + k;
    vals[k] = (idx < CNT_BLOCKS) ? H[idx * NB + b] : 0;
    ts += vals[k];
  }
  int incl = ts;
  for (int off = 1; off < 64; off <<= 1) {
    int n = __shfl_up(incl, off, 64);
    if (lane >= off) incl += n;
  }
  __shared__ int wsum[4];
  __shared__ int s_start;
  if (lane == 63) wsum[wid] = incl;
  __syncthreads();
  if (tid == 0) {
    int t0 = wsum[0], t1 = wsum[1], t2 = wsum[2], t3 = wsum[3];
    int tot = t0 + t1 + t2 + t3;
    int st = atomicAdd(gcur2, tot);
    regStart[b] = st;
    regTot[b] = tot;
    s_start = st;
    wsum[0] = 0; wsum[1] = t0; wsum[2] = t0 + t1; wsum[3] = t0 + t1 + t2;
  }
  __syncthreads();
  int run = s_start + wsum[wid] + incl - ts;
#pragma unroll
  for (int k = 0; k < 4; ++k) {
    int idx = tid * 4 + k;
    if (idx < CNT_BLOCKS) {
      baseM[idx * NB + b] = run;
      run += vals[k];
    }
  }
}

// K3: scatter endpoint records into bucket regions. LDS hist allocates the
// local offset; record packs (v&1023)<<21 | itemid (itemid = 2*i + side).
__global__ __launch_bounds__(256) void k_scat(const int* __restrict__ src,
                                              const int* __restrict__ tgt,
                                              const int* __restrict__ baseM,
                                              int* __restrict__ scratch,
                                              int nE) {
  int b = blockIdx.x;
  int tid = threadIdx.x;
  __shared__ int bh[NB];
  __shared__ int bb[NB];
  if (tid < NB) { bh[tid] = 0; bb[tid] = baseM[b * NB + tid]; }
  __syncthreads();
#pragma unroll
  for (int k = 0; k < 4; ++k) {
    int i = b * 1024 + k * 256 + tid;
    if (i < nE) {
      int t_ = tgt[i], s_ = src[i];
      int offT = atomicAdd(&bh[t_ >> 10], 1);
      scratch[bb[t_ >> 10] + offT] = ((t_ & 1023) << 21) | (2 * i);
      int offS = atomicAdd(&bh[s_ >> 10], 1);
      scratch[bb[s_ >> 10] + offS] = ((s_ & 1023) << 21) | (2 * i + 1);
    }
  }
}

// K4: one block per bucket; LDS counters assign slots; write eslot + cntv.
__global__ __launch_bounds__(256) void k_slot(const int* __restrict__ scratch,
                                              const int* __restrict__ regStart,
                                              const int* __restrict__ regTot,
                                              int* __restrict__ eslot,
                                              int* __restrict__ cntv,
                                              int nN) {
  int b = blockIdx.x;
  int tid = threadIdx.x;
  __shared__ int cnt[1024];
#pragma unroll
  for (int k = 0; k < 4; ++k) cnt[tid + k * 256] = 0;
  __syncthreads();
  int start = regStart[b];
  int tot = regTot[b];
  for (int it = tid; it < tot; it += 256) {
    int rec = scratch[start + it];
    int off = atomicAdd(&cnt[rec >> 21], 1);
    eslot[rec & 0x1FFFFF] = off;
  }
  __syncthreads();
#pragma unroll
  for (int k = 0; k < 4; ++k) {
    int v = b * 1024 + k * 256 + tid;
    if (v < nN) cntv[v] = cnt[k * 256 + tid];
  }
}

// Fused: bucket-prefix + rstart publish + tileRel + pad-records (blocks 0..439)
// and per-target segment scan (blocks 440..1221).
#define PREP_BLOCKS 440
#define VSEG_BLOCKS 782
__global__ __launch_bounds__(256) void k_scan(const int* __restrict__ cntr,
                                              int* __restrict__ rstart_g,
                                              uint8_t* __restrict__ tileRel,
                                              int2* __restrict__ recs,
                                              const int* __restrict__ cntv,
                                              const int* __restrict__ mask,
                                              int* __restrict__ vstart,
                                              int* __restrict__ cntt,
                                              int* __restrict__ gcur,
                                              int maxTiles, int nN) {
  int b = blockIdx.x;
  if (b < PREP_BLOCKS) {
    __shared__ int s[NREL + 2];
    if (threadIdx.x == 0) {
      int base = 0;
      for (int r = 0; r <= NREL; ++r) {
        s[r] = base;
        base = (base + cntr[r] + 15) & ~15;
      }
      s[NREL + 1] = base;
    }
    __syncthreads();
    if (b == 0) {
      if (threadIdx.x <= NREL + 1) rstart_g[threadIdx.x] = s[threadIdx.x];
      for (int w = threadIdx.x; w < (NREL + 1) * 16; w += 256) {
        int r = w >> 4, j = w & 15;
        int pos = s[r] + cntr[r] + j;
        if (pos < s[r + 1]) recs[pos] = make_int2(-1, -1);
      }
    }
    int t = b * 256 + threadIdx.x;
    if (t < maxTiles) {
      int p = t * 16;
      uint8_t rr = 255;
      if (p < s[NREL + 1]) {
        int q = 0;
        for (int k = 1; k <= NREL; ++k)
          if (p >= s[k]) q = k;
        rr = (uint8_t)q;
      }
      tileRel[t] = rr;
    }
  } else {
    __shared__ int wsum[4];
    __shared__ int s_base;
    int v = (b - PREP_BLOCKS) * 256 + threadIdx.x;
    int lane = threadIdx.x & 63;
    int wid = threadIdx.x >> 6;
    int c = 0;
    if (v < nN) c = cntv[v] + (mask[v] ? 1 : 0);
    int incl = c;
    for (int off = 1; off < 64; off <<= 1) {
      int n = __shfl_up(incl, off, 64);
      if (lane >= off) incl += n;
    }
    if (lane == 63) wsum[wid] = incl;
    __syncthreads();
    if (threadIdx.x == 0) {
      int t0 = wsum[0], t1 = wsum[1], t2 = wsum[2], t3 = wsum[3];
      s_base = atomicAdd(gcur, t0 + t1 + t2 + t3);
      wsum[0] = 0;
      wsum[1] = t0;
      wsum[2] = t0 + t1;
      wsum[3] = t0 + t1 + t2;
    }
    __syncthreads();
    if (v < nN) {
      vstart[v] = s_base + wsum[wid] + incl - c;
      cntt[v] = c;
    }
  }
}

// Record construction: ZERO atomics.
__global__ __launch_bounds__(256) void k_write(const int* __restrict__ src,
                                               const int* __restrict__ tgt,
                                               const int* __restrict__ et,
                                               const int* __restrict__ mask,
                                               const int* __restrict__ reloff,
                                               const int* __restrict__ noff,
                                               const int* __restrict__ eslot,
                                               const int* __restrict__ rstart,
                                               const int* __restrict__ cntv,
                                               const int* __restrict__ vstart,
                                               int2* __restrict__ recs,
                                               int nE, int nN) {
  __shared__ int s_rs[NREL + 1];
  if (threadIdx.x <= NREL) s_rs[threadIdx.x] = rstart[threadIdx.x];
  __syncthreads();
  int i = blockIdx.x * 256 + threadIdx.x;
  if (i < nE) {
    int r = et[i];
    int rl = __builtin_nontemporal_load(reloff + i);
    long long ev = __builtin_nontemporal_load((const long long*)(eslot + 2 * i));
    int o1 = (int)(ev & 0xFFFFFFFFll);        // tgt-side slot (itemid 2i)
    int o2 = (int)(ev >> 32);                 // src-side slot (itemid 2i+1)
    int s_ = src[i], t_ = tgt[i];
    int pos = s_rs[r] + rl;                   // even -> 16B aligned
    int s1 = vstart[t_] + o1;                 // msg (s_ -> t_)
    int s2 = vstart[s_] + o2;                 // msg (t_ -> s_)
    *(int4*)(recs + pos) = make_int4(s_, s1, t_, s2);
  }
  if (i < nN && mask[i]) {
    int pos = s_rs[NREL] + noff[i];
    int slot = vstart[i] + cntv[i];           // self takes the last slot
    recs[pos] = make_int2(i, slot);
  }
}

// Phase A: relation-grouped MFMA over bf16 x-table; 4-deep prefetch of
// tileRel/recs/xb fragments at wave entry breaks the per-tile serial chain.
// LDS is wave-private: in-wave DS ordering + lgkmcnt + sched_barrier (rule #18).
__global__ __launch_bounds__(256) void k_phaseA(const uint16_t* __restrict__ xb,
                                                const int2* __restrict__ recs,
                                                const uint16_t* __restrict__ Wt,
                                                const uint8_t* __restrict__ tileRel,
                                                uint16_t* __restrict__ msg,
                                                int ntiles) {
  __shared__ uint16_t s_m[4][16 * 72];   // +8 elem row pad
  __shared__ int s_slot[4][16];
  const int wid = threadIdx.x >> 6;
  const int lane = threadIdx.x & 63;
  const int quad = lane >> 4;
  const int m16 = lane & 15;
  const int t0 = (blockIdx.x * 4 + wid) * 4;

  if (tileRel[t0] == 255) return;        // wave-uniform tail exit (tileRel monotonic)

  // ---- prefetch: tileRel, recs, xb fragments for all 4 tiles ----
  int rel4[4];
#pragma unroll
  for (int it = 0; it < 4; ++it) {
    int t = t0 + it;
    rel4[it] = (t < ntiles) ? (int)tileRel[t] : 255;
  }
  int2 rec4[4];
#pragma unroll
  for (int it = 0; it < 4; ++it) {
    if (rel4[it] != 255) {
      long long rv = __builtin_nontemporal_load((const long long*)(recs + (t0 + it) * 16 + m16));
      rec4[it].x = (int)(rv & 0xFFFFFFFFll);
      rec4[it].y = (int)(rv >> 32);
    } else {
      rec4[it] = make_int2(-1, -1);
    }
  }
  short8b a0_[4], a1_[4];
#pragma unroll
  for (int it = 0; it < 4; ++it) {
    int u = rec4[it].x < 0 ? 0 : rec4[it].x;
    const uint16_t* xp = xb + (size_t)u * 64 + quad * 8;
    a0_[it] = *(const short8b*)(xp);
    a1_[it] = *(const short8b*)(xp + 32);
  }

  int curRel = -1;
  short8b bfrag[4][2] = {};

#pragma unroll
  for (int it = 0; it < 4; ++it) {
    int rel = rel4[it];
    if (rel == 255) continue;            // wave-uniform

    if (rel != curRel) {
      curRel = rel;
      const uint16_t* wbase = Wt + (size_t)rel * 4096;
      for (int nt = 0; nt < 4; ++nt)
        for (int kt = 0; kt < 2; ++kt)
          bfrag[nt][kt] = *(const short8b*)(wbase + (size_t)(nt * 16 + m16) * 64 + kt * 32 + quad * 8);
    }

    float4v acc[4];
    for (int nt = 0; nt < 4; ++nt) { acc[nt][0] = 0.f; acc[nt][1] = 0.f; acc[nt][2] = 0.f; acc[nt][3] = 0.f; }
    for (int nt = 0; nt < 4; ++nt) {
      acc[nt] = __builtin_amdgcn_mfma_f32_16x16x32_bf16(a0_[it], bfrag[nt][0], acc[nt], 0, 0, 0);
      acc[nt] = __builtin_amdgcn_mfma_f32_16x16x32_bf16(a1_[it], bfrag[nt][1], acc[nt], 0, 0, 0);
    }

    // C/D: col(dim) = m16 + nt*16, row(message) = quad*4 + reg
    if (quad == 0) s_slot[wid][m16] = rec4[it].y;
    for (int reg = 0; reg < 4; ++reg)
      for (int nt = 0; nt < 4; ++nt)
        s_m[wid][(quad * 4 + reg) * 72 + nt * 16 + m16] = f32_bf16_hw(acc[nt][reg]);

    asm volatile("s_waitcnt lgkmcnt(0)" ::: "memory");
    __builtin_amdgcn_sched_barrier(0);

    // 16 rows x 128 B, 8 lanes/row x 16 B; msg is write-once streaming -> nt
    for (int p = 0; p < 2; ++p) {
      int row = (lane >> 3) + p * 8;
      int slot = s_slot[wid][row];
      if (slot >= 0) {
        const uint16_t* lp = &s_m[wid][row * 72 + (lane & 7) * 8];
        int4v val = *(const int4v*)lp;
        __builtin_nontemporal_store(val, (int4v*)(msg + (size_t)slot * 64 + (lane & 7) * 8));
      }
    }
    __builtin_amdgcn_sched_barrier(0);   // keep next iter's ds_writes after these reads
  }
}

// Phase B: per-target segmented sum. 8 lanes/target, nt 16 B loads.
__global__ __launch_bounds__(256) void k_phaseB(const uint16_t* __restrict__ msg,
                                                const int* __restrict__ cntt,
                                                const int* __restrict__ vstart,
                                                float* __restrict__ out, int nN) {
  int v = blockIdx.x * 32 + (threadIdx.x >> 3);
  int l = threadIdx.x & 7;
  if (v >= nN) return;
  int cnt = cntt[v];
  int base = vstart[v];
  float a[8] = {0.f, 0.f, 0.f, 0.f, 0.f, 0.f, 0.f, 0.f};
  const uint16_t* mp = msg + (size_t)base * 64 + l * 8;
  int j = 0;
  for (; j + 2 <= cnt; j += 2) {
    int4v r0 = __builtin_nontemporal_load((const int4v*)(mp + (size_t)j * 64));
    int4v r1 = __builtin_nontemporal_load((const int4v*)(mp + (size_t)(j + 1) * 64));
    short8b h0 = __builtin_bit_cast(short8b, r0);
    short8b h1 = __builtin_bit_cast(short8b, r1);
#pragma unroll
    for (int k = 0; k < 8; ++k)
      a[k] += bf2f((uint16_t)h0[k]) + bf2f((uint16_t)h1[k]);
  }
  if (j < cnt) {
    int4v r0 = __builtin_nontemporal_load((const int4v*)(mp + (size_t)j * 64));
    short8b h = __builtin_bit_cast(short8b, r0);
#pragma unroll
    for (int k = 0; k < 8; ++k)
      a[k] += bf2f((uint16_t)h[k]);
  }
  float* op = out + (size_t)v * 64 + l * 8;
  float4v o0, o1;
  o0[0] = a[0]; o0[1] = a[1]; o0[2] = a[2]; o0[3] = a[3];
  o1[0] = a[4]; o1[1] = a[5]; o1[2] = a[6]; o1[3] = a[7];
  __builtin_nontemporal_store(o0, (float4v*)op);
  __builtin_nontemporal_store(o1, (float4v*)(op + 4));
}

// ======================================================================
// FALLBACK PATH (atomic scatter) — used only if ws_size too small
// ======================================================================
#define F_WS_HIST    0
#define F_WS_CURSOR  64
#define F_WS_START   128
#define F_WS_WT      512
#define F_WS_TILEREL 139776
#define F_WS_RECS    262144
#define F_MAXTILES   112520
#define F_MAXRECS    (F_MAXTILES * 16)

__global__ __launch_bounds__(256) void f_hist(const int* __restrict__ et,
                                              int* __restrict__ hist, int nE) {
  __shared__ int lh[NREL];
  if (threadIdx.x < NREL) lh[threadIdx.x] = 0;
  __syncthreads();
  int i = blockIdx.x * 256 + threadIdx.x;
  if (i < nE) atomicAdd(&lh[et[i]], 2);
  __syncthreads();
  if (threadIdx.x < NREL && lh[threadIdx.x] > 0)
    atomicAdd(&hist[threadIdx.x], lh[threadIdx.x]);
}

__global__ __launch_bounds__(256) void f_prefix(const int* __restrict__ hist,
                                                int* __restrict__ cursor,
                                                int* __restrict__ start,
                                                uint8_t* __restrict__ tileRel,
                                                int nN, int maxTiles) {
  __shared__ int s_start[17];
  if (threadIdx.x == 0) {
    int base = nN;
    for (int r = 0; r < NREL; ++r) {
      s_start[r] = base;
      cursor[r] = base;
      start[r] = base;
      base = (base + hist[r] + 15) & ~15;
    }
    s_start[16] = base;
    start[16] = base;
  }
  __syncthreads();
  int endp = s_start[16];
  for (int t = threadIdx.x; t < maxTiles; t += 256) {
    int p = t * 16;
    uint8_t r;
    if (p < nN) r = 16;
    else if (p >= endp) r = 255;
    else {
      int q = 0;
      for (int k = 1; k < NREL; ++k) if (p >= s_start[k]) q = k;
      r = (uint8_t)q;
    }
    tileRel[t] = r;
  }
}

__global__ __launch_bounds__(256) void f_scatter(const int* __restrict__ src,
                                                 const int* __restrict__ tgt,
                                                 const int* __restrict__ et,
                                                 const int* __restrict__ mask,
                                                 int2* __restrict__ recs,
                                                 int* __restrict__ cursor,
                                                 int nE, int nN) {
  __shared__ int lh[NREL];
  __shared__ int lbase[NREL];
  if (threadIdx.x < NREL) lh[threadIdx.x] = 0;
  __syncthreads();
  int i = blockIdx.x * 256 + threadIdx.x;
  int r = 0, loff = 0;
  bool isEdge = (i < nE);
  if (isEdge) {
    r = et[i];
    loff = atomicAdd(&lh[r], 2);
  }
  __syncthreads();
  if (threadIdx.x < NREL)
    lbase[threadIdx.x] = (lh[threadIdx.x] > 0) ? atomicAdd(&cursor[threadIdx.x], lh[threadIdx.x]) : 0;
  __syncthreads();
  if (isEdge) {
    int pos = lbase[r] + loff;
    int s = src[i], t = tgt[i];
    *(int4*)(recs + pos) = make_int4(s, t, t, s);
  }
  if (i < nN) {
    recs[i] = (mask[i] != 0) ? make_int2(i, i) : make_int2(-1, -1);
  }
}

__global__ __launch_bounds__(256) void f_compute(const float* __restrict__ x,
                                                 const int2* __restrict__ recs,
                                                 const uint16_t* __restrict__ Wt,
                                                 const uint8_t* __restrict__ tileRel,
                                                 float* __restrict__ out,
                                                 int ntiles) {
  const int lane = threadIdx.x & 63;
  const int quad = lane >> 4;
  const int m16 = lane & 15;
  const int wave = blockIdx.x * 4 + (threadIdx.x >> 6);
  const int t0 = wave * 4;

  int curRel = -1;
  short8b bfrag[4][2] = {};

  for (int it = 0; it < 4; ++it) {
    int t = t0 + it;
    if (t >= ntiles) return;
    int rel = tileRel[t];
    if (rel == 255) return;

    if (rel != curRel) {
      curRel = rel;
      const uint16_t* wbase = Wt + (size_t)rel * 4096;
      for (int nt = 0; nt < 4; ++nt)
        for (int kt = 0; kt < 2; ++kt)
          bfrag[nt][kt] = *(const short8b*)(wbase + (size_t)(nt * 16 + m16) * 64 + kt * 32 + quad * 8);
    }

    int2 rec = recs[t * 16 + m16];
    int u = rec.x < 0 ? 0 : rec.x;

    const float* xp = x + (size_t)u * 64 + quad * 8;
    float4v q0 = *(const float4v*)(xp);
    float4v q1 = *(const float4v*)(xp + 4);
    float4v q2 = *(const float4v*)(xp + 32);
    float4v q3 = *(const float4v*)(xp + 36);
    short8b a0, a1;
    a0[0] = f32_bf16(q0[0]); a0[1] = f32_bf16(q0[1]); a0[2] = f32_bf16(q0[2]); a0[3] = f32_bf16(q0[3]);
    a0[4] = f32_bf16(q1[0]); a0[5] = f32_bf16(q1[1]); a0[6] = f32_bf16(q1[2]); a0[7] = f32_bf16(q1[3]);
    a1[0] = f32_bf16(q2[0]); a1[1] = f32_bf16(q2[1]); a1[2] = f32_bf16(q2[2]); a1[3] = f32_bf16(q2[3]);
    a1[4] = f32_bf16(q3[0]); a1[5] = f32_bf16(q3[1]); a1[6] = f32_bf16(q3[2]); a1[7] = f32_bf16(q3[3]);

    float4v acc[4];
    for (int nt = 0; nt < 4; ++nt) { acc[nt][0] = 0.f; acc[nt][1] = 0.f; acc[nt][2] = 0.f; acc[nt][3] = 0.f; }
    for (int nt = 0; nt < 4; ++nt) {
      acc[nt] = __builtin_amdgcn_mfma_f32_16x16x32_bf16(a0, bfrag[nt][0], acc[nt], 0, 0, 0);
      acc[nt] = __builtin_amdgcn_mfma_f32_16x16x32_bf16(a1, bfrag[nt][1], acc[nt], 0, 0, 0);
    }

    int tg[4];
    for (int reg = 0; reg < 4; ++reg)
      tg[reg] = __shfl(rec.y, quad * 4 + reg, 64);
    for (int reg = 0; reg < 4; ++reg) {
      if (tg[reg] < 0) continue;
      float* op = out + (size_t)tg[reg] * 64 + m16;
      for (int nt = 0; nt < 4; ++nt)
        __hip_atomic_fetch_add(op + nt * 16, acc[nt][reg], __ATOMIC_RELAXED, __HIP_MEMORY_SCOPE_AGENT);
    }
  }
}

// ======================================================================
extern "C" void kernel_launch(void* const* d_in, const int* in_sizes, int n_in,
                              void* d_out, int out_size, void* d_ws, size_t ws_size,
                              hipStream_t stream) {
  const float* x     = (const float*)d_in[0];
  const int*   mask  = (const int*)d_in[1];
  const int*   src   = (const int*)d_in[2];
  const int*   tgt   = (const int*)d_in[3];
  const int*   et    = (const int*)d_in[4];
  const float* bases = (const float*)d_in[5];
  const float* att   = (const float*)d_in[6];
  float* out = (float*)d_out;
  char* ws = (char*)d_ws;

  if (ws_size >= WS_TOTAL) {
    // ---------- two-phase target-sorted path ----------
    int*      cntr    = (int*)(ws + WS_CNTR);
    int*      gcur2   = (int*)(ws + WS_GCUR2);
    int*      rstart  = (int*)(ws + WS_RSTART);
    int*      gcur    = (int*)(ws + WS_GCUR);
    uint16_t* Wt      = (uint16_t*)(ws + WS_WT);
    uint8_t*  tileRel = (uint8_t*)(ws + WS_TILEREL);
    int*      cntv    = (int*)(ws + WS_CNTV);
    int*      vstart  = (int*)(ws + WS_VSTART);
    int*      cntt    = (int*)(ws + WS_CNTT);
    int2*     recs    = (int2*)(ws + WS_RECS);
    uint16_t* msg     = (uint16_t*)(ws + WS_MSG);
    int*      reloff  = (int*)(ws + TR_RELOFF);
    int*      noff    = (int*)(ws + TR_NOFF);
    int*      eslot   = (int*)(ws + TR_ESLOT);
    int*      scratch = (int*)(ws + TR_SCRATCH);
    int*      H       = (int*)(ws + TR_H);
    int*      baseM   = (int*)(ws + TR_BASE);
    int*      regStart= (int*)(ws + TR_REGS);
    int*      regTot  = regStart + NB;
    uint16_t* xb      = (uint16_t*)out;           // bf16 x-table in dead output

    k_init<<<274, 256, 0, stream>>>(bases, att, Wt, (int*)ws);
    k_count<<<CNT_BLOCKS + CAST_BLOCKS, 256, 0, stream>>>(src, tgt, et, mask, cntr, H, reloff, noff, x, xb, N_EDGES, N_NODES);
    k_base<<<NB, 256, 0, stream>>>(H, baseM, regStart, regTot, gcur2);
    k_scat<<<CNT_BLOCKS, 256, 0, stream>>>(src, tgt, baseM, scratch, N_EDGES);
    k_slot<<<NB, 256, 0, stream>>>(scratch, regStart, regTot, eslot, cntv, N_NODES);
    k_scan<<<PREP_BLOCKS + VSEG_BLOCKS, 256, 0, stream>>>(cntr, rstart, tileRel, recs, cntv, mask, vstart, cntt, gcur, MAXTILES, N_NODES);
    k_write<<<(N_EDGES + 255) / 256, 256, 0, stream>>>(src, tgt, et, mask, reloff, noff, eslot, rstart, cntv, vstart, recs, N_EDGES, N_NODES);
    k_phaseA<<<(MAXTILES + 15) / 16, 256, 0, stream>>>(xb, recs, Wt, tileRel, msg, MAXTILES);
    k_phaseB<<<(N_NODES + 31) / 32, 256, 0, stream>>>(msg, cntt, vstart, out, N_NODES);
  } else {
    // ---------- fallback: atomic path ----------
    int*      hist    = (int*)(ws + F_WS_HIST);
    int*      cursor  = (int*)(ws + F_WS_CURSOR);
    int*      start   = (int*)(ws + F_WS_START);
    uint16_t* Wt      = (uint16_t*)(ws + F_WS_WT);
    uint8_t*  tileRel = (uint8_t*)(ws + F_WS_TILEREL);
    int2*     recs    = (int2*)(ws + F_WS_RECS);

    (void)hipMemsetAsync(out, 0, (size_t)N_NODES * 64 * sizeof(float), stream);
    (void)hipMemsetAsync(ws, 0, 512, stream);
    (void)hipMemsetAsync(recs, 0xFF, (size_t)F_MAXRECS * sizeof(int2), stream);

    k_wprep<<<(17 * 64 * 64 + 255) / 256, 256, 0, stream>>>(bases, att, Wt);
    f_hist<<<(N_EDGES + 255) / 256, 256, 0, stream>>>(et, hist, N_EDGES);
    f_prefix<<<1, 256, 0, stream>>>(hist, cursor, start, tileRel, N_NODES, F_MAXTILES);
    f_scatter<<<(N_EDGES + 255) / 256, 256, 0, stream>>>(src, tgt, et, mask, recs, cursor, N_EDGES, N_NODES);
    f_compute<<<(F_MAXTILES + 15) / 16, 256, 0, stream>>>(x, recs, Wt, tileRel, out, F_MAXTILES);
  }
}

// Round 8
// 298.751 us; speedup vs baseline: 1.5933x; 1.0333x over previous
//
#include <hip/hip_runtime.h>
#include <hip/hip_bf16.h>
#include <stdint.h>
#include <stddef.h>

#define N_NODES 200000
#define N_EDGES 800000
#define NREL 16
#define NBASES 8

typedef __attribute__((ext_vector_type(8))) short short8b;
typedef __attribute__((ext_vector_type(4))) float float4v;
typedef __attribute__((ext_vector_type(4))) int int4v;

__device__ __forceinline__ short f32_bf16(float f) {
  uint32_t u = __builtin_bit_cast(uint32_t, f);
  uint32_t r = u + 0x7FFFu + ((u >> 16) & 1u);
  return (short)(uint16_t)(r >> 16);
}
// hardware RNE conversion (gfx950); same rounding as the manual version
__device__ __forceinline__ uint16_t f32_bf16_hw(float f) {
  __hip_bfloat16 h = __float2bfloat16(f);
  return __builtin_bit_cast(uint16_t, h);
}
__device__ __forceinline__ float bf2f(uint16_t h) {
  return __builtin_bit_cast(float, (uint32_t)h << 16);
}

// ============================ shared: W table ============================
__global__ __launch_bounds__(256) void k_wprep(const float* __restrict__ bases,
                                               const float* __restrict__ att,
                                               uint16_t* __restrict__ Wt) {
  int i = blockIdx.x * 256 + threadIdx.x;
  if (i >= 17 * 64 * 64) return;
  int r = i >> 12;
  int e = (i >> 6) & 63;
  int d = i & 63;
  float acc = 0.f;
  for (int b = 0; b < NBASES; ++b)
    acc += att[r * NBASES + b] * bases[b * 4096 + d * 64 + e];
  Wt[i] = (uint16_t)f32_bf16(acc);
}

// ======================================================================
// MAIN PATH: two-phase target-sorted, ZERO scattered global atomics.
//   K1 k_count : per-block bucket histograms H + relation offsets (+x cast)
//   K2 k_base  : column scan of H -> bases | relation prefix + tileRel + pads
//   K3 k_scat  : scatter packed endpoint records into bucket regions
//   K4 k_slot  : per-bucket LDS counters + per-node segment scan ->
//                eslot = ABSOLUTE msg slots, vstart/cntt, self-loop records
//   K5 k_write : edge records, pure coalesced streaming (no gathers)
// xb (bf16 x copy) lives in the dead first half of the output buffer.
// All transients live at the head of the msg region (dead before phaseA).
// ======================================================================
#define MAXTILES 112528
#define MAXRECS  (MAXTILES * 16)
#define NB 196                 // node buckets of 1024 (196*1024 >= 200000)
#define CNT_BLOCKS  782        // ceil(800000/1024) edge blocks (4 edges/thread)
#define CAST_BLOCKS 6250
#define PREP_BLOCKS 440        // tileRel blocks appended to k_base
#define WS_CNTR    0          // 32 int
#define WS_GCUR2   128        // 1 int (bucket-region allocator)
#define WS_RSTART  256        // 18 int, written by k_base, read by k_slot/k_write
#define WS_GCUR    384        // 1 int (segment allocator)
#define WS_WT      512        // 17*64*64 u16 -> ends 139776
#define WS_TILEREL 139776     // MAXTILES u8 -> ends 252304 (pad to 252416)
#define WS_VSTART  1052416    // 200000 int
#define WS_CNTT    1852416    // 200000 int (total counts incl self)
#define WS_RECS    2652416    // MAXRECS int2 -> ends 17056000 (pad to 17056128)
#define WS_MSG     17056128   // MAXRECS * 64 u16 rows
#define WS_TOTAL   (WS_MSG + (size_t)MAXRECS * 128)   // ~247.5 MB
// transients inside msg region (consumed by k_write before phaseA):
#define TR_RELOFF  WS_MSG                      // E int   = 3.2 MB
#define TR_NOFF    (TR_RELOFF + 3200000)       // N int   = 0.8 MB
#define TR_ESLOT   (TR_NOFF + 800000)          // 2E int  = 6.4 MB (absolute slots)
#define TR_SCRATCH (TR_ESLOT + 6400000)        // 2E int  = 6.4 MB
#define TR_H       (TR_SCRATCH + 6400000)      // 782*196 int
#define TR_BASE    (TR_H + 613088)             // 782*196 int
#define TR_REGS    (TR_BASE + 613088)          // 2*196 int (regStart, regTot)

// Fused: Wt prep (0..272) | zero 512B control head (block 273)
__global__ __launch_bounds__(256) void k_init(const float* __restrict__ bases,
                                              const float* __restrict__ att,
                                              uint16_t* __restrict__ Wt,
                                              int* __restrict__ zero0) {
  int b = blockIdx.x;
  int tid = threadIdx.x;
  if (b < 273) {
    int i = b * 256 + tid;
    if (i < 17 * 64 * 64) {
      int r = i >> 12;
      int e = (i >> 6) & 63;
      int d = i & 63;
      float acc = 0.f;
      for (int bb = 0; bb < NBASES; ++bb)
        acc += att[r * NBASES + bb] * bases[bb * 4096 + d * 64 + e];
      Wt[i] = (uint16_t)f32_bf16(acc);
    }
  } else {
    if (tid < 128) zero0[tid] = 0;   // cntr/gcur2/rstart/gcur region
  }
}

// K1: edge blocks (0..781, 4 edges/thread) + x->bf16 cast blocks.
// LDS-only histograms; global atomics: 17 relation counters per block.
__global__ __launch_bounds__(256) void k_count(const int* __restrict__ src,
                                               const int* __restrict__ tgt,
                                               const int* __restrict__ et,
                                               const int* __restrict__ mask,
                                               int* __restrict__ cntr,
                                               int* __restrict__ H,
                                               int* __restrict__ reloff,
                                               int* __restrict__ noff,
                                               const float* __restrict__ x,
                                               uint16_t* __restrict__ xb,
                                               int nE, int nN) {
  int b = blockIdx.x;
  int tid = threadIdx.x;
  if (b >= CNT_BLOCKS) {
    int i = (b - CNT_BLOCKS) * 256 + tid;   // exact: i < 1,600,000
    const float* xp = x + (size_t)i * 8;
    float4v q0 = __builtin_nontemporal_load((const float4v*)xp);
    float4v q1 = __builtin_nontemporal_load((const float4v*)(xp + 4));
    short8b o;
    o[0] = f32_bf16_hw(q0[0]); o[1] = f32_bf16_hw(q0[1]); o[2] = f32_bf16_hw(q0[2]); o[3] = f32_bf16_hw(q0[3]);
    o[4] = f32_bf16_hw(q1[0]); o[5] = f32_bf16_hw(q1[1]); o[6] = f32_bf16_hw(q1[2]); o[7] = f32_bf16_hw(q1[3]);
    *(short8b*)(xb + (size_t)i * 8) = o;      // cacheable: phaseA re-reads it
    return;
  }
  __shared__ int lh[NREL + 1], lbase[NREL + 1];
  __shared__ int bh[NB];
  if (tid <= NREL) lh[tid] = 0;
  if (tid < NB) bh[tid] = 0;
  __syncthreads();
  int base = b * 1024 + tid;
  bool isE[4], isN[4];
  int r4[4], loff[4], loffN[4];
#pragma unroll
  for (int k = 0; k < 4; ++k) {
    int i = base + k * 256;
    isE[k] = i < nE;
    isN[k] = (i < nN) && mask[i];
    if (isE[k]) {
      r4[k] = et[i];
      int s_ = src[i], t_ = tgt[i];
      loff[k] = atomicAdd(&lh[r4[k]], 2);
      atomicAdd(&bh[t_ >> 10], 1);
      atomicAdd(&bh[s_ >> 10], 1);
    }
    if (isN[k]) loffN[k] = atomicAdd(&lh[NREL], 1);
  }
  __syncthreads();
  if (tid <= NREL)
    lbase[tid] = lh[tid] ? atomicAdd(&cntr[tid], lh[tid]) : 0;
  if (tid < NB) H[b * NB + tid] = bh[tid];
  __syncthreads();
#pragma unroll
  for (int k = 0; k < 4; ++k) {
    int i = base + k * 256;
    if (isE[k]) __builtin_nontemporal_store(lbase[r4[k]] + loff[k], reloff + i);
    if (isN[k]) __builtin_nontemporal_store(lbase[NREL] + loffN[k], noff + i);
  }
}

// K2: blocks 0..NB-1: per-bucket column scan of H -> baseM; blocks NB..NB+439:
// relation bucket-prefix + rstart publish + tileRel + pad-record writes.
__global__ __launch_bounds__(256) void k_base(const int* __restrict__ H,
                                              int* __restrict__ baseM,
                                              int* __restrict__ regStart,
                                              int* __restrict__ regTot,
                                              int* __restrict__ gcur2,
                                              const int* __restrict__ cntr,
                                              int* __restrict__ rstart_g,
                                              uint8_t* __restrict__ tileRel,
                                              int2* __restrict__ recs,
                                              int maxTiles) {
  int tid = threadIdx.x;
  if (blockIdx.x >= NB) {
    int bp = blockIdx.x - NB;
    __shared__ int s[NREL + 2];
    if (tid == 0) {
      int base = 0;
      for (int r = 0; r <= NREL; ++r) {
        s[r] = base;
        base = (base + cntr[r] + 15) & ~15;
      }
      s[NREL + 1] = base;
    }
    __syncthreads();
    if (bp == 0) {
      if (tid <= NREL + 1) rstart_g[tid] = s[tid];
      for (int w = tid; w < (NREL + 1) * 16; w += 256) {
        int r = w >> 4, j = w & 15;
        int pos = s[r] + cntr[r] + j;
        if (pos < s[r + 1]) recs[pos] = make_int2(-1, -1);
      }
    }
    int t = bp * 256 + tid;
    if (t < maxTiles) {
      int p = t * 16;
      uint8_t rr = 255;
      if (p < s[NREL + 1]) {
        int q = 0;
        for (int k = 1; k <= NREL; ++k)
          if (p >= s[k]) q = k;
        rr = (uint8_t)q;
      }
      tileRel[t] = rr;
    }
    return;
  }
  int b = blockIdx.x;
  int lane = tid & 63, wid = tid >> 6;
  int vals[4]; int ts = 0;
#pragma unroll
  for (int k = 0; k < 4; ++k) {
    int idx = tid * 4 + k;
    vals[k] = (idx < CNT_BLOCKS) ? H[idx * NB + b] : 0;
    ts += vals[k];
  }
  int incl = ts;
  for (int off = 1; off < 64; off <<= 1) {
    int n = __shfl_up(incl, off, 64);
    if (lane >= off) incl += n;
  }
  __shared__ int wsum[4];
  __shared__ int s_start;
  if (lane == 63) wsum[wid] = incl;
  __syncthreads();
  if (tid == 0) {
    int t0 = wsum[0], t1 = wsum[1], t2 = wsum[2], t3 = wsum[3];
    int tot = t0 + t1 + t2 + t3;
    int st = atomicAdd(gcur2, tot);
    regStart[b] = st;
    regTot[b] = tot;
    s_start = st;
    wsum[0] = 0; wsum[1] = t0; wsum[2] = t0 + t1; wsum[3] = t0 + t1 + t2;
  }
  __syncthreads();
  int run = s_start + wsum[wid] + incl - ts;
#pragma unroll
  for (int k = 0; k < 4; ++k) {
    int idx = tid * 4 + k;
    if (idx < CNT_BLOCKS) {
      baseM[idx * NB + b] = run;
      run += vals[k];
    }
  }
}

// K3: scatter endpoint records into bucket regions. LDS hist allocates the
// local offset; record packs (v&1023)<<21 | itemid (itemid = 2*i + side).
__global__ __launch_bounds__(256) void k_scat(const int* __restrict__ src,
                                              const int* __restrict__ tgt,
                                              const int* __restrict__ baseM,
                                              int* __restrict__ scratch,
                                              int nE) {
  int b = blockIdx.x;
  int tid = threadIdx.x;
  __shared__ int bh[NB];
  __shared__ int bb[NB];
  if (tid < NB) { bh[tid] = 0; bb[tid] = baseM[b * NB + tid]; }
  __syncthreads();
#pragma unroll
  for (int k = 0; k < 4; ++k) {
    int i = b * 1024 + k * 256 + tid;
    if (i < nE) {
      int t_ = tgt[i], s_ = src[i];
      int offT = atomicAdd(&bh[t_ >> 10], 1);
      scratch[bb[t_ >> 10] + offT] = ((t_ & 1023) << 21) | (2 * i);
      int offS = atomicAdd(&bh[s_ >> 10], 1);
      scratch[bb[s_ >> 10] + offS] = ((s_ & 1023) << 21) | (2 * i + 1);
    }
  }
}

// K4: one block per 1024-node bucket. Pass 1 counts into LDS; block scan of
// (cnt+mask) allocates per-node segments (one gcur atomicAdd per block);
// pass 2 assigns ABSOLUTE msg slots into eslot; emits vstart/cntt and the
// self-loop records (self slot = end of segment). Replaces old k_slot + vseg.
__global__ __launch_bounds__(256) void k_slot(const int* __restrict__ scratch,
                                              const int* __restrict__ regStart,
                                              const int* __restrict__ regTot,
                                              const int* __restrict__ mask,
                                              const int* __restrict__ noff,
                                              const int* __restrict__ rstart,
                                              int* __restrict__ eslot,
                                              int* __restrict__ vstart,
                                              int* __restrict__ cntt,
                                              int* __restrict__ gcur,
                                              int2* __restrict__ recs,
                                              int nN) {
  int b = blockIdx.x;
  int tid = threadIdx.x;
  __shared__ int cnt[1024];
  __shared__ int sabs[1024];
  __shared__ int wsum[4];
  __shared__ int s_base, s_rs16;
#pragma unroll
  for (int k = 0; k < 4; ++k) cnt[tid + k * 256] = 0;
  if (tid == 0) s_rs16 = rstart[NREL];
  __syncthreads();
  int start = regStart[b];
  int tot = regTot[b];
  for (int it = tid; it < tot; it += 256)
    atomicAdd(&cnt[scratch[start + it] >> 21], 1);
  __syncthreads();
  int lane = tid & 63, wid = tid >> 6;
  int vals[4]; int ts = 0;
#pragma unroll
  for (int k = 0; k < 4; ++k) {
    int j = tid * 4 + k;
    int v = b * 1024 + j;
    int m = (v < nN) ? (mask[v] ? 1 : 0) : 0;
    vals[k] = cnt[j] + m;
    ts += vals[k];
  }
  int incl = ts;
  for (int off = 1; off < 64; off <<= 1) {
    int n = __shfl_up(incl, off, 64);
    if (lane >= off) incl += n;
  }
  if (lane == 63) wsum[wid] = incl;
  __syncthreads();
  if (tid == 0) {
    int t0 = wsum[0], t1 = wsum[1], t2 = wsum[2], t3 = wsum[3];
    s_base = atomicAdd(gcur, t0 + t1 + t2 + t3);
    wsum[0] = 0; wsum[1] = t0; wsum[2] = t0 + t1; wsum[3] = t0 + t1 + t2;
  }
  __syncthreads();
  int run = s_base + wsum[wid] + incl - ts;
#pragma unroll
  for (int k = 0; k < 4; ++k) {
    int j = tid * 4 + k;
    sabs[j] = run;
    int v = b * 1024 + j;
    if (v < nN) { vstart[v] = run; cntt[v] = vals[k]; }
    run += vals[k];
  }
  __syncthreads();
  for (int it = tid; it < tot; it += 256) {
    int rec = scratch[start + it];
    int slot = atomicAdd(&sabs[rec >> 21], 1);
    eslot[rec & 0x1FFFFF] = slot;
  }
  __syncthreads();                       // all slots assigned; sabs = segment end
#pragma unroll
  for (int k = 0; k < 4; ++k) {
    int j = tid * 4 + k;
    int v = b * 1024 + j;
    if (v < nN && mask[v])
      recs[s_rs16 + noff[v]] = make_int2(v, sabs[j]);   // self = last slot
  }
}

// K5: edge records only; pure coalesced streaming, zero gathers/atomics.
__global__ __launch_bounds__(256) void k_write(const int* __restrict__ src,
                                               const int* __restrict__ tgt,
                                               const int* __restrict__ et,
                                               const int* __restrict__ reloff,
                                               const int* __restrict__ eslot,
                                               const int* __restrict__ rstart,
                                               int2* __restrict__ recs,
                                               int nE) {
  __shared__ int s_rs[NREL + 1];
  if (threadIdx.x <= NREL) s_rs[threadIdx.x] = rstart[threadIdx.x];
  __syncthreads();
  int i = blockIdx.x * 256 + threadIdx.x;
  if (i < nE) {
    int r = et[i];
    int rl = __builtin_nontemporal_load(reloff + i);
    long long ev = __builtin_nontemporal_load((const long long*)(eslot + 2 * i));
    int s1 = (int)(ev & 0xFFFFFFFFll);        // abs slot, tgt segment (itemid 2i)
    int s2 = (int)(ev >> 32);                 // abs slot, src segment (itemid 2i+1)
    int s_ = src[i], t_ = tgt[i];
    int pos = s_rs[r] + rl;                   // even -> 16B aligned
    *(int4*)(recs + pos) = make_int4(s_, s1, t_, s2);
  }
}

// Phase A: relation-grouped MFMA over bf16 x-table; 4-deep prefetch +
// double-buffered wave-private LDS transpose (overlap stores with next MFMA).
// LDS is wave-private: in-wave DS ordering + lgkmcnt + sched_barrier (rule #18).
__global__ __launch_bounds__(256) void k_phaseA(const uint16_t* __restrict__ xb,
                                                const int2* __restrict__ recs,
                                                const uint16_t* __restrict__ Wt,
                                                const uint8_t* __restrict__ tileRel,
                                                uint16_t* __restrict__ msg,
                                                int ntiles) {
  __shared__ uint16_t s_m[4][2][16 * 72];   // double buffer, +8 elem row pad
  __shared__ int s_slot[4][2][16];
  const int wid = threadIdx.x >> 6;
  const int lane = threadIdx.x & 63;
  const int quad = lane >> 4;
  const int m16 = lane & 15;
  const int t0 = (blockIdx.x * 4 + wid) * 4;

  if (tileRel[t0] == 255) return;        // wave-uniform tail exit (tileRel monotonic)

  // ---- prefetch: tileRel, recs, xb fragments for all 4 tiles ----
  int rel4[4];
#pragma unroll
  for (int it = 0; it < 4; ++it) {
    int t = t0 + it;
    rel4[it] = (t < ntiles) ? (int)tileRel[t] : 255;
  }
  int2 rec4[4];
#pragma unroll
  for (int it = 0; it < 4; ++it) {
    if (rel4[it] != 255) {
      long long rv = __builtin_nontemporal_load((const long long*)(recs + (t0 + it) * 16 + m16));
      rec4[it].x = (int)(rv & 0xFFFFFFFFll);
      rec4[it].y = (int)(rv >> 32);
    } else {
      rec4[it] = make_int2(-1, -1);
    }
  }
  short8b a0_[4], a1_[4];
#pragma unroll
  for (int it = 0; it < 4; ++it) {
    int u = rec4[it].x < 0 ? 0 : rec4[it].x;
    const uint16_t* xp = xb + (size_t)u * 64 + quad * 8;
    a0_[it] = *(const short8b*)(xp);
    a1_[it] = *(const short8b*)(xp + 32);
  }

  int curRel = -1;
  short8b bfrag[4][2] = {};

#pragma unroll
  for (int it = 0; it < 4; ++it) {
    int rel = rel4[it];
    if (rel == 255) continue;            // wave-uniform
    int par = it & 1;

    if (rel != curRel) {
      curRel = rel;
      const uint16_t* wbase = Wt + (size_t)rel * 4096;
      for (int nt = 0; nt < 4; ++nt)
        for (int kt = 0; kt < 2; ++kt)
          bfrag[nt][kt] = *(const short8b*)(wbase + (size_t)(nt * 16 + m16) * 64 + kt * 32 + quad * 8);
    }

    float4v acc[4];
    for (int nt = 0; nt < 4; ++nt) { acc[nt][0] = 0.f; acc[nt][1] = 0.f; acc[nt][2] = 0.f; acc[nt][3] = 0.f; }
    for (int nt = 0; nt < 4; ++nt) {
      acc[nt] = __builtin_amdgcn_mfma_f32_16x16x32_bf16(a0_[it], bfrag[nt][0], acc[nt], 0, 0, 0);
      acc[nt] = __builtin_amdgcn_mfma_f32_16x16x32_bf16(a1_[it], bfrag[nt][1], acc[nt], 0, 0, 0);
    }

    // C/D: col(dim) = m16 + nt*16, row(message) = quad*4 + reg
    if (quad == 0) s_slot[wid][par][m16] = rec4[it].y;
    for (int reg = 0; reg < 4; ++reg)
      for (int nt = 0; nt < 4; ++nt)
        s_m[wid][par][(quad * 4 + reg) * 72 + nt * 16 + m16] = f32_bf16_hw(acc[nt][reg]);

    asm volatile("s_waitcnt lgkmcnt(0)" ::: "memory");
    __builtin_amdgcn_sched_barrier(0);

    // 16 rows x 128 B, 8 lanes/row x 16 B; msg is write-once streaming -> nt.
    // No trailing barrier: next tile's MFMA/ds_writes (other buffer) overlap
    // these stores; buffer reuse at it+2 is ordered by in-wave DS + MayAlias.
    for (int p = 0; p < 2; ++p) {
      int row = (lane >> 3) + p * 8;
      int slot = s_slot[wid][par][row];
      if (slot >= 0) {
        const uint16_t* lp = &s_m[wid][par][row * 72 + (lane & 7) * 8];
        int4v val = *(const int4v*)lp;
        __builtin_nontemporal_store(val, (int4v*)(msg + (size_t)slot * 64 + (lane & 7) * 8));
      }
    }
  }
}

// Phase B: per-target segmented sum. 8 lanes/target, nt 16 B loads.
__global__ __launch_bounds__(256) void k_phaseB(const uint16_t* __restrict__ msg,
                                                const int* __restrict__ cntt,
                                                const int* __restrict__ vstart,
                                                float* __restrict__ out, int nN) {
  int v = blockIdx.x * 32 + (threadIdx.x >> 3);
  int l = threadIdx.x & 7;
  if (v >= nN) return;
  int cnt = cntt[v];
  int base = vstart[v];
  float a[8] = {0.f, 0.f, 0.f, 0.f, 0.f, 0.f, 0.f, 0.f};
  const uint16_t* mp = msg + (size_t)base * 64 + l * 8;
  int j = 0;
  for (; j + 2 <= cnt; j += 2) {
    int4v r0 = __builtin_nontemporal_load((const int4v*)(mp + (size_t)j * 64));
    int4v r1 = __builtin_nontemporal_load((const int4v*)(mp + (size_t)(j + 1) * 64));
    short8b h0 = __builtin_bit_cast(short8b, r0);
    short8b h1 = __builtin_bit_cast(short8b, r1);
#pragma unroll
    for (int k = 0; k < 8; ++k)
      a[k] += bf2f((uint16_t)h0[k]) + bf2f((uint16_t)h1[k]);
  }
  if (j < cnt) {
    int4v r0 = __builtin_nontemporal_load((const int4v*)(mp + (size_t)j * 64));
    short8b h = __builtin_bit_cast(short8b, r0);
#pragma unroll
    for (int k = 0; k < 8; ++k)
      a[k] += bf2f((uint16_t)h[k]);
  }
  float* op = out + (size_t)v * 64 + l * 8;
  float4v o0, o1;
  o0[0] = a[0]; o0[1] = a[1]; o0[2] = a[2]; o0[3] = a[3];
  o1[0] = a[4]; o1[1] = a[5]; o1[2] = a[6]; o1[3] = a[7];
  __builtin_nontemporal_store(o0, (float4v*)op);
  __builtin_nontemporal_store(o1, (float4v*)(op + 4));
}

// ======================================================================
// FALLBACK PATH (atomic scatter) — used only if ws_size too small
// ======================================================================
#define F_WS_HIST    0
#define F_WS_CURSOR  64
#define F_WS_START   128
#define F_WS_WT      512
#define F_WS_TILEREL 139776
#define F_WS_RECS    262144
#define F_MAXTILES   112520
#define F_MAXRECS    (F_MAXTILES * 16)

__global__ __launch_bounds__(256) void f_hist(const int* __restrict__ et,
                                              int* __restrict__ hist, int nE) {
  __shared__ int lh[NREL];
  if (threadIdx.x < NREL) lh[threadIdx.x] = 0;
  __syncthreads();
  int i = blockIdx.x * 256 + threadIdx.x;
  if (i < nE) atomicAdd(&lh[et[i]], 2);
  __syncthreads();
  if (threadIdx.x < NREL && lh[threadIdx.x] > 0)
    atomicAdd(&hist[threadIdx.x], lh[threadIdx.x]);
}

__global__ __launch_bounds__(256) void f_prefix(const int* __restrict__ hist,
                                                int* __restrict__ cursor,
                                                int* __restrict__ start,
                                                uint8_t* __restrict__ tileRel,
                                                int nN, int maxTiles) {
  __shared__ int s_start[17];
  if (threadIdx.x == 0) {
    int base = nN;
    for (int r = 0; r < NREL; ++r) {
      s_start[r] = base;
      cursor[r] = base;
      start[r] = base;
      base = (base + hist[r] + 15) & ~15;
    }
    s_start[16] = base;
    start[16] = base;
  }
  __syncthreads();
  int endp = s_start[16];
  for (int t = threadIdx.x; t < maxTiles; t += 256) {
    int p = t * 16;
    uint8_t r;
    if (p < nN) r = 16;
    else if (p >= endp) r = 255;
    else {
      int q = 0;
      for (int k = 1; k < NREL; ++k) if (p >= s_start[k]) q = k;
      r = (uint8_t)q;
    }
    tileRel[t] = r;
  }
}

__global__ __launch_bounds__(256) void f_scatter(const int* __restrict__ src,
                                                 const int* __restrict__ tgt,
                                                 const int* __restrict__ et,
                                                 const int* __restrict__ mask,
                                                 int2* __restrict__ recs,
                                                 int* __restrict__ cursor,
                                                 int nE, int nN) {
  __shared__ int lh[NREL];
  __shared__ int lbase[NREL];
  if (threadIdx.x < NREL) lh[threadIdx.x] = 0;
  __syncthreads();
  int i = blockIdx.x * 256 + threadIdx.x;
  int r = 0, loff = 0;
  bool isEdge = (i < nE);
  if (isEdge) {
    r = et[i];
    loff = atomicAdd(&lh[r], 2);
  }
  __syncthreads();
  if (threadIdx.x < NREL)
    lbase[threadIdx.x] = (lh[threadIdx.x] > 0) ? atomicAdd(&cursor[threadIdx.x], lh[threadIdx.x]) : 0;
  __syncthreads();
  if (isEdge) {
    int pos = lbase[r] + loff;
    int s = src[i], t = tgt[i];
    *(int4*)(recs + pos) = make_int4(s, t, t, s);
  }
  if (i < nN) {
    recs[i] = (mask[i] != 0) ? make_int2(i, i) : make_int2(-1, -1);
  }
}

__global__ __launch_bounds__(256) void f_compute(const float* __restrict__ x,
                                                 const int2* __restrict__ recs,
                                                 const uint16_t* __restrict__ Wt,
                                                 const uint8_t* __restrict__ tileRel,
                                                 float* __restrict__ out,
                                                 int ntiles) {
  const int lane = threadIdx.x & 63;
  const int quad = lane >> 4;
  const int m16 = lane & 15;
  const int wave = blockIdx.x * 4 + (threadIdx.x >> 6);
  const int t0 = wave * 4;

  int curRel = -1;
  short8b bfrag[4][2] = {};

  for (int it = 0; it < 4; ++it) {
    int t = t0 + it;
    if (t >= ntiles) return;
    int rel = tileRel[t];
    if (rel == 255) return;

    if (rel != curRel) {
      curRel = rel;
      const uint16_t* wbase = Wt + (size_t)rel * 4096;
      for (int nt = 0; nt < 4; ++nt)
        for (int kt = 0; kt < 2; ++kt)
          bfrag[nt][kt] = *(const short8b*)(wbase + (size_t)(nt * 16 + m16) * 64 + kt * 32 + quad * 8);
    }

    int2 rec = recs[t * 16 + m16];
    int u = rec.x < 0 ? 0 : rec.x;

    const float* xp = x + (size_t)u * 64 + quad * 8;
    float4v q0 = *(const float4v*)(xp);
    float4v q1 = *(const float4v*)(xp + 4);
    float4v q2 = *(const float4v*)(xp + 32);
    float4v q3 = *(const float4v*)(xp + 36);
    short8b a0, a1;
    a0[0] = f32_bf16(q0[0]); a0[1] = f32_bf16(q0[1]); a0[2] = f32_bf16(q0[2]); a0[3] = f32_bf16(q0[3]);
    a0[4] = f32_bf16(q1[0]); a0[5] = f32_bf16(q1[1]); a0[6] = f32_bf16(q1[2]); a0[7] = f32_bf16(q1[3]);
    a1[0] = f32_bf16(q2[0]); a1[1] = f32_bf16(q2[1]); a1[2] = f32_bf16(q2[2]); a1[3] = f32_bf16(q2[3]);
    a1[4] = f32_bf16(q3[0]); a1[5] = f32_bf16(q3[1]); a1[6] = f32_bf16(q3[2]); a1[7] = f32_bf16(q3[3]);

    float4v acc[4];
    for (int nt = 0; nt < 4; ++nt) { acc[nt][0] = 0.f; acc[nt][1] = 0.f; acc[nt][2] = 0.f; acc[nt][3] = 0.f; }
    for (int nt = 0; nt < 4; ++nt) {
      acc[nt] = __builtin_amdgcn_mfma_f32_16x16x32_bf16(a0, bfrag[nt][0], acc[nt], 0, 0, 0);
      acc[nt] = __builtin_amdgcn_mfma_f32_16x16x32_bf16(a1, bfrag[nt][1], acc[nt], 0, 0, 0);
    }

    int tg[4];
    for (int reg = 0; reg < 4; ++reg)
      tg[reg] = __shfl(rec.y, quad * 4 + reg, 64);
    for (int reg = 0; reg < 4; ++reg) {
      if (tg[reg] < 0) continue;
      float* op = out + (size_t)tg[reg] * 64 + m16;
      for (int nt = 0; nt < 4; ++nt)
        __hip_atomic_fetch_add(op + nt * 16, acc[nt][reg], __ATOMIC_RELAXED, __HIP_MEMORY_SCOPE_AGENT);
    }
  }
}

// ======================================================================
extern "C" void kernel_launch(void* const* d_in, const int* in_sizes, int n_in,
                              void* d_out, int out_size, void* d_ws, size_t ws_size,
                              hipStream_t stream) {
  const float* x     = (const float*)d_in[0];
  const int*   mask  = (const int*)d_in[1];
  const int*   src   = (const int*)d_in[2];
  const int*   tgt   = (const int*)d_in[3];
  const int*   et    = (const int*)d_in[4];
  const float* bases = (const float*)d_in[5];
  const float* att   = (const float*)d_in[6];
  float* out = (float*)d_out;
  char* ws = (char*)d_ws;

  if (ws_size >= WS_TOTAL) {
    // ---------- two-phase target-sorted path ----------
    int*      cntr    = (int*)(ws + WS_CNTR);
    int*      gcur2   = (int*)(ws + WS_GCUR2);
    int*      rstart  = (int*)(ws + WS_RSTART);
    int*      gcur    = (int*)(ws + WS_GCUR);
    uint16_t* Wt      = (uint16_t*)(ws + WS_WT);
    uint8_t*  tileRel = (uint8_t*)(ws + WS_TILEREL);
    int*      vstart  = (int*)(ws + WS_VSTART);
    int*      cntt    = (int*)(ws + WS_CNTT);
    int2*     recs    = (int2*)(ws + WS_RECS);
    uint16_t* msg     = (uint16_t*)(ws + WS_MSG);
    int*      reloff  = (int*)(ws + TR_RELOFF);
    int*      noff    = (int*)(ws + TR_NOFF);
    int*      eslot   = (int*)(ws + TR_ESLOT);
    int*      scratch = (int*)(ws + TR_SCRATCH);
    int*      H       = (int*)(ws + TR_H);
    int*      baseM   = (int*)(ws + TR_BASE);
    int*      regStart= (int*)(ws + TR_REGS);
    int*      regTot  = regStart + NB;
    uint16_t* xb      = (uint16_t*)out;           // bf16 x-table in dead output

    k_init<<<274, 256, 0, stream>>>(bases, att, Wt, (int*)ws);
    k_count<<<CNT_BLOCKS + CAST_BLOCKS, 256, 0, stream>>>(src, tgt, et, mask, cntr, H, reloff, noff, x, xb, N_EDGES, N_NODES);
    k_base<<<NB + PREP_BLOCKS, 256, 0, stream>>>(H, baseM, regStart, regTot, gcur2, cntr, rstart, tileRel, recs, MAXTILES);
    k_scat<<<CNT_BLOCKS, 256, 0, stream>>>(src, tgt, baseM, scratch, N_EDGES);
    k_slot<<<NB, 256, 0, stream>>>(scratch, regStart, regTot, mask, noff, rstart, eslot, vstart, cntt, gcur, recs, N_NODES);
    k_write<<<(N_EDGES + 255) / 256, 256, 0, stream>>>(src, tgt, et, reloff, eslot, rstart, recs, N_EDGES);
    k_phaseA<<<(MAXTILES + 15) / 16, 256, 0, stream>>>(xb, recs, Wt, tileRel, msg, MAXTILES);
    k_phaseB<<<(N_NODES + 31) / 32, 256, 0, stream>>>(msg, cntt, vstart, out, N_NODES);
  } else {
    // ---------- fallback: atomic path ----------
    int*      hist    = (int*)(ws + F_WS_HIST);
    int*      cursor  = (int*)(ws + F_WS_CURSOR);
    int*      start   = (int*)(ws + F_WS_START);
    uint16_t* Wt      = (uint16_t*)(ws + F_WS_WT);
    uint8_t*  tileRel = (uint8_t*)(ws + F_WS_TILEREL);
    int2*     recs    = (int2*)(ws + F_WS_RECS);

    (void)hipMemsetAsync(out, 0, (size_t)N_NODES * 64 * sizeof(float), stream);
    (void)hipMemsetAsync(ws, 0, 512, stream);
    (void)hipMemsetAsync(recs, 0xFF, (size_t)F_MAXRECS * sizeof(int2), stream);

    k_wprep<<<(17 * 64 * 64 + 255) / 256, 256, 0, stream>>>(bases, att, Wt);
    f_hist<<<(N_EDGES + 255) / 256, 256, 0, stream>>>(et, hist, N_EDGES);
    f_prefix<<<1, 256, 0, stream>>>(hist, cursor, start, tileRel, N_NODES, F_MAXTILES);
    f_scatter<<<(N_EDGES + 255) / 256, 256, 0, stream>>>(src, tgt, et, mask, recs, cursor, N_EDGES, N_NODES);
    f_compute<<<(F_MAXTILES + 15) / 16, 256, 0, stream>>>(x, recs, Wt, tileRel, out, F_MAXTILES);
  }
}